// Round 4
// baseline (905.106 us; speedup 1.0000x reference)
//
#include <hip/hip_runtime.h>
#include <hip/hip_fp16.h>

#define NN 50000
#define NE 800000
#define HH 128
#define SCAN_BS 512
#define SCAN_NB ((NN + SCAN_BS - 1) / SCAN_BS)   // 98

typedef short bf16x8 __attribute__((ext_vector_type(8)));
typedef short bf16x4 __attribute__((ext_vector_type(4)));
typedef float f32x4  __attribute__((ext_vector_type(4)));

// ---------------------------------------------------------------------------
// fp32 -> bf16 hi/lo split (RNE)
// ---------------------------------------------------------------------------
__device__ __forceinline__ void split_bf16(float x, short& h, short& l)
{
    unsigned u = __builtin_bit_cast(unsigned, x);
    unsigned r = u + 0x7FFFu + ((u >> 16) & 1u);
    h = (short)(r >> 16);
    float hf = __builtin_bit_cast(float, (unsigned)((r >> 16) << 16));
    float lf = x - hf;
    unsigned u2 = __builtin_bit_cast(unsigned, lf);
    unsigned r2 = u2 + 0x7FFFu + ((u2 >> 16) & 1u);
    l = (short)(r2 >> 16);
}

#define LDK 40

// ---------------------------------------------------------------------------
// Generic split-bf16 MFMA GEMM: C = act(bias + A@W), fp32 in/out.
// Block tile 128x128, BK=32, 4 waves (2x2), 64x64/wave.
// ---------------------------------------------------------------------------
template<bool RELU>
__global__ __launch_bounds__(256)
void gemm_mfma(const float* __restrict__ A, int lda,
               const float* __restrict__ W, int ldw,
               const float* __restrict__ bias,
               float* __restrict__ C, int ldc,
               int M, int K)
{
    __shared__ short Ah[128 * LDK], Al[128 * LDK];
    __shared__ short Bh[128 * LDK], Bl[128 * LDK];

    const int t    = threadIdx.x;
    const int m0   = blockIdx.y << 7;
    const int n0   = blockIdx.x << 7;
    const int lane = t & 63;
    const int wid  = t >> 6;
    const int wr   = wid >> 1, wc = wid & 1;
    const int fr   = lane & 15;
    const int fg   = lane >> 4;

    f32x4 acc[4][4] = {};

    for (int k0 = 0; k0 < K; k0 += 32) {
        {
            const int m  = t >> 1;
            const int kh = (t & 1) << 4;
            const int gm = m0 + m;
            float f[16];
            if (gm < M) {
                const float* p = A + (size_t)gm * lda + k0 + kh;
#pragma unroll
                for (int x = 0; x < 4; ++x) {
                    const float4 v = *reinterpret_cast<const float4*>(p + x * 4);
                    f[x * 4 + 0] = v.x; f[x * 4 + 1] = v.y;
                    f[x * 4 + 2] = v.z; f[x * 4 + 3] = v.w;
                }
            } else {
#pragma unroll
                for (int x = 0; x < 16; ++x) f[x] = 0.f;
            }
            bf16x8 h0, h1, l0, l1;
#pragma unroll
            for (int x = 0; x < 8; ++x) { short h, l; split_bf16(f[x],     h, l); h0[x] = h; l0[x] = l; }
#pragma unroll
            for (int x = 0; x < 8; ++x) { short h, l; split_bf16(f[8 + x], h, l); h1[x] = h; l1[x] = l; }
            *reinterpret_cast<bf16x8*>(&Ah[m * LDK + kh])     = h0;
            *reinterpret_cast<bf16x8*>(&Ah[m * LDK + kh + 8]) = h1;
            *reinterpret_cast<bf16x8*>(&Al[m * LDK + kh])     = l0;
            *reinterpret_cast<bf16x8*>(&Al[m * LDK + kh + 8]) = l1;
        }
        {
            const int n  = t & 127;
            const int kb = (t >> 7) << 2;
#pragma unroll
            for (int kk0 = 0; kk0 < 32; kk0 += 8) {
                const int kk = kk0 + kb;
                bf16x4 hv, lv;
#pragma unroll
                for (int x = 0; x < 4; ++x) {
                    const float v = W[(size_t)(k0 + kk + x) * ldw + n0 + n];
                    short h, l; split_bf16(v, h, l);
                    hv[x] = h; lv[x] = l;
                }
                *reinterpret_cast<bf16x4*>(&Bh[n * LDK + kk]) = hv;
                *reinterpret_cast<bf16x4*>(&Bl[n * LDK + kk]) = lv;
            }
        }
        __syncthreads();

        bf16x8 ah[4], al[4], bh[4], bl[4];
#pragma unroll
        for (int i = 0; i < 4; ++i) {
            const int m = wr * 64 + i * 16 + fr;
            ah[i] = *reinterpret_cast<const bf16x8*>(&Ah[m * LDK + fg * 8]);
            al[i] = *reinterpret_cast<const bf16x8*>(&Al[m * LDK + fg * 8]);
        }
#pragma unroll
        for (int j = 0; j < 4; ++j) {
            const int n = wc * 64 + j * 16 + fr;
            bh[j] = *reinterpret_cast<const bf16x8*>(&Bh[n * LDK + fg * 8]);
            bl[j] = *reinterpret_cast<const bf16x8*>(&Bl[n * LDK + fg * 8]);
        }
#pragma unroll
        for (int i = 0; i < 4; ++i)
#pragma unroll
            for (int j = 0; j < 4; ++j) {
                f32x4 a = acc[i][j];
                a = __builtin_amdgcn_mfma_f32_16x16x32_bf16(ah[i], bh[j], a, 0, 0, 0);
                a = __builtin_amdgcn_mfma_f32_16x16x32_bf16(ah[i], bl[j], a, 0, 0, 0);
                a = __builtin_amdgcn_mfma_f32_16x16x32_bf16(al[i], bh[j], a, 0, 0, 0);
                acc[i][j] = a;
            }
        __syncthreads();
    }

#pragma unroll
    for (int j = 0; j < 4; ++j) {
        const int gn = n0 + wc * 64 + j * 16 + fr;
        const float bv = bias[gn];
#pragma unroll
        for (int i = 0; i < 4; ++i) {
            const int mbase = m0 + wr * 64 + i * 16 + fg * 4;
#pragma unroll
            for (int r = 0; r < 4; ++r) {
                const int gm = mbase + r;
                if (gm < M) {
                    float v = acc[i][j][r] + bv;
                    if (RELU) v = fmaxf(v, 0.f);
                    C[(size_t)gm * ldc + gn] = v;
                }
            }
        }
    }
}

// ---------------------------------------------------------------------------
// Fused kqvs GEMM for one conv: 4 weight sets, N=512 logical, K=128, lda=128.
// blockIdx.x selects {Wk,Ws,Wq,Wv}. Outputs:
//   nb<2  -> Cks [N][256] fp32  (k | s)
//   nb>=2 -> qvh [N][256] fp16  (q | v)
// ---------------------------------------------------------------------------
__global__ __launch_bounds__(256)
void gemm_kqvs(const float* __restrict__ A,
               const float* __restrict__ W0, const float* __restrict__ b0,
               const float* __restrict__ W1, const float* __restrict__ b1,
               const float* __restrict__ W2, const float* __restrict__ b2,
               const float* __restrict__ W3, const float* __restrict__ b3,
               float* __restrict__ Cks,
               __half* __restrict__ qvh,
               int M)
{
    __shared__ short Ah[128 * LDK], Al[128 * LDK];
    __shared__ short Bh[128 * LDK], Bl[128 * LDK];

    const int nb = blockIdx.x;
    const float* Wt; const float* bt;
    if      (nb == 0) { Wt = W0; bt = b0; }
    else if (nb == 1) { Wt = W1; bt = b1; }
    else if (nb == 2) { Wt = W2; bt = b2; }
    else              { Wt = W3; bt = b3; }

    const int t    = threadIdx.x;
    const int m0   = blockIdx.y << 7;
    const int lane = t & 63;
    const int wid  = t >> 6;
    const int wr   = wid >> 1, wc = wid & 1;
    const int fr   = lane & 15;
    const int fg   = lane >> 4;

    f32x4 acc[4][4] = {};

    for (int k0 = 0; k0 < 128; k0 += 32) {
        {
            const int m  = t >> 1;
            const int kh = (t & 1) << 4;
            const int gm = m0 + m;
            float f[16];
            if (gm < M) {
                const float* p = A + (size_t)gm * 128 + k0 + kh;
#pragma unroll
                for (int x = 0; x < 4; ++x) {
                    const float4 v = *reinterpret_cast<const float4*>(p + x * 4);
                    f[x * 4 + 0] = v.x; f[x * 4 + 1] = v.y;
                    f[x * 4 + 2] = v.z; f[x * 4 + 3] = v.w;
                }
            } else {
#pragma unroll
                for (int x = 0; x < 16; ++x) f[x] = 0.f;
            }
            bf16x8 h0, h1, l0, l1;
#pragma unroll
            for (int x = 0; x < 8; ++x) { short h, l; split_bf16(f[x],     h, l); h0[x] = h; l0[x] = l; }
#pragma unroll
            for (int x = 0; x < 8; ++x) { short h, l; split_bf16(f[8 + x], h, l); h1[x] = h; l1[x] = l; }
            *reinterpret_cast<bf16x8*>(&Ah[m * LDK + kh])     = h0;
            *reinterpret_cast<bf16x8*>(&Ah[m * LDK + kh + 8]) = h1;
            *reinterpret_cast<bf16x8*>(&Al[m * LDK + kh])     = l0;
            *reinterpret_cast<bf16x8*>(&Al[m * LDK + kh + 8]) = l1;
        }
        {
            const int n  = t & 127;
            const int kb = (t >> 7) << 2;
#pragma unroll
            for (int kk0 = 0; kk0 < 32; kk0 += 8) {
                const int kk = kk0 + kb;
                bf16x4 hv, lv;
#pragma unroll
                for (int x = 0; x < 4; ++x) {
                    const float v = Wt[(size_t)(k0 + kk + x) * 128 + n];
                    short h, l; split_bf16(v, h, l);
                    hv[x] = h; lv[x] = l;
                }
                *reinterpret_cast<bf16x4*>(&Bh[n * LDK + kk]) = hv;
                *reinterpret_cast<bf16x4*>(&Bl[n * LDK + kk]) = lv;
            }
        }
        __syncthreads();

        bf16x8 ah[4], al[4], bh[4], bl[4];
#pragma unroll
        for (int i = 0; i < 4; ++i) {
            const int m = wr * 64 + i * 16 + fr;
            ah[i] = *reinterpret_cast<const bf16x8*>(&Ah[m * LDK + fg * 8]);
            al[i] = *reinterpret_cast<const bf16x8*>(&Al[m * LDK + fg * 8]);
        }
#pragma unroll
        for (int j = 0; j < 4; ++j) {
            const int n = wc * 64 + j * 16 + fr;
            bh[j] = *reinterpret_cast<const bf16x8*>(&Bh[n * LDK + fg * 8]);
            bl[j] = *reinterpret_cast<const bf16x8*>(&Bl[n * LDK + fg * 8]);
        }
#pragma unroll
        for (int i = 0; i < 4; ++i)
#pragma unroll
            for (int j = 0; j < 4; ++j) {
                f32x4 a = acc[i][j];
                a = __builtin_amdgcn_mfma_f32_16x16x32_bf16(ah[i], bh[j], a, 0, 0, 0);
                a = __builtin_amdgcn_mfma_f32_16x16x32_bf16(ah[i], bl[j], a, 0, 0, 0);
                a = __builtin_amdgcn_mfma_f32_16x16x32_bf16(al[i], bh[j], a, 0, 0, 0);
                acc[i][j] = a;
            }
        __syncthreads();
    }

#pragma unroll
    for (int j = 0; j < 4; ++j) {
        const int gnl = wc * 64 + j * 16 + fr;          // local col 0..127
        const float bv = bt[gnl];
#pragma unroll
        for (int i = 0; i < 4; ++i) {
            const int mbase = m0 + wr * 64 + i * 16 + fg * 4;
#pragma unroll
            for (int r = 0; r < 4; ++r) {
                const int gm = mbase + r;
                if (gm < M) {
                    const float v = acc[i][j][r] + bv;
                    if (nb < 2)
                        Cks[(size_t)gm * 256 + nb * 128 + gnl] = v;
                    else
                        qvh[(size_t)gm * 256 + (nb - 2) * 128 + gnl] = __float2half(v);
                }
            }
        }
    }
}

// ---------------------------------------------------------------------------
// CSR build
// ---------------------------------------------------------------------------
__global__ __launch_bounds__(256)
void hist_kernel(const int* __restrict__ ei, int* __restrict__ deg)
{
    const int e = blockIdx.x * 256 + threadIdx.x;
    if (e < NE) atomicAdd(&deg[ei[NE + e]], 1);
}

__global__ __launch_bounds__(SCAN_BS)
void scan1_kernel(const int* __restrict__ deg, int* __restrict__ incl,
                  int* __restrict__ bsum)
{
    __shared__ int sm[SCAN_BS];
    const int t = threadIdx.x;
    const int i = blockIdx.x * SCAN_BS + t;
    sm[t] = (i < NN) ? deg[i] : 0;
    __syncthreads();
    for (int d = 1; d < SCAN_BS; d <<= 1) {
        const int add = (t >= d) ? sm[t - d] : 0;
        __syncthreads();
        sm[t] += add;
        __syncthreads();
    }
    if (i < NN) incl[i] = sm[t];
    if (t == SCAN_BS - 1) bsum[blockIdx.x] = sm[t];
}

__global__ __launch_bounds__(128)
void scan2_kernel(int* __restrict__ bsum)
{
    __shared__ int sm[128];
    const int t = threadIdx.x;
    const int v = (t < SCAN_NB) ? bsum[t] : 0;
    sm[t] = v;
    __syncthreads();
    for (int d = 1; d < 128; d <<= 1) {
        const int add = (t >= d) ? sm[t - d] : 0;
        __syncthreads();
        sm[t] += add;
        __syncthreads();
    }
    if (t < SCAN_NB) bsum[t] = sm[t] - v;   // exclusive prefix of block sums
}

__global__ __launch_bounds__(SCAN_BS)
void scan3_kernel(const int* __restrict__ incl, const int* __restrict__ deg,
                  const int* __restrict__ bsum, int* __restrict__ offs)
{
    const int t = threadIdx.x;
    const int i = blockIdx.x * SCAN_BS + t;
    if (i < NN) offs[i] = incl[i] - deg[i] + bsum[blockIdx.x];
    if (i == 0) offs[NN] = NE;
}

__global__ __launch_bounds__(256)
void scatter_kernel(const int* __restrict__ ei, const int* __restrict__ offs,
                    int* __restrict__ cur, int2* __restrict__ csr)
{
    const int e = blockIdx.x * 256 + threadIdx.x;
    if (e >= NE) return;
    const int d = ei[NE + e];
    const int p = offs[d] + atomicAdd(&cur[d], 1);
    csr[p] = make_int2(ei[e], e);
}

// ---------------------------------------------------------------------------
// Fused conv aggregation + skip + ReLU. One wave per dst node.
// ks  [N][256] fp32 (k|s) read contiguously per node;
// qvh [N][256] fp16 (q|v) gathered per edge (512B/edge);
// ea fp32 via wave-uniform scalar loads. 2-bank software pipeline.
// ---------------------------------------------------------------------------
__global__ __launch_bounds__(256)
void conv_agg_kernel(const int* __restrict__ offs,
                     const int2* __restrict__ csr,
                     const float* __restrict__ ea,
                     const float* __restrict__ We,
                     const float* __restrict__ ks,
                     const __half* __restrict__ qvh,
                     float* __restrict__ out)
{
    const int t    = threadIdx.x;
    const int lane = t & 63;
    const int n    = blockIdx.x * 4 + (t >> 6);
    if (n >= NN) return;

    float w0[21], w1[21];
#pragma unroll
    for (int q = 0; q < 21; ++q) {
        w0[q] = We[q * HH + lane];
        w1[q] = We[q * HH + 64 + lane];
    }

    const float* row = ks + (size_t)n * 256;
    const float kd0 = row[lane], kd1 = row[64 + lane];

    const int j0 = offs[n], j1 = offs[n + 1];
    float acc0 = 0.f, acc1 = 0.f;

    float aA[21], aB[21];
    __half qA0, qA1, vA0, vA1, qB0, qB1, vB0, vB1;

#define LOADD(B, SE) { \
    const int s_ = __builtin_amdgcn_readfirstlane((SE).x); \
    const int i_ = __builtin_amdgcn_readfirstlane((SE).y); \
    const __half* rp_ = qvh + (size_t)s_ * 256; \
    q##B##0 = rp_[lane];       q##B##1 = rp_[64 + lane]; \
    v##B##0 = rp_[128 + lane]; v##B##1 = rp_[192 + lane]; \
    const float* ap_ = ea + (size_t)i_ * 21; \
    _Pragma("unroll") \
    for (int q = 0; q < 21; ++q) a##B[q] = ap_[q]; }

#define COMPUTE(B) { \
    float e0x = 0.f, e0y = 0.f, e1x = 0.f, e1y = 0.f; \
    _Pragma("unroll") \
    for (int q = 0; q < 20; q += 2) { \
        e0x += a##B[q]     * w0[q];     e1x += a##B[q]     * w1[q]; \
        e0y += a##B[q + 1] * w0[q + 1]; e1y += a##B[q + 1] * w1[q + 1]; } \
    const float e0 = e0x + e0y + a##B[20] * w0[20]; \
    const float e1 = e1x + e1y + a##B[20] * w1[20]; \
    float g0 = kd0 + __half2float(q##B##0) + 2.f * e0; \
    float g1 = kd1 + __half2float(q##B##1) + 2.f * e1; \
    g0 = 1.f / (1.f + __expf(-g0)); \
    g1 = 1.f / (1.f + __expf(-g1)); \
    acc0 += g0 * (__half2float(v##B##0) + e0); \
    acc1 += g1 * (__half2float(v##B##1) + e1); }

    if (j0 < j1) {
        int2 seA = csr[j0];
        int2 seB = (j0 + 1 < j1) ? csr[j0 + 1] : seA;
        LOADD(A, seA)
        int j = j0;
        for (; j + 1 < j1; j += 2) {
            if (j + 2 < j1) seA = csr[j + 2];
            LOADD(B, seB)
            COMPUTE(A)
            if (j + 3 < j1) seB = csr[j + 3];
            if (j + 2 < j1) { LOADD(A, seA) }
            COMPUTE(B)
        }
        if (j < j1) COMPUTE(A)
    }
#undef LOADD
#undef COMPUTE

    const float s0 = row[128 + lane], s1 = row[192 + lane];
    out[(size_t)n * HH + lane]      = fmaxf(acc0 + s0, 0.f);
    out[(size_t)n * HH + 64 + lane] = fmaxf(acc1 + s1, 0.f);
}

// ---------------------------------------------------------------------------
__global__ __launch_bounds__(128)
void colsum_kernel(const float* __restrict__ g2, float* __restrict__ gsum, int M)
{
    const int c     = threadIdx.x;
    const int nb    = gridDim.x;
    const int chunk = (M + nb - 1) / nb;
    const int r0    = blockIdx.x * chunk;
    const int r1    = min(M, r0 + chunk);
    float acc = 0.f;
    for (int r = r0; r < r1; ++r) acc += g2[(size_t)r * HH + c];
    atomicAdd(&gsum[c], acc);
}

__global__ __launch_bounds__(256)
void gvec_kernel(const float* __restrict__ gsum,
                 const float* __restrict__ Wl1,
                 const float* __restrict__ bl1,
                 float* __restrict__ gvec, float invM)
{
    const int j = threadIdx.x;
    float acc = bl1[j];
    for (int k = 0; k < 128; ++k)
        acc += (gsum[k] * invM) * Wl1[(size_t)(128 + k) * 256 + j];
    gvec[j] = acc;
}

__global__ __launch_bounds__(256)
void head_out_kernel(const float* __restrict__ u2,
                     const float* __restrict__ Wl3,
                     const float* __restrict__ bl3,
                     float* __restrict__ out, int M)
{
    __shared__ float w[128];
    const int t = threadIdx.x;
    if (t < 128) w[t] = Wl3[t];
    __syncthreads();

    const int lane = t & 63;
    const int wv   = t >> 6;
    const int r    = blockIdx.x * 64 + wv * 16 + (lane >> 2);
    const int p    = lane & 3;
    float acc = 0.f;
    if (r < M) {
        const float* row = u2 + (size_t)r * HH + p * 32;
#pragma unroll
        for (int j = 0; j < 32; ++j) acc += row[j] * w[p * 32 + j];
    }
    acc += __shfl_xor(acc, 1);
    acc += __shfl_xor(acc, 2);
    if (p == 0 && r < M) out[r] = acc + bl3[0];
}

// ---------------------------------------------------------------------------
extern "C" void kernel_launch(void* const* d_in, const int* in_sizes, int n_in,
                              void* d_out, int out_size, void* d_ws, size_t ws_size,
                              hipStream_t stream)
{
    const float* G   = (const float*)d_in[0];
    const int*   ei  = (const int*)  d_in[1];
    const float* ea  = (const float*)d_in[2];
    const float* We1 = (const float*)d_in[3];  const float* be1 = (const float*)d_in[4];
    const float* We2 = (const float*)d_in[5];  const float* be2 = (const float*)d_in[6];
    const float* We3 = (const float*)d_in[7];  const float* be3 = (const float*)d_in[8];
    const float* c1_Wk = (const float*)d_in[9];  const float* c1_bk = (const float*)d_in[10];
    const float* c1_Wq = (const float*)d_in[11]; const float* c1_bq = (const float*)d_in[12];
    const float* c1_Wv = (const float*)d_in[13]; const float* c1_bv = (const float*)d_in[14];
    const float* c1_We = (const float*)d_in[15];
    const float* c1_Ws = (const float*)d_in[16]; const float* c1_bs = (const float*)d_in[17];
    const float* c2_Wk = (const float*)d_in[18]; const float* c2_bk = (const float*)d_in[19];
    const float* c2_Wq = (const float*)d_in[20]; const float* c2_bq = (const float*)d_in[21];
    const float* c2_Wv = (const float*)d_in[22]; const float* c2_bv = (const float*)d_in[23];
    const float* c2_We = (const float*)d_in[24];
    const float* c2_Ws = (const float*)d_in[25]; const float* c2_bs = (const float*)d_in[26];
    const float* Wg1 = (const float*)d_in[27]; const float* bg1 = (const float*)d_in[28];
    const float* Wg2 = (const float*)d_in[29]; const float* bg2 = (const float*)d_in[30];
    const float* Wl1 = (const float*)d_in[31]; const float* bl1 = (const float*)d_in[32];
    const float* Wl2 = (const float*)d_in[33]; const float* bl2 = (const float*)d_in[34];
    const float* Wl3 = (const float*)d_in[35]; const float* bl3 = (const float*)d_in[36];

    float* out = (float*)d_out;

    // ---- workspace layout
    const size_t SZ_A  = (size_t)NN * HH  * 4;    // 25.6 MB
    const size_t SZ_KS = (size_t)NN * 256 * 4;    // 51.2 MB (also u1 [N][256])
    const size_t SZ_QV = (size_t)NN * 256 * 2;    // 25.6 MB
    char* ws = (char*)d_ws;
    size_t off = 0;
    float*  bufA = (float*) (ws + off); off += SZ_A;
    float*  bufC = (float*) (ws + off); off += SZ_A;
    float*  ksb  = (float*) (ws + off); off += SZ_KS;
    __half* qvh  = (__half*)(ws + off); off += SZ_QV;
    float*  gsum = (float*) (ws + off); off += 256 * 4;
    float*  gvec = (float*) (ws + off); off += 256 * 4;
    int*    deg  = (int*)   (ws + off); off += (size_t)NN * 4;
    int*    incl = (int*)   (ws + off); off += (size_t)NN * 4;
    int*    bsum = (int*)   (ws + off); off += 128 * 4;
    int*    offs = (int*)   (ws + off); off += (size_t)(NN + 2) * 4;
    int*    cur  = (int*)   (ws + off); off += (size_t)NN * 4;
    off = (off + 15) & ~(size_t)15;
    int2*   csr  = (int2*)  (ws + off); off += (size_t)NE * 8;

    const dim3 blk(256);
    const int  MT = (NN + 127) / 128;                  // 391 m-tiles
    const dim3 g128(1, MT), g256(2, MT), g512(4, MT);
    const int  EB = (NE + 255) / 256;
    const int  AGGB = (NN + 3) / 4;
    const int  MB64 = (NN + 63) / 64;

    // ---- CSR build
    hipMemsetAsync(deg, 0, (size_t)NN * 4, stream);
    hipMemsetAsync(cur, 0, (size_t)NN * 4, stream);
    hist_kernel<<<dim3(EB), blk, 0, stream>>>(ei, deg);
    scan1_kernel<<<dim3(SCAN_NB), dim3(SCAN_BS), 0, stream>>>(deg, incl, bsum);
    scan2_kernel<<<dim3(1), dim3(128), 0, stream>>>(bsum);
    scan3_kernel<<<dim3(SCAN_NB), dim3(SCAN_BS), 0, stream>>>(incl, deg, bsum, offs);
    scatter_kernel<<<dim3(EB), blk, 0, stream>>>(ei, offs, cur, csr);

    // ---- node-feature MLP
    gemm_mfma<true><<<g128, blk, 0, stream>>>(G,    64,  We1, 128, be1, bufA, 128, NN, 64);
    gemm_mfma<true><<<g128, blk, 0, stream>>>(bufA, 128, We2, 128, be2, bufC, 128, NN, 128);
    gemm_mfma<true><<<g128, blk, 0, stream>>>(bufC, 128, We3, 128, be3, bufA, 128, NN, 128);

    // ---- conv1
    gemm_kqvs<<<g512, blk, 0, stream>>>(bufA,
        c1_Wk, c1_bk, c1_Ws, c1_bs, c1_Wq, c1_bq, c1_Wv, c1_bv, ksb, qvh, NN);
    conv_agg_kernel<<<dim3(AGGB), blk, 0, stream>>>(offs, csr, ea, c1_We, ksb, qvh, bufA);

    // ---- conv2
    gemm_kqvs<<<g512, blk, 0, stream>>>(bufA,
        c2_Wk, c2_bk, c2_Ws, c2_bs, c2_Wq, c2_bq, c2_Wv, c2_bv, ksb, qvh, NN);
    conv_agg_kernel<<<dim3(AGGB), blk, 0, stream>>>(offs, csr, ea, c2_We, ksb, qvh, bufA);

    // ---- graph-level MLP
    gemm_mfma<true ><<<g128, blk, 0, stream>>>(bufA, 128, Wg1, 128, bg1, bufC, 128, NN, 128);
    gemm_mfma<false><<<g128, blk, 0, stream>>>(bufC, 128, Wg2, 128, bg2, bufA, 128, NN, 128);  // g2

    // ---- graph mean -> gvec
    hipMemsetAsync(gsum, 0, 128 * 4, stream);
    colsum_kernel<<<dim3(256), dim3(128), 0, stream>>>(bufA, gsum, NN);
    gvec_kernel<<<dim3(1), dim3(256), 0, stream>>>(gsum, Wl1, bl1, gvec, 1.f / NN);

    // ---- head: u1 into ksb ([N][256]), u2 into bufC, dot -> out
    gemm_mfma<true><<<g256, blk, 0, stream>>>(bufA, 128, Wl1, 256, gvec, ksb, 256, NN, 128);
    gemm_mfma<true><<<g128, blk, 0, stream>>>(ksb, 256, Wl2, 128, bl2, bufC, 128, NN, 256);
    head_out_kernel<<<dim3(MB64), blk, 0, stream>>>(bufC, Wl3, bl3, out, NN);
}

// Round 5
// 733.261 us; speedup vs baseline: 1.2344x; 1.2344x over previous
//
#include <hip/hip_runtime.h>
#include <hip/hip_fp16.h>

#define NN 50000
#define NE 800000
#define HH 128
#define SCAN_BS 512
#define SCAN_NB ((NN + SCAN_BS - 1) / SCAN_BS)   // 98

typedef short bf16x8 __attribute__((ext_vector_type(8)));
typedef short bf16x4 __attribute__((ext_vector_type(4)));
typedef float f32x4  __attribute__((ext_vector_type(4)));

// ---------------------------------------------------------------------------
// fp32 -> bf16 hi/lo split (RNE)
// ---------------------------------------------------------------------------
__device__ __forceinline__ void split_bf16(float x, short& h, short& l)
{
    unsigned u = __builtin_bit_cast(unsigned, x);
    unsigned r = u + 0x7FFFu + ((u >> 16) & 1u);
    h = (short)(r >> 16);
    float hf = __builtin_bit_cast(float, (unsigned)((r >> 16) << 16));
    float lf = x - hf;
    unsigned u2 = __builtin_bit_cast(unsigned, lf);
    unsigned r2 = u2 + 0x7FFFu + ((u2 >> 16) & 1u);
    l = (short)(r2 >> 16);
}

#define LDK 40

// ---------------------------------------------------------------------------
// Generic split-bf16 MFMA GEMM: C = act(bias + A@W), fp32 in/out.
// Block tile 128x128, BK=32, 4 waves (2x2), 64x64/wave.
// ---------------------------------------------------------------------------
template<bool RELU>
__global__ __launch_bounds__(256)
void gemm_mfma(const float* __restrict__ A, int lda,
               const float* __restrict__ W, int ldw,
               const float* __restrict__ bias,
               float* __restrict__ C, int ldc,
               int M, int K)
{
    __shared__ short Ah[128 * LDK], Al[128 * LDK];
    __shared__ short Bh[128 * LDK], Bl[128 * LDK];

    const int t    = threadIdx.x;
    const int m0   = blockIdx.y << 7;
    const int n0   = blockIdx.x << 7;
    const int lane = t & 63;
    const int wid  = t >> 6;
    const int wr   = wid >> 1, wc = wid & 1;
    const int fr   = lane & 15;
    const int fg   = lane >> 4;

    f32x4 acc[4][4] = {};

    for (int k0 = 0; k0 < K; k0 += 32) {
        {
            const int m  = t >> 1;
            const int kh = (t & 1) << 4;
            const int gm = m0 + m;
            float f[16];
            if (gm < M) {
                const float* p = A + (size_t)gm * lda + k0 + kh;
#pragma unroll
                for (int x = 0; x < 4; ++x) {
                    const float4 v = *reinterpret_cast<const float4*>(p + x * 4);
                    f[x * 4 + 0] = v.x; f[x * 4 + 1] = v.y;
                    f[x * 4 + 2] = v.z; f[x * 4 + 3] = v.w;
                }
            } else {
#pragma unroll
                for (int x = 0; x < 16; ++x) f[x] = 0.f;
            }
            bf16x8 h0, h1, l0, l1;
#pragma unroll
            for (int x = 0; x < 8; ++x) { short h, l; split_bf16(f[x],     h, l); h0[x] = h; l0[x] = l; }
#pragma unroll
            for (int x = 0; x < 8; ++x) { short h, l; split_bf16(f[8 + x], h, l); h1[x] = h; l1[x] = l; }
            *reinterpret_cast<bf16x8*>(&Ah[m * LDK + kh])     = h0;
            *reinterpret_cast<bf16x8*>(&Ah[m * LDK + kh + 8]) = h1;
            *reinterpret_cast<bf16x8*>(&Al[m * LDK + kh])     = l0;
            *reinterpret_cast<bf16x8*>(&Al[m * LDK + kh + 8]) = l1;
        }
        {
            const int n  = t & 127;
            const int kb = (t >> 7) << 2;
#pragma unroll
            for (int kk0 = 0; kk0 < 32; kk0 += 8) {
                const int kk = kk0 + kb;
                bf16x4 hv, lv;
#pragma unroll
                for (int x = 0; x < 4; ++x) {
                    const float v = W[(size_t)(k0 + kk + x) * ldw + n0 + n];
                    short h, l; split_bf16(v, h, l);
                    hv[x] = h; lv[x] = l;
                }
                *reinterpret_cast<bf16x4*>(&Bh[n * LDK + kk]) = hv;
                *reinterpret_cast<bf16x4*>(&Bl[n * LDK + kk]) = lv;
            }
        }
        __syncthreads();

        bf16x8 ah[4], al[4], bh[4], bl[4];
#pragma unroll
        for (int i = 0; i < 4; ++i) {
            const int m = wr * 64 + i * 16 + fr;
            ah[i] = *reinterpret_cast<const bf16x8*>(&Ah[m * LDK + fg * 8]);
            al[i] = *reinterpret_cast<const bf16x8*>(&Al[m * LDK + fg * 8]);
        }
#pragma unroll
        for (int j = 0; j < 4; ++j) {
            const int n = wc * 64 + j * 16 + fr;
            bh[j] = *reinterpret_cast<const bf16x8*>(&Bh[n * LDK + fg * 8]);
            bl[j] = *reinterpret_cast<const bf16x8*>(&Bl[n * LDK + fg * 8]);
        }
#pragma unroll
        for (int i = 0; i < 4; ++i)
#pragma unroll
            for (int j = 0; j < 4; ++j) {
                f32x4 a = acc[i][j];
                a = __builtin_amdgcn_mfma_f32_16x16x32_bf16(ah[i], bh[j], a, 0, 0, 0);
                a = __builtin_amdgcn_mfma_f32_16x16x32_bf16(ah[i], bl[j], a, 0, 0, 0);
                a = __builtin_amdgcn_mfma_f32_16x16x32_bf16(al[i], bh[j], a, 0, 0, 0);
                acc[i][j] = a;
            }
        __syncthreads();
    }

#pragma unroll
    for (int j = 0; j < 4; ++j) {
        const int gn = n0 + wc * 64 + j * 16 + fr;
        const float bv = bias[gn];
#pragma unroll
        for (int i = 0; i < 4; ++i) {
            const int mbase = m0 + wr * 64 + i * 16 + fg * 4;
#pragma unroll
            for (int r = 0; r < 4; ++r) {
                const int gm = mbase + r;
                if (gm < M) {
                    float v = acc[i][j][r] + bv;
                    if (RELU) v = fmaxf(v, 0.f);
                    C[(size_t)gm * ldc + gn] = v;
                }
            }
        }
    }
}

// ---------------------------------------------------------------------------
// Fused kqvs GEMM for one conv: blockIdx.x selects {Wk,Ws,Wq,Wv}.
//   nb<2  -> Cks [N][256] fp32  (k | s)
//   nb>=2 -> qvh [N][256] fp16  (q | v)
// ---------------------------------------------------------------------------
__global__ __launch_bounds__(256)
void gemm_kqvs(const float* __restrict__ A,
               const float* __restrict__ W0, const float* __restrict__ b0,
               const float* __restrict__ W1, const float* __restrict__ b1,
               const float* __restrict__ W2, const float* __restrict__ b2,
               const float* __restrict__ W3, const float* __restrict__ b3,
               float* __restrict__ Cks,
               __half* __restrict__ qvh,
               int M)
{
    __shared__ short Ah[128 * LDK], Al[128 * LDK];
    __shared__ short Bh[128 * LDK], Bl[128 * LDK];

    const int nb = blockIdx.x;
    const float* Wt; const float* bt;
    if      (nb == 0) { Wt = W0; bt = b0; }
    else if (nb == 1) { Wt = W1; bt = b1; }
    else if (nb == 2) { Wt = W2; bt = b2; }
    else              { Wt = W3; bt = b3; }

    const int t    = threadIdx.x;
    const int m0   = blockIdx.y << 7;
    const int lane = t & 63;
    const int wid  = t >> 6;
    const int wr   = wid >> 1, wc = wid & 1;
    const int fr   = lane & 15;
    const int fg   = lane >> 4;

    f32x4 acc[4][4] = {};

    for (int k0 = 0; k0 < 128; k0 += 32) {
        {
            const int m  = t >> 1;
            const int kh = (t & 1) << 4;
            const int gm = m0 + m;
            float f[16];
            if (gm < M) {
                const float* p = A + (size_t)gm * 128 + k0 + kh;
#pragma unroll
                for (int x = 0; x < 4; ++x) {
                    const float4 v = *reinterpret_cast<const float4*>(p + x * 4);
                    f[x * 4 + 0] = v.x; f[x * 4 + 1] = v.y;
                    f[x * 4 + 2] = v.z; f[x * 4 + 3] = v.w;
                }
            } else {
#pragma unroll
                for (int x = 0; x < 16; ++x) f[x] = 0.f;
            }
            bf16x8 h0, h1, l0, l1;
#pragma unroll
            for (int x = 0; x < 8; ++x) { short h, l; split_bf16(f[x],     h, l); h0[x] = h; l0[x] = l; }
#pragma unroll
            for (int x = 0; x < 8; ++x) { short h, l; split_bf16(f[8 + x], h, l); h1[x] = h; l1[x] = l; }
            *reinterpret_cast<bf16x8*>(&Ah[m * LDK + kh])     = h0;
            *reinterpret_cast<bf16x8*>(&Ah[m * LDK + kh + 8]) = h1;
            *reinterpret_cast<bf16x8*>(&Al[m * LDK + kh])     = l0;
            *reinterpret_cast<bf16x8*>(&Al[m * LDK + kh + 8]) = l1;
        }
        {
            const int n  = t & 127;
            const int kb = (t >> 7) << 2;
#pragma unroll
            for (int kk0 = 0; kk0 < 32; kk0 += 8) {
                const int kk = kk0 + kb;
                bf16x4 hv, lv;
#pragma unroll
                for (int x = 0; x < 4; ++x) {
                    const float v = Wt[(size_t)(k0 + kk + x) * 128 + n];
                    short h, l; split_bf16(v, h, l);
                    hv[x] = h; lv[x] = l;
                }
                *reinterpret_cast<bf16x4*>(&Bh[n * LDK + kk]) = hv;
                *reinterpret_cast<bf16x4*>(&Bl[n * LDK + kk]) = lv;
            }
        }
        __syncthreads();

        bf16x8 ah[4], al[4], bh[4], bl[4];
#pragma unroll
        for (int i = 0; i < 4; ++i) {
            const int m = wr * 64 + i * 16 + fr;
            ah[i] = *reinterpret_cast<const bf16x8*>(&Ah[m * LDK + fg * 8]);
            al[i] = *reinterpret_cast<const bf16x8*>(&Al[m * LDK + fg * 8]);
        }
#pragma unroll
        for (int j = 0; j < 4; ++j) {
            const int n = wc * 64 + j * 16 + fr;
            bh[j] = *reinterpret_cast<const bf16x8*>(&Bh[n * LDK + fg * 8]);
            bl[j] = *reinterpret_cast<const bf16x8*>(&Bl[n * LDK + fg * 8]);
        }
#pragma unroll
        for (int i = 0; i < 4; ++i)
#pragma unroll
            for (int j = 0; j < 4; ++j) {
                f32x4 a = acc[i][j];
                a = __builtin_amdgcn_mfma_f32_16x16x32_bf16(ah[i], bh[j], a, 0, 0, 0);
                a = __builtin_amdgcn_mfma_f32_16x16x32_bf16(ah[i], bl[j], a, 0, 0, 0);
                a = __builtin_amdgcn_mfma_f32_16x16x32_bf16(al[i], bh[j], a, 0, 0, 0);
                acc[i][j] = a;
            }
        __syncthreads();
    }

#pragma unroll
    for (int j = 0; j < 4; ++j) {
        const int gnl = wc * 64 + j * 16 + fr;          // local col 0..127
        const float bv = bt[gnl];
#pragma unroll
        for (int i = 0; i < 4; ++i) {
            const int mbase = m0 + wr * 64 + i * 16 + fg * 4;
#pragma unroll
            for (int r = 0; r < 4; ++r) {
                const int gm = mbase + r;
                if (gm < M) {
                    const float v = acc[i][j][r] + bv;
                    if (nb < 2)
                        Cks[(size_t)gm * 256 + nb * 128 + gnl] = v;
                    else
                        qvh[(size_t)gm * 256 + (nb - 2) * 128 + gnl] = __float2half(v);
                }
            }
        }
    }
}

// ---------------------------------------------------------------------------
// CSR build
// ---------------------------------------------------------------------------
__global__ __launch_bounds__(256)
void hist_kernel(const int* __restrict__ ei, int* __restrict__ deg)
{
    const int e = blockIdx.x * 256 + threadIdx.x;
    if (e < NE) atomicAdd(&deg[ei[NE + e]], 1);
}

__global__ __launch_bounds__(SCAN_BS)
void scan1_kernel(const int* __restrict__ deg, int* __restrict__ incl,
                  int* __restrict__ bsum)
{
    __shared__ int sm[SCAN_BS];
    const int t = threadIdx.x;
    const int i = blockIdx.x * SCAN_BS + t;
    sm[t] = (i < NN) ? deg[i] : 0;
    __syncthreads();
    for (int d = 1; d < SCAN_BS; d <<= 1) {
        const int add = (t >= d) ? sm[t - d] : 0;
        __syncthreads();
        sm[t] += add;
        __syncthreads();
    }
    if (i < NN) incl[i] = sm[t];
    if (t == SCAN_BS - 1) bsum[blockIdx.x] = sm[t];
}

__global__ __launch_bounds__(128)
void scan2_kernel(int* __restrict__ bsum)
{
    __shared__ int sm[128];
    const int t = threadIdx.x;
    const int v = (t < SCAN_NB) ? bsum[t] : 0;
    sm[t] = v;
    __syncthreads();
    for (int d = 1; d < 128; d <<= 1) {
        const int add = (t >= d) ? sm[t - d] : 0;
        __syncthreads();
        sm[t] += add;
        __syncthreads();
    }
    if (t < SCAN_NB) bsum[t] = sm[t] - v;   // exclusive prefix of block sums
}

__global__ __launch_bounds__(SCAN_BS)
void scan3_kernel(const int* __restrict__ incl, const int* __restrict__ deg,
                  const int* __restrict__ bsum, int* __restrict__ offs)
{
    const int t = threadIdx.x;
    const int i = blockIdx.x * SCAN_BS + t;
    if (i < NN) offs[i] = incl[i] - deg[i] + bsum[blockIdx.x];
    if (i == 0) offs[NN] = NE;
}

__global__ __launch_bounds__(256)
void scatter_kernel(const int* __restrict__ ei, const int* __restrict__ offs,
                    int* __restrict__ cur, int2* __restrict__ csr)
{
    const int e = blockIdx.x * 256 + threadIdx.x;
    if (e >= NE) return;
    const int d = ei[NE + e];
    const int p = offs[d] + atomicAdd(&cur[d], 1);
    csr[p] = make_int2(ei[e], e);
}

// ---------------------------------------------------------------------------
// Fused conv aggregation + skip + ReLU. One wave per dst node; lane handles
// channel pair {2*lane, 2*lane+1}.
// ks  [N][256] fp32 (k|s), contiguous per node.
// qvh [N][256] fp16 (q|v): q-gather and v-gather are one dword load each.
// __launch_bounds__(256,8) pins VGPR <= 64 (wave-residency cliff at 64).
// ---------------------------------------------------------------------------
__global__ __launch_bounds__(256, 8)
void conv_agg_kernel(const int* __restrict__ offs,
                     const int2* __restrict__ csr,
                     const float* __restrict__ ea,
                     const float* __restrict__ We,
                     const float* __restrict__ ks,
                     const __half* __restrict__ qvh,
                     float* __restrict__ out)
{
    const int t    = threadIdx.x;
    const int lane = t & 63;
    const int n    = blockIdx.x * 4 + (t >> 6);
    if (n >= NN) return;

    // We column pair for this lane (42 VGPRs)
    float2 w[21];
#pragma unroll
    for (int q = 0; q < 21; ++q)
        w[q] = *reinterpret_cast<const float2*>(&We[q * HH + 2 * lane]);

    const float2* ksrow = reinterpret_cast<const float2*>(ks + (size_t)n * 256);
    const float2 kd = ksrow[lane];   // k channels (2l, 2l+1)

    const int j0 = offs[n], j1 = offs[n + 1];
    float acc0 = 0.f, acc1 = 0.f;

    for (int j = j0; j < j1; ++j) {
        const int2 se   = csr[j];
        const int  s    = __builtin_amdgcn_readfirstlane(se.x);
        const int  eidx = __builtin_amdgcn_readfirstlane(se.y);

        // one dword gather each: q pair + v pair (saddr form, uniform base)
        const __half2* rp = reinterpret_cast<const __half2*>(qvh + (size_t)s * 256);
        const __half2 q2 = rp[lane];
        const __half2 v2 = rp[64 + lane];

        const float* av = ea + (size_t)eidx * 21;   // uniform -> s_load
        float e0 = 0.f, e1 = 0.f;
#pragma unroll
        for (int q = 0; q < 21; ++q) {
            const float a = av[q];
            e0 += a * w[q].x;
            e1 += a * w[q].y;
        }

        const float2 qf = __half22float2(q2);
        const float2 vf = __half22float2(v2);
        float g0 = kd.x + qf.x + 2.f * e0;
        float g1 = kd.y + qf.y + 2.f * e1;
        g0 = 1.f / (1.f + __expf(-g0));
        g1 = 1.f / (1.f + __expf(-g1));

        acc0 += g0 * (vf.x + e0);
        acc1 += g1 * (vf.y + e1);
    }

    const float2 sd = ksrow[64 + lane];
    float2 r;
    r.x = fmaxf(acc0 + sd.x, 0.f);
    r.y = fmaxf(acc1 + sd.y, 0.f);
    *reinterpret_cast<float2*>(&out[(size_t)n * HH + 2 * lane]) = r;
}

// ---------------------------------------------------------------------------
__global__ __launch_bounds__(128)
void colsum_kernel(const float* __restrict__ g2, float* __restrict__ gsum, int M)
{
    const int c     = threadIdx.x;
    const int nb    = gridDim.x;
    const int chunk = (M + nb - 1) / nb;
    const int r0    = blockIdx.x * chunk;
    const int r1    = min(M, r0 + chunk);
    float acc = 0.f;
    for (int r = r0; r < r1; ++r) acc += g2[(size_t)r * HH + c];
    atomicAdd(&gsum[c], acc);
}

__global__ __launch_bounds__(256)
void gvec_kernel(const float* __restrict__ gsum,
                 const float* __restrict__ Wl1,
                 const float* __restrict__ bl1,
                 float* __restrict__ gvec, float invM)
{
    const int j = threadIdx.x;
    float acc = bl1[j];
    for (int k = 0; k < 128; ++k)
        acc += (gsum[k] * invM) * Wl1[(size_t)(128 + k) * 256 + j];
    gvec[j] = acc;
}

__global__ __launch_bounds__(256)
void head_out_kernel(const float* __restrict__ u2,
                     const float* __restrict__ Wl3,
                     const float* __restrict__ bl3,
                     float* __restrict__ out, int M)
{
    __shared__ float w[128];
    const int t = threadIdx.x;
    if (t < 128) w[t] = Wl3[t];
    __syncthreads();

    const int lane = t & 63;
    const int wv   = t >> 6;
    const int r    = blockIdx.x * 64 + wv * 16 + (lane >> 2);
    const int p    = lane & 3;
    float acc = 0.f;
    if (r < M) {
        const float* row = u2 + (size_t)r * HH + p * 32;
#pragma unroll
        for (int j = 0; j < 32; ++j) acc += row[j] * w[p * 32 + j];
    }
    acc += __shfl_xor(acc, 1);
    acc += __shfl_xor(acc, 2);
    if (p == 0 && r < M) out[r] = acc + bl3[0];
}

// ---------------------------------------------------------------------------
extern "C" void kernel_launch(void* const* d_in, const int* in_sizes, int n_in,
                              void* d_out, int out_size, void* d_ws, size_t ws_size,
                              hipStream_t stream)
{
    const float* G   = (const float*)d_in[0];
    const int*   ei  = (const int*)  d_in[1];
    const float* ea  = (const float*)d_in[2];
    const float* We1 = (const float*)d_in[3];  const float* be1 = (const float*)d_in[4];
    const float* We2 = (const float*)d_in[5];  const float* be2 = (const float*)d_in[6];
    const float* We3 = (const float*)d_in[7];  const float* be3 = (const float*)d_in[8];
    const float* c1_Wk = (const float*)d_in[9];  const float* c1_bk = (const float*)d_in[10];
    const float* c1_Wq = (const float*)d_in[11]; const float* c1_bq = (const float*)d_in[12];
    const float* c1_Wv = (const float*)d_in[13]; const float* c1_bv = (const float*)d_in[14];
    const float* c1_We = (const float*)d_in[15];
    const float* c1_Ws = (const float*)d_in[16]; const float* c1_bs = (const float*)d_in[17];
    const float* c2_Wk = (const float*)d_in[18]; const float* c2_bk = (const float*)d_in[19];
    const float* c2_Wq = (const float*)d_in[20]; const float* c2_bq = (const float*)d_in[21];
    const float* c2_Wv = (const float*)d_in[22]; const float* c2_bv = (const float*)d_in[23];
    const float* c2_We = (const float*)d_in[24];
    const float* c2_Ws = (const float*)d_in[25]; const float* c2_bs = (const float*)d_in[26];
    const float* Wg1 = (const float*)d_in[27]; const float* bg1 = (const float*)d_in[28];
    const float* Wg2 = (const float*)d_in[29]; const float* bg2 = (const float*)d_in[30];
    const float* Wl1 = (const float*)d_in[31]; const float* bl1 = (const float*)d_in[32];
    const float* Wl2 = (const float*)d_in[33]; const float* bl2 = (const float*)d_in[34];
    const float* Wl3 = (const float*)d_in[35]; const float* bl3 = (const float*)d_in[36];

    float* out = (float*)d_out;

    // ---- workspace layout
    const size_t SZ_A  = (size_t)NN * HH  * 4;    // 25.6 MB
    const size_t SZ_KS = (size_t)NN * 256 * 4;    // 51.2 MB (also u1 [N][256])
    const size_t SZ_QV = (size_t)NN * 256 * 2;    // 25.6 MB
    char* ws = (char*)d_ws;
    size_t off = 0;
    float*  bufA = (float*) (ws + off); off += SZ_A;
    float*  bufC = (float*) (ws + off); off += SZ_A;
    float*  ksb  = (float*) (ws + off); off += SZ_KS;
    __half* qvh  = (__half*)(ws + off); off += SZ_QV;
    float*  gsum = (float*) (ws + off); off += 256 * 4;
    float*  gvec = (float*) (ws + off); off += 256 * 4;
    int*    deg  = (int*)   (ws + off); off += (size_t)NN * 4;
    int*    incl = (int*)   (ws + off); off += (size_t)NN * 4;
    int*    bsum = (int*)   (ws + off); off += 128 * 4;
    int*    offs = (int*)   (ws + off); off += (size_t)(NN + 2) * 4;
    int*    cur  = (int*)   (ws + off); off += (size_t)NN * 4;
    off = (off + 15) & ~(size_t)15;
    int2*   csr  = (int2*)  (ws + off); off += (size_t)NE * 8;

    const dim3 blk(256);
    const int  MT = (NN + 127) / 128;                  // 391 m-tiles
    const dim3 g128(1, MT), g256(2, MT), g512(4, MT);
    const int  EB = (NE + 255) / 256;
    const int  AGGB = (NN + 3) / 4;
    const int  MB64 = (NN + 63) / 64;

    // ---- CSR build
    hipMemsetAsync(deg, 0, (size_t)NN * 4, stream);
    hipMemsetAsync(cur, 0, (size_t)NN * 4, stream);
    hist_kernel<<<dim3(EB), blk, 0, stream>>>(ei, deg);
    scan1_kernel<<<dim3(SCAN_NB), dim3(SCAN_BS), 0, stream>>>(deg, incl, bsum);
    scan2_kernel<<<dim3(1), dim3(128), 0, stream>>>(bsum);
    scan3_kernel<<<dim3(SCAN_NB), dim3(SCAN_BS), 0, stream>>>(incl, deg, bsum, offs);
    scatter_kernel<<<dim3(EB), blk, 0, stream>>>(ei, offs, cur, csr);

    // ---- node-feature MLP
    gemm_mfma<true><<<g128, blk, 0, stream>>>(G,    64,  We1, 128, be1, bufA, 128, NN, 64);
    gemm_mfma<true><<<g128, blk, 0, stream>>>(bufA, 128, We2, 128, be2, bufC, 128, NN, 128);
    gemm_mfma<true><<<g128, blk, 0, stream>>>(bufC, 128, We3, 128, be3, bufA, 128, NN, 128);

    // ---- conv1
    gemm_kqvs<<<g512, blk, 0, stream>>>(bufA,
        c1_Wk, c1_bk, c1_Ws, c1_bs, c1_Wq, c1_bq, c1_Wv, c1_bv, ksb, qvh, NN);
    conv_agg_kernel<<<dim3(AGGB), blk, 0, stream>>>(offs, csr, ea, c1_We, ksb, qvh, bufA);

    // ---- conv2
    gemm_kqvs<<<g512, blk, 0, stream>>>(bufA,
        c2_Wk, c2_bk, c2_Ws, c2_bs, c2_Wq, c2_bq, c2_Wv, c2_bv, ksb, qvh, NN);
    conv_agg_kernel<<<dim3(AGGB), blk, 0, stream>>>(offs, csr, ea, c2_We, ksb, qvh, bufA);

    // ---- graph-level MLP
    gemm_mfma<true ><<<g128, blk, 0, stream>>>(bufA, 128, Wg1, 128, bg1, bufC, 128, NN, 128);
    gemm_mfma<false><<<g128, blk, 0, stream>>>(bufC, 128, Wg2, 128, bg2, bufA, 128, NN, 128);  // g2

    // ---- graph mean -> gvec
    hipMemsetAsync(gsum, 0, 128 * 4, stream);
    colsum_kernel<<<dim3(256), dim3(128), 0, stream>>>(bufA, gsum, NN);
    gvec_kernel<<<dim3(1), dim3(256), 0, stream>>>(gsum, Wl1, bl1, gvec, 1.f / NN);

    // ---- head: u1 into ksb ([N][256]), u2 into bufC, dot -> out
    gemm_mfma<true><<<g256, blk, 0, stream>>>(bufA, 128, Wl1, 256, gvec, ksb, 256, NN, 128);
    gemm_mfma<true><<<g128, blk, 0, stream>>>(ksb, 256, Wl2, 128, bl2, bufC, 128, NN, 256);
    head_out_kernel<<<dim3(MB64), blk, 0, stream>>>(bufC, Wl3, bl3, out, NN);
}

// Round 6
// 715.476 us; speedup vs baseline: 1.2650x; 1.0249x over previous
//
#include <hip/hip_runtime.h>
#include <hip/hip_fp16.h>

#define NN 50000
#define NE 800000
#define HH 128
#define SCAN_BS 512
#define SCAN_NB 98
#define LDK 40

typedef short bf16x8 __attribute__((ext_vector_type(8)));
typedef short short4v __attribute__((ext_vector_type(4)));
typedef short short2v __attribute__((ext_vector_type(2)));
typedef float f32x4  __attribute__((ext_vector_type(4)));

// ---------------------------------------------------------------------------
__device__ __forceinline__ void split_bf16(float x, short& h, short& l)
{
    unsigned u = __builtin_bit_cast(unsigned, x);
    unsigned r = u + 0x7FFFu + ((u >> 16) & 1u);
    h = (short)(r >> 16);
    float hf = __builtin_bit_cast(float, (unsigned)((r >> 16) << 16));
    float lf = x - hf;
    unsigned u2 = __builtin_bit_cast(unsigned, lf);
    unsigned r2 = u2 + 0x7FFFu + ((u2 >> 16) & 1u);
    l = (short)(r2 >> 16);
}

// ---------------------------------------------------------------------------
// One-time pre-split of weights into transposed hi|lo bf16: Wt[n][hi K | lo K].
// Thread handles 4 consecutive k for one n -> contiguous dst writes.
// ---------------------------------------------------------------------------
__global__ __launch_bounds__(256)
void presplit_w(const float* __restrict__ s0,  const float* __restrict__ s1,
                const float* __restrict__ s2,  const float* __restrict__ s3,
                const float* __restrict__ s4,  const float* __restrict__ s5,
                const float* __restrict__ s6,  const float* __restrict__ s7,
                const float* __restrict__ s8,  const float* __restrict__ s9,
                const float* __restrict__ s10, const float* __restrict__ s11,
                const float* __restrict__ s12, const float* __restrict__ s13,
                const float* __restrict__ s14, short* __restrict__ wps)
{
    const float* srcs[15] = {s0,s1,s2,s3,s4,s5,s6,s7,s8,s9,s10,s11,s12,s13,s14};
    const int Ks[15]   = {64,128,128,128,128,128,128,128,128,128,128,128,128,128,256};
    const int logKs[15]= { 6,  7,  7,  7,  7,  7,  7,  7,  7,  7,  7,  7,  7,  7,  8};
    const int Ns[15]   = {128,128,128,128,128,128,128,128,128,128,128,128,128,256,128};
    const int off[15]  = {0,16384,49152,81920,114688,147456,180224,212992,245760,
                          278528,311296,344064,376832,409600,475136};

    const int mi = blockIdx.y;
    const float* src = srcs[mi];
    const int K = Ks[mi], logK = logKs[mi], N = Ns[mi];
    short* dst = wps + off[mi];
    const int tot = K * N;
    const int base = (blockIdx.x * 256 + threadIdx.x) * 4;   // index in (n,k) order
    if (base >= tot) return;
    const int n = base >> logK;
    const int k = base & (K - 1);
#pragma unroll
    for (int x = 0; x < 4; ++x) {
        short h, l; split_bf16(src[(size_t)(k + x) * N + n], h, l);
        dst[(size_t)n * 2 * K + k + x] = h;
        dst[(size_t)n * 2 * K + K + k + x] = l;
    }
}

// ---------------------------------------------------------------------------
// One-time pre-split of G [N][64] fp32 -> Gps [N][hi 64 | lo 64]
// ---------------------------------------------------------------------------
__global__ __launch_bounds__(256)
void presplit_g(const float* __restrict__ G, short* __restrict__ Gps)
{
    const int i = (blockIdx.x * 256 + threadIdx.x) * 4;
    if (i >= NN * 64) return;
    const int r = i >> 6, c = i & 63;
    const float4 v = *reinterpret_cast<const float4*>(G + i);
    short4v hv, lv;
    { short h,l; split_bf16(v.x,h,l); hv[0]=h; lv[0]=l; }
    { short h,l; split_bf16(v.y,h,l); hv[1]=h; lv[1]=l; }
    { short h,l; split_bf16(v.z,h,l); hv[2]=h; lv[2]=l; }
    { short h,l; split_bf16(v.w,h,l); hv[3]=h; lv[3]=l; }
    *reinterpret_cast<short4v*>(&Gps[(size_t)r * 128 + c])      = hv;
    *reinterpret_cast<short4v*>(&Gps[(size_t)r * 128 + 64 + c]) = lv;
}

// ---------------------------------------------------------------------------
// Shared GEMM core: acc += A(128 rows, K) @ B(128 cols from Bps rows, K)
// A/B pre-split [row][hi K | lo K]. Pure-copy staging, 3-term bf16 MFMA.
// ---------------------------------------------------------------------------
__device__ __forceinline__ void gemm_core(
    const short* __restrict__ Aps, const int K,
    const short* __restrict__ Bps,
    const int M, const int m0, f32x4 (&acc)[4][4])
{
    __shared__ short Ah[128 * LDK], Al[128 * LDK];
    __shared__ short Bh[128 * LDK], Bl[128 * LDK];

    const int t    = threadIdx.x;
    const int lane = t & 63;
    const int wr   = (t >> 6) >> 1, wc = (t >> 6) & 1;
    const int fr   = lane & 15, fg = lane >> 4;
    const int r    = t >> 1;
    const int kh   = (t & 1) << 4;
    const int K2   = K * 2;

    for (int k0 = 0; k0 < K; k0 += 32) {
        {
            const int gm = m0 + r;
            bf16x8 h0 = {0,0,0,0,0,0,0,0}, h1 = h0, l0 = h0, l1 = h0;
            if (gm < M) {
                const short* p = Aps + (size_t)gm * K2 + k0 + kh;
                h0 = *reinterpret_cast<const bf16x8*>(p);
                h1 = *reinterpret_cast<const bf16x8*>(p + 8);
                l0 = *reinterpret_cast<const bf16x8*>(p + K);
                l1 = *reinterpret_cast<const bf16x8*>(p + K + 8);
            }
            *reinterpret_cast<bf16x8*>(&Ah[r * LDK + kh])     = h0;
            *reinterpret_cast<bf16x8*>(&Ah[r * LDK + kh + 8]) = h1;
            *reinterpret_cast<bf16x8*>(&Al[r * LDK + kh])     = l0;
            *reinterpret_cast<bf16x8*>(&Al[r * LDK + kh + 8]) = l1;
        }
        {
            const short* p = Bps + (size_t)r * K2 + k0 + kh;
            const bf16x8 h0 = *reinterpret_cast<const bf16x8*>(p);
            const bf16x8 h1 = *reinterpret_cast<const bf16x8*>(p + 8);
            const bf16x8 l0 = *reinterpret_cast<const bf16x8*>(p + K);
            const bf16x8 l1 = *reinterpret_cast<const bf16x8*>(p + K + 8);
            *reinterpret_cast<bf16x8*>(&Bh[r * LDK + kh])     = h0;
            *reinterpret_cast<bf16x8*>(&Bh[r * LDK + kh + 8]) = h1;
            *reinterpret_cast<bf16x8*>(&Bl[r * LDK + kh])     = l0;
            *reinterpret_cast<bf16x8*>(&Bl[r * LDK + kh + 8]) = l1;
        }
        __syncthreads();

        bf16x8 ah[4], al[4], bh[4], bl[4];
#pragma unroll
        for (int i = 0; i < 4; ++i) {
            const int m = wr * 64 + i * 16 + fr;
            ah[i] = *reinterpret_cast<const bf16x8*>(&Ah[m * LDK + fg * 8]);
            al[i] = *reinterpret_cast<const bf16x8*>(&Al[m * LDK + fg * 8]);
        }
#pragma unroll
        for (int j = 0; j < 4; ++j) {
            const int n = wc * 64 + j * 16 + fr;
            bh[j] = *reinterpret_cast<const bf16x8*>(&Bh[n * LDK + fg * 8]);
            bl[j] = *reinterpret_cast<const bf16x8*>(&Bl[n * LDK + fg * 8]);
        }
#pragma unroll
        for (int i = 0; i < 4; ++i)
#pragma unroll
            for (int j = 0; j < 4; ++j) {
                f32x4 a = acc[i][j];
                a = __builtin_amdgcn_mfma_f32_16x16x32_bf16(ah[i], bh[j], a, 0, 0, 0);
                a = __builtin_amdgcn_mfma_f32_16x16x32_bf16(ah[i], bl[j], a, 0, 0, 0);
                a = __builtin_amdgcn_mfma_f32_16x16x32_bf16(al[i], bh[j], a, 0, 0, 0);
                acc[i][j] = a;
            }
        __syncthreads();
    }
}

// ---------------------------------------------------------------------------
// GEMM -> pre-split activation output [m][hi Kout | lo Kout]; optional colsum.
// ---------------------------------------------------------------------------
template<bool RELU, bool COLSUM>
__global__ __launch_bounds__(256)
void gemm_ps(const short* __restrict__ Aps, int K,
             const short* __restrict__ Bps,
             const float* __restrict__ bias,
             short* __restrict__ outps, int Kout,
             float* __restrict__ gsum, int M)
{
    f32x4 acc[4][4] = {};
    const int m0 = blockIdx.y << 7;
    const int n0 = blockIdx.x << 7;
    gemm_core(Aps, K, Bps + (size_t)n0 * 2 * K, M, m0, acc);

    const int t = threadIdx.x, lane = t & 63;
    const int wr = (t >> 6) >> 1, wc = (t >> 6) & 1;
    const int fr = lane & 15, fg = lane >> 4;
    const int ld = 2 * Kout;
#pragma unroll
    for (int j = 0; j < 4; ++j) {
        const int gn = n0 + wc * 64 + j * 16 + fr;
        const float bv = bias[gn];
        float csum = 0.f;
#pragma unroll
        for (int i = 0; i < 4; ++i) {
            const int mbase = m0 + wr * 64 + i * 16 + fg * 4;
#pragma unroll
            for (int rr = 0; rr < 4; ++rr) {
                const int gm = mbase + rr;
                if (gm < M) {
                    float v = acc[i][j][rr] + bv;
                    if (RELU) v = fmaxf(v, 0.f);
                    if (COLSUM) csum += v;
                    short h, l; split_bf16(v, h, l);
                    outps[(size_t)gm * ld + gn] = h;
                    outps[(size_t)gm * ld + Kout + gn] = l;
                }
            }
        }
        if (COLSUM) {
            csum += __shfl_xor(csum, 16);
            csum += __shfl_xor(csum, 32);
            if (fg == 0) atomicAdd(&gsum[gn], csum);
        }
    }
}

// ---------------------------------------------------------------------------
// Fused k|s|q|v GEMM: blockIdx.x picks weight set; all outputs fp16 [m][512].
// ---------------------------------------------------------------------------
__global__ __launch_bounds__(256)
void gemm_kqvs(const short* __restrict__ Aps,
               const short* __restrict__ B0, const short* __restrict__ B1,
               const short* __restrict__ B2, const short* __restrict__ B3,
               const float* __restrict__ b0, const float* __restrict__ b1,
               const float* __restrict__ b2, const float* __restrict__ b3,
               __half* __restrict__ kqv, int M)
{
    const int nb = blockIdx.x;
    const short* Bt = (nb == 0) ? B0 : (nb == 1) ? B1 : (nb == 2) ? B2 : B3;
    const float* bt = (nb == 0) ? b0 : (nb == 1) ? b1 : (nb == 2) ? b2 : b3;

    f32x4 acc[4][4] = {};
    const int m0 = blockIdx.y << 7;
    gemm_core(Aps, 128, Bt, M, m0, acc);

    const int t = threadIdx.x, lane = t & 63;
    const int wr = (t >> 6) >> 1, wc = (t >> 6) & 1;
    const int fr = lane & 15, fg = lane >> 4;
#pragma unroll
    for (int j = 0; j < 4; ++j) {
        const int gnl = wc * 64 + j * 16 + fr;
        const float bv = bt[gnl];
#pragma unroll
        for (int i = 0; i < 4; ++i) {
            const int mbase = m0 + wr * 64 + i * 16 + fg * 4;
#pragma unroll
            for (int rr = 0; rr < 4; ++rr) {
                const int gm = mbase + rr;
                if (gm < M)
                    kqv[(size_t)gm * 512 + nb * 128 + gnl] = __float2half(acc[i][j][rr] + bv);
            }
        }
    }
}

// ---------------------------------------------------------------------------
// Head: u2 = relu(u1 @ Wl2 + bl2); out = u2 . wl3 + bl3  (fused final dot)
// ---------------------------------------------------------------------------
__global__ __launch_bounds__(256)
void gemm_head(const short* __restrict__ Aps,   // u1ps, K=256
               const short* __restrict__ Bt,    // Wl2t
               const float* __restrict__ bl2,
               const float* __restrict__ wl3,
               const float* __restrict__ bl3,
               float* __restrict__ out, int M)
{
    __shared__ float psum[2][128];
    f32x4 acc[4][4] = {};
    const int m0 = blockIdx.y << 7;
    gemm_core(Aps, 256, Bt, M, m0, acc);

    const int t = threadIdx.x, lane = t & 63;
    const int wr = (t >> 6) >> 1, wc = (t >> 6) & 1;
    const int fr = lane & 15, fg = lane >> 4;

    float p[4][4] = {};
#pragma unroll
    for (int j = 0; j < 4; ++j) {
        const int gnl = wc * 64 + j * 16 + fr;
        const float bv = bl2[gnl];
        const float wv = wl3[gnl];
#pragma unroll
        for (int i = 0; i < 4; ++i)
#pragma unroll
            for (int rr = 0; rr < 4; ++rr)
                p[i][rr] += fmaxf(acc[i][j][rr] + bv, 0.f) * wv;
    }
#pragma unroll
    for (int i = 0; i < 4; ++i)
#pragma unroll
        for (int rr = 0; rr < 4; ++rr) {
            float s = p[i][rr];
            s += __shfl_xor(s, 1);
            s += __shfl_xor(s, 2);
            s += __shfl_xor(s, 4);
            s += __shfl_xor(s, 8);
            p[i][rr] = s;
        }
    if (fr == 0) {
#pragma unroll
        for (int i = 0; i < 4; ++i)
#pragma unroll
            for (int rr = 0; rr < 4; ++rr)
                psum[wc][wr * 64 + i * 16 + fg * 4 + rr] = p[i][rr];
    }
    __syncthreads();
    if (t < 128) {
        const int gm = m0 + t;
        if (gm < M) out[gm] = psum[0][t] + psum[1][t] + bl3[0];
    }
}

// ---------------------------------------------------------------------------
// CSR build
// ---------------------------------------------------------------------------
__global__ __launch_bounds__(256)
void hist_kernel(const int* __restrict__ ei, int* __restrict__ deg)
{
    const int e = blockIdx.x * 256 + threadIdx.x;
    if (e < NE) atomicAdd(&deg[ei[NE + e]], 1);
}

__global__ __launch_bounds__(SCAN_BS)
void scan1_kernel(const int* __restrict__ deg, int* __restrict__ incl,
                  int* __restrict__ bsum)
{
    __shared__ int sm[SCAN_BS];
    const int t = threadIdx.x;
    const int i = blockIdx.x * SCAN_BS + t;
    sm[t] = (i < NN) ? deg[i] : 0;
    __syncthreads();
    for (int d = 1; d < SCAN_BS; d <<= 1) {
        const int add = (t >= d) ? sm[t - d] : 0;
        __syncthreads();
        sm[t] += add;
        __syncthreads();
    }
    if (i < NN) incl[i] = sm[t];
    if (t == SCAN_BS - 1) bsum[blockIdx.x] = sm[t];
}

__global__ __launch_bounds__(128)
void scan2_kernel(int* __restrict__ bsum)
{
    __shared__ int sm[128];
    const int t = threadIdx.x;
    const int v = (t < SCAN_NB) ? bsum[t] : 0;
    sm[t] = v;
    __syncthreads();
    for (int d = 1; d < 128; d <<= 1) {
        const int add = (t >= d) ? sm[t - d] : 0;
        __syncthreads();
        sm[t] += add;
        __syncthreads();
    }
    if (t < SCAN_NB) bsum[t] = sm[t] - v;
}

__global__ __launch_bounds__(SCAN_BS)
void scan3_kernel(const int* __restrict__ incl, const int* __restrict__ deg,
                  const int* __restrict__ bsum, int* __restrict__ offs)
{
    const int t = threadIdx.x;
    const int i = blockIdx.x * SCAN_BS + t;
    if (i < NN) offs[i] = incl[i] - deg[i] + bsum[blockIdx.x];
    if (i == 0) offs[NN] = NE;
}

__global__ __launch_bounds__(256)
void scatter_kernel(const int* __restrict__ ei, const int* __restrict__ offs,
                    int* __restrict__ cur, int2* __restrict__ csr)
{
    const int e = blockIdx.x * 256 + threadIdx.x;
    if (e >= NE) return;
    const int d = ei[NE + e];
    const int p = offs[d] + atomicAdd(&cur[d], 1);
    csr[p] = make_int2(ei[e], e);
}

// ---------------------------------------------------------------------------
// Conv aggregation + skip + ReLU + split-store. One wave per dst node; lane
// handles channel pair {2l, 2l+1}. kqv [N][512] fp16 = [k|s|q|v].
// 2-edge unroll; We resident in 42 VGPRs (launch_bounds caps at 128).
// ---------------------------------------------------------------------------
__global__ __launch_bounds__(256, 4)
void conv_agg_kernel(const int* __restrict__ offs,
                     const int2* __restrict__ csr,
                     const float* __restrict__ ea,
                     const float* __restrict__ We,
                     const __half* __restrict__ kqv,
                     short* __restrict__ outps)
{
    const int t    = threadIdx.x;
    const int lane = t & 63;
    const int n    = blockIdx.x * 4 + (t >> 6);
    if (n >= NN) return;

    float2 w[21];
#pragma unroll
    for (int q = 0; q < 21; ++q)
        w[q] = *reinterpret_cast<const float2*>(&We[q * HH + 2 * lane]);

    const __half2* krow = reinterpret_cast<const __half2*>(kqv + (size_t)n * 512);
    const float2 kd = __half22float2(krow[lane]);

    const int j0 = offs[n], j1 = offs[n + 1];
    float acc0 = 0.f, acc1 = 0.f, acc2 = 0.f, acc3 = 0.f;

    int j = j0;
    for (; j + 1 < j1; j += 2) {
        const int2 seA = csr[j];
        const int2 seB = csr[j + 1];
        const int sA = __builtin_amdgcn_readfirstlane(seA.x);
        const int iA = __builtin_amdgcn_readfirstlane(seA.y);
        const int sB = __builtin_amdgcn_readfirstlane(seB.x);
        const int iB = __builtin_amdgcn_readfirstlane(seB.y);

        const __half2* rA = reinterpret_cast<const __half2*>(kqv + (size_t)sA * 512 + 256);
        const __half2* rB = reinterpret_cast<const __half2*>(kqv + (size_t)sB * 512 + 256);
        const __half2 qA = rA[lane], vA = rA[64 + lane];
        const __half2 qB = rB[lane], vB = rB[64 + lane];

        const float* avA = ea + (size_t)iA * 21;
        const float* avB = ea + (size_t)iB * 21;
        float e0A = 0.f, e1A = 0.f, e0B = 0.f, e1B = 0.f;
#pragma unroll
        for (int q = 0; q < 21; ++q) {
            const float aA = avA[q];
            const float aB = avB[q];
            e0A += aA * w[q].x;  e1A += aA * w[q].y;
            e0B += aB * w[q].x;  e1B += aB * w[q].y;
        }

        const float2 qfA = __half22float2(qA), vfA = __half22float2(vA);
        const float2 qfB = __half22float2(qB), vfB = __half22float2(vB);
        float g0 = kd.x + qfA.x + 2.f * e0A;
        float g1 = kd.y + qfA.y + 2.f * e1A;
        float g2 = kd.x + qfB.x + 2.f * e0B;
        float g3 = kd.y + qfB.y + 2.f * e1B;
        g0 = 1.f / (1.f + __expf(-g0));
        g1 = 1.f / (1.f + __expf(-g1));
        g2 = 1.f / (1.f + __expf(-g2));
        g3 = 1.f / (1.f + __expf(-g3));
        acc0 += g0 * (vfA.x + e0A);
        acc1 += g1 * (vfA.y + e1A);
        acc2 += g2 * (vfB.x + e0B);
        acc3 += g3 * (vfB.y + e1B);
    }
    if (j < j1) {
        const int2 se = csr[j];
        const int s    = __builtin_amdgcn_readfirstlane(se.x);
        const int eidx = __builtin_amdgcn_readfirstlane(se.y);
        const __half2* rp = reinterpret_cast<const __half2*>(kqv + (size_t)s * 512 + 256);
        const __half2 q2 = rp[lane], v2 = rp[64 + lane];
        const float* av = ea + (size_t)eidx * 21;
        float e0 = 0.f, e1 = 0.f;
#pragma unroll
        for (int q = 0; q < 21; ++q) {
            const float a = av[q];
            e0 += a * w[q].x;
            e1 += a * w[q].y;
        }
        const float2 qf = __half22float2(q2), vf = __half22float2(v2);
        float g0 = kd.x + qf.x + 2.f * e0;
        float g1 = kd.y + qf.y + 2.f * e1;
        g0 = 1.f / (1.f + __expf(-g0));
        g1 = 1.f / (1.f + __expf(-g1));
        acc0 += g0 * (vf.x + e0);
        acc1 += g1 * (vf.y + e1);
    }
    acc0 += acc2;
    acc1 += acc3;

    const float2 sd = __half22float2(krow[64 + lane]);
    const float r0 = fmaxf(acc0 + sd.x, 0.f);
    const float r1 = fmaxf(acc1 + sd.y, 0.f);
    short h0, l0, h1, l1;
    split_bf16(r0, h0, l0);
    split_bf16(r1, h1, l1);
    short2v hi; hi[0] = h0; hi[1] = h1;
    short2v lo; lo[0] = l0; lo[1] = l1;
    *reinterpret_cast<short2v*>(&outps[(size_t)n * 256 + 2 * lane])       = hi;
    *reinterpret_cast<short2v*>(&outps[(size_t)n * 256 + 128 + 2 * lane]) = lo;
}

// ---------------------------------------------------------------------------
__global__ __launch_bounds__(256)
void gvec_kernel(const float* __restrict__ gsum,
                 const float* __restrict__ Wl1,
                 const float* __restrict__ bl1,
                 float* __restrict__ gvec, float invM)
{
    const int j = threadIdx.x;
    float acc = bl1[j];
    for (int k = 0; k < 128; ++k)
        acc += (gsum[k] * invM) * Wl1[(size_t)(128 + k) * 256 + j];
    gvec[j] = acc;
}

// ---------------------------------------------------------------------------
extern "C" void kernel_launch(void* const* d_in, const int* in_sizes, int n_in,
                              void* d_out, int out_size, void* d_ws, size_t ws_size,
                              hipStream_t stream)
{
    const float* G   = (const float*)d_in[0];
    const int*   ei  = (const int*)  d_in[1];
    const float* ea  = (const float*)d_in[2];
    const float* We1 = (const float*)d_in[3];  const float* be1 = (const float*)d_in[4];
    const float* We2 = (const float*)d_in[5];  const float* be2 = (const float*)d_in[6];
    const float* We3 = (const float*)d_in[7];  const float* be3 = (const float*)d_in[8];
    const float* c1_Wk = (const float*)d_in[9];  const float* c1_bk = (const float*)d_in[10];
    const float* c1_Wq = (const float*)d_in[11]; const float* c1_bq = (const float*)d_in[12];
    const float* c1_Wv = (const float*)d_in[13]; const float* c1_bv = (const float*)d_in[14];
    const float* c1_We = (const float*)d_in[15];
    const float* c1_Ws = (const float*)d_in[16]; const float* c1_bs = (const float*)d_in[17];
    const float* c2_Wk = (const float*)d_in[18]; const float* c2_bk = (const float*)d_in[19];
    const float* c2_Wq = (const float*)d_in[20]; const float* c2_bq = (const float*)d_in[21];
    const float* c2_Wv = (const float*)d_in[22]; const float* c2_bv = (const float*)d_in[23];
    const float* c2_We = (const float*)d_in[24];
    const float* c2_Ws = (const float*)d_in[25]; const float* c2_bs = (const float*)d_in[26];
    const float* Wg1 = (const float*)d_in[27]; const float* bg1 = (const float*)d_in[28];
    const float* Wg2 = (const float*)d_in[29]; const float* bg2 = (const float*)d_in[30];
    const float* Wl1 = (const float*)d_in[31]; const float* bl1 = (const float*)d_in[32];
    const float* Wl2 = (const float*)d_in[33]; const float* bl2 = (const float*)d_in[34];
    const float* Wl3 = (const float*)d_in[35]; const float* bl3 = (const float*)d_in[36];

    float* out = (float*)d_out;

    // ---- workspace layout
    char* ws = (char*)d_ws;
    size_t off = 0;
    short*  Gps  = (short*) (ws + off); off += (size_t)NN * 128 * 2;   // 12.8 MB
    short*  wps  = (short*) (ws + off); off += 540672 * 2;             // 1.1 MB
    short*  hpsA = (short*) (ws + off); off += (size_t)NN * 256 * 2;   // 25.6 MB
    short*  hpsB = (short*) (ws + off); off += (size_t)NN * 256 * 2;   // 25.6 MB
    __half* kqv  = (__half*)(ws + off); off += (size_t)NN * 512 * 2;   // 51.2 MB (aliased as u1ps later)
    float*  gsum = (float*) (ws + off); off += 256 * 4;
    float*  gvec = (float*) (ws + off); off += 256 * 4;
    int*    deg  = (int*)   (ws + off); off += (size_t)NN * 4;
    int*    incl = (int*)   (ws + off); off += (size_t)NN * 4;
    int*    bsum = (int*)   (ws + off); off += 128 * 4;
    int*    offs = (int*)   (ws + off); off += (size_t)(NN + 2) * 4;
    int*    cur  = (int*)   (ws + off); off += (size_t)NN * 4;
    off = (off + 15) & ~(size_t)15;
    int2*   csr  = (int2*)  (ws + off); off += (size_t)NE * 8;
    short*  u1ps = (short*)kqv;   // reuse (dead after conv2)

    // pre-split weight offsets (shorts)
    const int O_We1 = 0,      O_We2 = 16384,  O_We3 = 49152;
    const int O_c1k = 81920,  O_c1s = 114688, O_c1q = 147456, O_c1v = 180224;
    const int O_c2k = 212992, O_c2s = 245760, O_c2q = 278528, O_c2v = 311296;
    const int O_Wg1 = 344064, O_Wg2 = 376832, O_Wl1 = 409600, O_Wl2 = 475136;

    const dim3 blk(256);
    const int  MT = (NN + 127) / 128;     // 391
    const dim3 g1(1, MT), g2(2, MT), g4(4, MT);
    const int  EB = (NE + 255) / 256;
    const int  AGGB = (NN + 3) / 4;

    // ---- one-time pre-splits
    presplit_w<<<dim3(32, 15), blk, 0, stream>>>(
        We1, We2, We3, c1_Wk, c1_Ws, c1_Wq, c1_Wv,
        c2_Wk, c2_Ws, c2_Wq, c2_Wv, Wg1, Wg2, Wl1, Wl2, wps);
    presplit_g<<<dim3((NN * 64 + 1023) / 1024), blk, 0, stream>>>(G, Gps);

    // ---- CSR build
    hipMemsetAsync(deg, 0, (size_t)NN * 4, stream);
    hipMemsetAsync(cur, 0, (size_t)NN * 4, stream);
    hipMemsetAsync(gsum, 0, 128 * 4, stream);
    hist_kernel<<<dim3(EB), blk, 0, stream>>>(ei, deg);
    scan1_kernel<<<dim3(SCAN_NB), dim3(SCAN_BS), 0, stream>>>(deg, incl, bsum);
    scan2_kernel<<<dim3(1), dim3(128), 0, stream>>>(bsum);
    scan3_kernel<<<dim3(SCAN_NB), dim3(SCAN_BS), 0, stream>>>(incl, deg, bsum, offs);
    scatter_kernel<<<dim3(EB), blk, 0, stream>>>(ei, offs, cur, csr);

    // ---- node-feature MLP (pre-split chain)
    gemm_ps<true, false><<<g1, blk, 0, stream>>>(Gps,  64,  wps + O_We1, be1, hpsA, 128, nullptr, NN);
    gemm_ps<true, false><<<g1, blk, 0, stream>>>(hpsA, 128, wps + O_We2, be2, hpsB, 128, nullptr, NN);
    gemm_ps<true, false><<<g1, blk, 0, stream>>>(hpsB, 128, wps + O_We3, be3, hpsA, 128, nullptr, NN);

    // ---- conv1
    gemm_kqvs<<<g4, blk, 0, stream>>>(hpsA,
        wps + O_c1k, wps + O_c1s, wps + O_c1q, wps + O_c1v,
        c1_bk, c1_bs, c1_bq, c1_bv, kqv, NN);
    conv_agg_kernel<<<dim3(AGGB), blk, 0, stream>>>(offs, csr, ea, c1_We, kqv, hpsB);

    // ---- conv2
    gemm_kqvs<<<g4, blk, 0, stream>>>(hpsB,
        wps + O_c2k, wps + O_c2s, wps + O_c2q, wps + O_c2v,
        c2_bk, c2_bs, c2_bq, c2_bv, kqv, NN);
    conv_agg_kernel<<<dim3(AGGB), blk, 0, stream>>>(offs, csr, ea, c2_We, kqv, hpsA);

    // ---- graph-level MLP (+ fused colsum in g2)
    gemm_ps<true,  false><<<g1, blk, 0, stream>>>(hpsA, 128, wps + O_Wg1, bg1, hpsB, 128, nullptr, NN);
    gemm_ps<false, true ><<<g1, blk, 0, stream>>>(hpsB, 128, wps + O_Wg2, bg2, hpsA, 128, gsum, NN);

    // ---- graph mean -> gvec
    gvec_kernel<<<dim3(1), dim3(256), 0, stream>>>(gsum, Wl1, bl1, gvec, 1.f / NN);

    // ---- head: u1 (N=256, bias=gvec), then fused u2+dot -> out
    gemm_ps<true, false><<<g2, blk, 0, stream>>>(hpsA, 128, wps + O_Wl1, gvec, u1ps, 256, nullptr, NN);
    gemm_head<<<g1, blk, 0, stream>>>(u1ps, wps + O_Wl2, bl2, Wl3, bl3, out, NN);
}

// Round 7
// 678.993 us; speedup vs baseline: 1.3330x; 1.0537x over previous
//
#include <hip/hip_runtime.h>
#include <hip/hip_fp16.h>

#define NN 50000
#define NE 800000
#define HH 128
#define SCAN_BS 512
#define SCAN_NB 98
#define LDK 40

typedef _Float16 half8 __attribute__((ext_vector_type(8)));
typedef float f32x4  __attribute__((ext_vector_type(4)));

// ---------------------------------------------------------------------------
// One-time pre-split of weights into transposed hi|lo fp16: Wt[n][hi K | lo K].
// ---------------------------------------------------------------------------
__global__ __launch_bounds__(256)
void presplit_w(const float* __restrict__ s0,  const float* __restrict__ s1,
                const float* __restrict__ s2,  const float* __restrict__ s3,
                const float* __restrict__ s4,  const float* __restrict__ s5,
                const float* __restrict__ s6,  const float* __restrict__ s7,
                const float* __restrict__ s8,  const float* __restrict__ s9,
                const float* __restrict__ s10, const float* __restrict__ s11,
                const float* __restrict__ s12, const float* __restrict__ s13,
                const float* __restrict__ s14, _Float16* __restrict__ wps)
{
    const float* srcs[15] = {s0,s1,s2,s3,s4,s5,s6,s7,s8,s9,s10,s11,s12,s13,s14};
    const int Ks[15]   = {64,128,128,128,128,128,128,128,128,128,128,128,128,128,256};
    const int logKs[15]= { 6,  7,  7,  7,  7,  7,  7,  7,  7,  7,  7,  7,  7,  7,  8};
    const int off[15]  = {0,16384,49152,81920,114688,147456,180224,212992,245760,
                          278528,311296,344064,376832,409600,475136};

    const int mi = blockIdx.y;
    const float* src = srcs[mi];
    const int K = Ks[mi], logK = logKs[mi];
    const int N = (mi == 13) ? 256 : 128;
    _Float16* dst = wps + off[mi];
    const int tot = K * N;
    const int base = (blockIdx.x * 256 + threadIdx.x) * 4;
    if (base >= tot) return;
    const int n = base >> logK;
    const int k = base & (K - 1);
#pragma unroll
    for (int x = 0; x < 4; ++x) {
        const float v = src[(size_t)(k + x) * N + n];
        const _Float16 h = (_Float16)v;
        const _Float16 l = (_Float16)(v - (float)h);
        dst[(size_t)n * 2 * K + k + x]     = h;
        dst[(size_t)n * 2 * K + K + k + x] = l;
    }
}

// ---------------------------------------------------------------------------
// One-time cast of G [N][64] fp32 -> fp16
// ---------------------------------------------------------------------------
__global__ __launch_bounds__(256)
void presplit_g(const float* __restrict__ G, _Float16* __restrict__ Gf)
{
    const int i = (blockIdx.x * 256 + threadIdx.x) * 4;
    if (i >= NN * 64) return;
    const float4 v = *reinterpret_cast<const float4*>(G + i);
    Gf[i]     = (_Float16)v.x;
    Gf[i + 1] = (_Float16)v.y;
    Gf[i + 2] = (_Float16)v.z;
    Gf[i + 3] = (_Float16)v.w;
}

// ---------------------------------------------------------------------------
// Shared GEMM core: acc += A(128 rows x K fp16) @ B(128 cols; Bps[n][hiK|loK])
// 2-term fp16 MFMA (A single, B hi+lo). Pure-copy staging.
// ---------------------------------------------------------------------------
__device__ __forceinline__ void gemm_core(
    const _Float16* __restrict__ Aps, const int K,
    const _Float16* __restrict__ Bps,
    const int M, const int m0, f32x4 (&acc)[4][4])
{
    __shared__ __attribute__((aligned(16))) _Float16 As[128 * LDK];
    __shared__ __attribute__((aligned(16))) _Float16 Bh[128 * LDK];
    __shared__ __attribute__((aligned(16))) _Float16 Bl[128 * LDK];

    const int t    = threadIdx.x;
    const int lane = t & 63;
    const int wr   = (t >> 6) >> 1, wc = (t >> 6) & 1;
    const int fr   = lane & 15, fg = lane >> 4;
    const int r    = t >> 1;
    const int kh   = (t & 1) << 4;
    const int K2   = K * 2;

    for (int k0 = 0; k0 < K; k0 += 32) {
        {
            const int gm = m0 + r;
            half8 v0 = {0,0,0,0,0,0,0,0}, v1 = v0;
            if (gm < M) {
                const _Float16* p = Aps + (size_t)gm * K + k0 + kh;
                v0 = *reinterpret_cast<const half8*>(p);
                v1 = *reinterpret_cast<const half8*>(p + 8);
            }
            *reinterpret_cast<half8*>(&As[r * LDK + kh])     = v0;
            *reinterpret_cast<half8*>(&As[r * LDK + kh + 8]) = v1;
        }
        {
            const _Float16* p = Bps + (size_t)r * K2 + k0 + kh;
            const half8 h0 = *reinterpret_cast<const half8*>(p);
            const half8 h1 = *reinterpret_cast<const half8*>(p + 8);
            const half8 l0 = *reinterpret_cast<const half8*>(p + K);
            const half8 l1 = *reinterpret_cast<const half8*>(p + K + 8);
            *reinterpret_cast<half8*>(&Bh[r * LDK + kh])     = h0;
            *reinterpret_cast<half8*>(&Bh[r * LDK + kh + 8]) = h1;
            *reinterpret_cast<half8*>(&Bl[r * LDK + kh])     = l0;
            *reinterpret_cast<half8*>(&Bl[r * LDK + kh + 8]) = l1;
        }
        __syncthreads();

        half8 a[4], bh[4], bl[4];
#pragma unroll
        for (int i = 0; i < 4; ++i) {
            const int m = wr * 64 + i * 16 + fr;
            a[i] = *reinterpret_cast<const half8*>(&As[m * LDK + fg * 8]);
        }
#pragma unroll
        for (int j = 0; j < 4; ++j) {
            const int n = wc * 64 + j * 16 + fr;
            bh[j] = *reinterpret_cast<const half8*>(&Bh[n * LDK + fg * 8]);
            bl[j] = *reinterpret_cast<const half8*>(&Bl[n * LDK + fg * 8]);
        }
#pragma unroll
        for (int i = 0; i < 4; ++i)
#pragma unroll
            for (int j = 0; j < 4; ++j) {
                f32x4 x = acc[i][j];
                x = __builtin_amdgcn_mfma_f32_16x16x32_f16(a[i], bh[j], x, 0, 0, 0);
                x = __builtin_amdgcn_mfma_f32_16x16x32_f16(a[i], bl[j], x, 0, 0, 0);
                acc[i][j] = x;
            }
        __syncthreads();
    }
}

// ---------------------------------------------------------------------------
// GEMM -> fp16 activation output [m][Kout]; optional fused colsum.
// ---------------------------------------------------------------------------
template<bool RELU, bool COLSUM>
__global__ __launch_bounds__(256)
void gemm_ps(const _Float16* __restrict__ Aps, int K,
             const _Float16* __restrict__ Bps,
             const float* __restrict__ bias,
             _Float16* __restrict__ outf, int Kout,
             float* __restrict__ gsum, int M)
{
    f32x4 acc[4][4] = {};
    const int m0 = blockIdx.y << 7;
    const int n0 = blockIdx.x << 7;
    gemm_core(Aps, K, Bps + (size_t)n0 * 2 * K, M, m0, acc);

    const int t = threadIdx.x, lane = t & 63;
    const int wr = (t >> 6) >> 1, wc = (t >> 6) & 1;
    const int fr = lane & 15, fg = lane >> 4;
#pragma unroll
    for (int j = 0; j < 4; ++j) {
        const int gn = n0 + wc * 64 + j * 16 + fr;
        const float bv = bias[gn];
        float csum = 0.f;
#pragma unroll
        for (int i = 0; i < 4; ++i) {
            const int mbase = m0 + wr * 64 + i * 16 + fg * 4;
#pragma unroll
            for (int rr = 0; rr < 4; ++rr) {
                const int gm = mbase + rr;
                if (gm < M) {
                    float v = acc[i][j][rr] + bv;
                    if (RELU) v = fmaxf(v, 0.f);
                    if (COLSUM) csum += v;
                    outf[(size_t)gm * Kout + gn] = (_Float16)v;
                }
            }
        }
        if (COLSUM) {
            csum += __shfl_xor(csum, 16);
            csum += __shfl_xor(csum, 32);
            if (fg == 0) atomicAdd(&gsum[gn], csum);
        }
    }
}

// ---------------------------------------------------------------------------
// Fused k|s|q|v GEMM: blockIdx.x picks weight set; output fp16 [m][512].
// ---------------------------------------------------------------------------
__global__ __launch_bounds__(256)
void gemm_kqvs(const _Float16* __restrict__ Aps,
               const _Float16* __restrict__ B0, const _Float16* __restrict__ B1,
               const _Float16* __restrict__ B2, const _Float16* __restrict__ B3,
               const float* __restrict__ b0, const float* __restrict__ b1,
               const float* __restrict__ b2, const float* __restrict__ b3,
               _Float16* __restrict__ kqv, int M)
{
    const int nb = blockIdx.x;
    const _Float16* Bt = (nb == 0) ? B0 : (nb == 1) ? B1 : (nb == 2) ? B2 : B3;
    const float*    bt = (nb == 0) ? b0 : (nb == 1) ? b1 : (nb == 2) ? b2 : b3;

    f32x4 acc[4][4] = {};
    const int m0 = blockIdx.y << 7;
    gemm_core(Aps, 128, Bt, M, m0, acc);

    const int t = threadIdx.x, lane = t & 63;
    const int wr = (t >> 6) >> 1, wc = (t >> 6) & 1;
    const int fr = lane & 15, fg = lane >> 4;
#pragma unroll
    for (int j = 0; j < 4; ++j) {
        const int gnl = wc * 64 + j * 16 + fr;
        const float bv = bt[gnl];
#pragma unroll
        for (int i = 0; i < 4; ++i) {
            const int mbase = m0 + wr * 64 + i * 16 + fg * 4;
#pragma unroll
            for (int rr = 0; rr < 4; ++rr) {
                const int gm = mbase + rr;
                if (gm < M)
                    kqv[(size_t)gm * 512 + nb * 128 + gnl] = (_Float16)(acc[i][j][rr] + bv);
            }
        }
    }
}

// ---------------------------------------------------------------------------
// Head: u2 = relu(u1 @ Wl2 + bl2); out = u2 . wl3 + bl3
// ---------------------------------------------------------------------------
__global__ __launch_bounds__(256)
void gemm_head(const _Float16* __restrict__ Aps,   // u1 fp16, K=256
               const _Float16* __restrict__ Bt,    // Wl2t
               const float* __restrict__ bl2,
               const float* __restrict__ wl3,
               const float* __restrict__ bl3,
               float* __restrict__ out, int M)
{
    __shared__ float psum[2][128];
    f32x4 acc[4][4] = {};
    const int m0 = blockIdx.y << 7;
    gemm_core(Aps, 256, Bt, M, m0, acc);

    const int t = threadIdx.x, lane = t & 63;
    const int wr = (t >> 6) >> 1, wc = (t >> 6) & 1;
    const int fr = lane & 15, fg = lane >> 4;

    float p[4][4] = {};
#pragma unroll
    for (int j = 0; j < 4; ++j) {
        const int gnl = wc * 64 + j * 16 + fr;
        const float bv = bl2[gnl];
        const float wv = wl3[gnl];
#pragma unroll
        for (int i = 0; i < 4; ++i)
#pragma unroll
            for (int rr = 0; rr < 4; ++rr)
                p[i][rr] += fmaxf(acc[i][j][rr] + bv, 0.f) * wv;
    }
#pragma unroll
    for (int i = 0; i < 4; ++i)
#pragma unroll
        for (int rr = 0; rr < 4; ++rr) {
            float s = p[i][rr];
            s += __shfl_xor(s, 1);
            s += __shfl_xor(s, 2);
            s += __shfl_xor(s, 4);
            s += __shfl_xor(s, 8);
            p[i][rr] = s;
        }
    if (fr == 0) {
#pragma unroll
        for (int i = 0; i < 4; ++i)
#pragma unroll
            for (int rr = 0; rr < 4; ++rr)
                psum[wc][wr * 64 + i * 16 + fg * 4 + rr] = p[i][rr];
    }
    __syncthreads();
    if (t < 128) {
        const int gm = m0 + t;
        if (gm < M) out[gm] = psum[0][t] + psum[1][t] + bl3[0];
    }
}

// ---------------------------------------------------------------------------
// CSR build
// ---------------------------------------------------------------------------
__global__ __launch_bounds__(256)
void hist_kernel(const int* __restrict__ ei, int* __restrict__ deg)
{
    const int e = blockIdx.x * 256 + threadIdx.x;
    if (e < NE) atomicAdd(&deg[ei[NE + e]], 1);
}

__global__ __launch_bounds__(SCAN_BS)
void scan1_kernel(const int* __restrict__ deg, int* __restrict__ incl,
                  int* __restrict__ bsum)
{
    __shared__ int sm[SCAN_BS];
    const int t = threadIdx.x;
    const int i = blockIdx.x * SCAN_BS + t;
    sm[t] = (i < NN) ? deg[i] : 0;
    __syncthreads();
    for (int d = 1; d < SCAN_BS; d <<= 1) {
        const int add = (t >= d) ? sm[t - d] : 0;
        __syncthreads();
        sm[t] += add;
        __syncthreads();
    }
    if (i < NN) incl[i] = sm[t];
    if (t == SCAN_BS - 1) bsum[blockIdx.x] = sm[t];
}

__global__ __launch_bounds__(128)
void scan2_kernel(int* __restrict__ bsum)
{
    __shared__ int sm[128];
    const int t = threadIdx.x;
    const int v = (t < SCAN_NB) ? bsum[t] : 0;
    sm[t] = v;
    __syncthreads();
    for (int d = 1; d < 128; d <<= 1) {
        const int add = (t >= d) ? sm[t - d] : 0;
        __syncthreads();
        sm[t] += add;
        __syncthreads();
    }
    if (t < SCAN_NB) bsum[t] = sm[t] - v;
}

__global__ __launch_bounds__(SCAN_BS)
void scan3_kernel(const int* __restrict__ incl, const int* __restrict__ deg,
                  const int* __restrict__ bsum, int* __restrict__ offs)
{
    const int t = threadIdx.x;
    const int i = blockIdx.x * SCAN_BS + t;
    if (i < NN) offs[i] = incl[i] - deg[i] + bsum[blockIdx.x];
    if (i == 0) offs[NN] = NE;
}

__global__ __launch_bounds__(256)
void scatter_kernel(const int* __restrict__ ei, const int* __restrict__ offs,
                    int* __restrict__ cur, int2* __restrict__ csr)
{
    const int e = blockIdx.x * 256 + threadIdx.x;
    if (e >= NE) return;
    const int d = ei[NE + e];
    const int p = offs[d] + atomicAdd(&cur[d], 1);
    csr[p] = make_int2(ei[e], e);
}

// ---------------------------------------------------------------------------
// Conv aggregation + skip + ReLU. One wave per dst node; lane = channels
// {2l, 2l+1}. kqv [N][512] fp16 = [k|s|q|v]. We forced into 42 VGPRs via
// opaque asm (compiler cannot rematerialize). Output fp16 [n][128].
// ---------------------------------------------------------------------------
__global__ __launch_bounds__(256, 6)
void conv_agg_kernel(const int* __restrict__ offs,
                     const int2* __restrict__ csr,
                     const float* __restrict__ ea,
                     const float* __restrict__ We,
                     const __half* __restrict__ kqv,
                     __half* __restrict__ outh)
{
    const int t    = threadIdx.x;
    const int lane = t & 63;
    const int n    = blockIdx.x * 4 + (t >> 6);
    if (n >= NN) return;

    float2 w[21];
#pragma unroll
    for (int q = 0; q < 21; ++q) {
        w[q] = *reinterpret_cast<const float2*>(&We[q * HH + 2 * lane]);
        asm volatile("" : "+v"(w[q].x), "+v"(w[q].y));   // pin in VGPRs
    }

    const __half2* krow = reinterpret_cast<const __half2*>(kqv + (size_t)n * 512);
    const float2 kd = __half22float2(krow[lane]);

    const int j0 = offs[n], j1 = offs[n + 1];
    float acc0 = 0.f, acc1 = 0.f;

    for (int j = j0; j < j1; ++j) {
        const int2 se   = csr[j];
        const int  s    = __builtin_amdgcn_readfirstlane(se.x);
        const int  eidx = __builtin_amdgcn_readfirstlane(se.y);

        const __half2* rp = reinterpret_cast<const __half2*>(kqv + (size_t)s * 512 + 256);
        const __half2 q2 = rp[lane];
        const __half2 v2 = rp[64 + lane];

        const float* av = ea + (size_t)eidx * 21;   // uniform -> s_load
        float e0 = 0.f, e1 = 0.f;
#pragma unroll
        for (int q = 0; q < 21; ++q) {
            const float a = av[q];
            e0 += a * w[q].x;
            e1 += a * w[q].y;
        }

        const float2 qf = __half22float2(q2);
        const float2 vf = __half22float2(v2);
        float g0 = kd.x + qf.x + 2.f * e0;
        float g1 = kd.y + qf.y + 2.f * e1;
        g0 = 1.f / (1.f + __expf(-g0));
        g1 = 1.f / (1.f + __expf(-g1));

        acc0 += g0 * (vf.x + e0);
        acc1 += g1 * (vf.y + e1);
    }

    const float2 sd = __half22float2(krow[64 + lane]);
    const float r0 = fmaxf(acc0 + sd.x, 0.f);
    const float r1 = fmaxf(acc1 + sd.y, 0.f);
    *reinterpret_cast<__half2*>(&outh[(size_t)n * HH + 2 * lane]) =
        __floats2half2_rn(r0, r1);
}

// ---------------------------------------------------------------------------
__global__ __launch_bounds__(256)
void gvec_kernel(const float* __restrict__ gsum,
                 const float* __restrict__ Wl1,
                 const float* __restrict__ bl1,
                 float* __restrict__ gvec, float invM)
{
    const int j = threadIdx.x;
    float acc = bl1[j];
    for (int k = 0; k < 128; ++k)
        acc += (gsum[k] * invM) * Wl1[(size_t)(128 + k) * 256 + j];
    gvec[j] = acc;
}

// ---------------------------------------------------------------------------
extern "C" void kernel_launch(void* const* d_in, const int* in_sizes, int n_in,
                              void* d_out, int out_size, void* d_ws, size_t ws_size,
                              hipStream_t stream)
{
    const float* G   = (const float*)d_in[0];
    const int*   ei  = (const int*)  d_in[1];
    const float* ea  = (const float*)d_in[2];
    const float* We1 = (const float*)d_in[3];  const float* be1 = (const float*)d_in[4];
    const float* We2 = (const float*)d_in[5];  const float* be2 = (const float*)d_in[6];
    const float* We3 = (const float*)d_in[7];  const float* be3 = (const float*)d_in[8];
    const float* c1_Wk = (const float*)d_in[9];  const float* c1_bk = (const float*)d_in[10];
    const float* c1_Wq = (const float*)d_in[11]; const float* c1_bq = (const float*)d_in[12];
    const float* c1_Wv = (const float*)d_in[13]; const float* c1_bv = (const float*)d_in[14];
    const float* c1_We = (const float*)d_in[15];
    const float* c1_Ws = (const float*)d_in[16]; const float* c1_bs = (const float*)d_in[17];
    const float* c2_Wk = (const float*)d_in[18]; const float* c2_bk = (const float*)d_in[19];
    const float* c2_Wq = (const float*)d_in[20]; const float* c2_bq = (const float*)d_in[21];
    const float* c2_Wv = (const float*)d_in[22]; const float* c2_bv = (const float*)d_in[23];
    const float* c2_We = (const float*)d_in[24];
    const float* c2_Ws = (const float*)d_in[25]; const float* c2_bs = (const float*)d_in[26];
    const float* Wg1 = (const float*)d_in[27]; const float* bg1 = (const float*)d_in[28];
    const float* Wg2 = (const float*)d_in[29]; const float* bg2 = (const float*)d_in[30];
    const float* Wl1 = (const float*)d_in[31]; const float* bl1 = (const float*)d_in[32];
    const float* Wl2 = (const float*)d_in[33]; const float* bl2 = (const float*)d_in[34];
    const float* Wl3 = (const float*)d_in[35]; const float* bl3 = (const float*)d_in[36];

    float* out = (float*)d_out;

    // ---- workspace layout
    char* ws = (char*)d_ws;
    size_t off = 0;
    _Float16* Gf   = (_Float16*)(ws + off); off += (size_t)NN * 64 * 2;    // 6.4 MB
    _Float16* wps  = (_Float16*)(ws + off); off += 540672 * 2;             // 1.1 MB
    _Float16* hA   = (_Float16*)(ws + off); off += (size_t)NN * 128 * 2;   // 12.8 MB
    _Float16* hB   = (_Float16*)(ws + off); off += (size_t)NN * 128 * 2;   // 12.8 MB
    _Float16* kqv  = (_Float16*)(ws + off); off += (size_t)NN * 512 * 2;   // 51.2 MB (alias u1)
    float*    gsum = (float*)   (ws + off); off += 256 * 4;
    float*    gvec = (float*)   (ws + off); off += 256 * 4;
    int*      deg  = (int*)     (ws + off); off += (size_t)NN * 4;
    int*      incl = (int*)     (ws + off); off += (size_t)NN * 4;
    int*      bsum = (int*)     (ws + off); off += 128 * 4;
    int*      offs = (int*)     (ws + off); off += (size_t)(NN + 2) * 4;
    int*      cur  = (int*)     (ws + off); off += (size_t)NN * 4;
    off = (off + 15) & ~(size_t)15;
    int2*     csr  = (int2*)    (ws + off); off += (size_t)NE * 8;
    _Float16* u1f  = kqv;   // reuse (dead after conv2)

    const int O_We1 = 0,      O_We2 = 16384,  O_We3 = 49152;
    const int O_c1k = 81920,  O_c1s = 114688, O_c1q = 147456, O_c1v = 180224;
    const int O_c2k = 212992, O_c2s = 245760, O_c2q = 278528, O_c2v = 311296;
    const int O_Wg1 = 344064, O_Wg2 = 376832, O_Wl1 = 409600, O_Wl2 = 475136;

    const dim3 blk(256);
    const int  MT = (NN + 127) / 128;     // 391
    const dim3 g1(1, MT), g2(2, MT), g4(4, MT);
    const int  EB = (NE + 255) / 256;
    const int  AGGB = (NN + 3) / 4;

    // ---- one-time pre-splits
    presplit_w<<<dim3(32, 15), blk, 0, stream>>>(
        We1, We2, We3, c1_Wk, c1_Ws, c1_Wq, c1_Wv,
        c2_Wk, c2_Ws, c2_Wq, c2_Wv, Wg1, Wg2, Wl1, Wl2, wps);
    presplit_g<<<dim3((NN * 64 + 1023) / 1024), blk, 0, stream>>>(G, Gf);

    // ---- CSR build
    hipMemsetAsync(deg, 0, (size_t)NN * 4, stream);
    hipMemsetAsync(cur, 0, (size_t)NN * 4, stream);
    hipMemsetAsync(gsum, 0, 128 * 4, stream);
    hist_kernel<<<dim3(EB), blk, 0, stream>>>(ei, deg);
    scan1_kernel<<<dim3(SCAN_NB), dim3(SCAN_BS), 0, stream>>>(deg, incl, bsum);
    scan2_kernel<<<dim3(1), dim3(128), 0, stream>>>(bsum);
    scan3_kernel<<<dim3(SCAN_NB), dim3(SCAN_BS), 0, stream>>>(incl, deg, bsum, offs);
    scatter_kernel<<<dim3(EB), blk, 0, stream>>>(ei, offs, cur, csr);

    // ---- node-feature MLP
    gemm_ps<true, false><<<g1, blk, 0, stream>>>(Gf, 64,  wps + O_We1, be1, hA, 128, nullptr, NN);
    gemm_ps<true, false><<<g1, blk, 0, stream>>>(hA, 128, wps + O_We2, be2, hB, 128, nullptr, NN);
    gemm_ps<true, false><<<g1, blk, 0, stream>>>(hB, 128, wps + O_We3, be3, hA, 128, nullptr, NN);

    // ---- conv1
    gemm_kqvs<<<g4, blk, 0, stream>>>(hA,
        wps + O_c1k, wps + O_c1s, wps + O_c1q, wps + O_c1v,
        c1_bk, c1_bs, c1_bq, c1_bv, kqv, NN);
    conv_agg_kernel<<<dim3(AGGB), blk, 0, stream>>>(offs, csr, ea, c1_We,
        (const __half*)kqv, (__half*)hB);

    // ---- conv2
    gemm_kqvs<<<g4, blk, 0, stream>>>(hB,
        wps + O_c2k, wps + O_c2s, wps + O_c2q, wps + O_c2v,
        c2_bk, c2_bs, c2_bq, c2_bv, kqv, NN);
    conv_agg_kernel<<<dim3(AGGB), blk, 0, stream>>>(offs, csr, ea, c2_We,
        (const __half*)kqv, (__half*)hA);

    // ---- graph-level MLP (+ fused colsum)
    gemm_ps<true,  false><<<g1, blk, 0, stream>>>(hA, 128, wps + O_Wg1, bg1, hB, 128, nullptr, NN);
    gemm_ps<false, true ><<<g1, blk, 0, stream>>>(hB, 128, wps + O_Wg2, bg2, hA, 128, gsum, NN);

    // ---- graph mean -> gvec
    gvec_kernel<<<dim3(1), dim3(256), 0, stream>>>(gsum, Wl1, bl1, gvec, 1.f / NN);

    // ---- head
    gemm_ps<true, false><<<g2, blk, 0, stream>>>(hA, 128, wps + O_Wl1, gvec, u1f, 256, nullptr, NN);
    gemm_head<<<g1, blk, 0, stream>>>(u1f, wps + O_Wl2, bl2, Wl3, bl3, out, NN);
}

// Round 8
// 659.930 us; speedup vs baseline: 1.3715x; 1.0289x over previous
//
#include <hip/hip_runtime.h>
#include <hip/hip_fp16.h>

#define NN 50000
#define NE 800000
#define HH 128
#define SCAN_BS 512
#define SCAN_NB 98
#define LDK 40

typedef _Float16 half8 __attribute__((ext_vector_type(8)));
typedef float f32x4  __attribute__((ext_vector_type(4)));

// ---------------------------------------------------------------------------
// One-time pre-split of weights into transposed hi|lo fp16: Wt[n][hi K | lo K].
// ---------------------------------------------------------------------------
__global__ __launch_bounds__(256)
void presplit_w(const float* __restrict__ s0,  const float* __restrict__ s1,
                const float* __restrict__ s2,  const float* __restrict__ s3,
                const float* __restrict__ s4,  const float* __restrict__ s5,
                const float* __restrict__ s6,  const float* __restrict__ s7,
                const float* __restrict__ s8,  const float* __restrict__ s9,
                const float* __restrict__ s10, const float* __restrict__ s11,
                const float* __restrict__ s12, const float* __restrict__ s13,
                const float* __restrict__ s14, _Float16* __restrict__ wps)
{
    const float* srcs[15] = {s0,s1,s2,s3,s4,s5,s6,s7,s8,s9,s10,s11,s12,s13,s14};
    const int Ks[15]   = {64,128,128,128,128,128,128,128,128,128,128,128,128,128,256};
    const int logKs[15]= { 6,  7,  7,  7,  7,  7,  7,  7,  7,  7,  7,  7,  7,  7,  8};
    const int off[15]  = {0,16384,49152,81920,114688,147456,180224,212992,245760,
                          278528,311296,344064,376832,409600,475136};

    const int mi = blockIdx.y;
    const float* src = srcs[mi];
    const int K = Ks[mi], logK = logKs[mi];
    const int N = (mi == 13) ? 256 : 128;
    _Float16* dst = wps + off[mi];
    const int tot = K * N;
    const int base = (blockIdx.x * 256 + threadIdx.x) * 4;
    if (base >= tot) return;
    const int n = base >> logK;
    const int k = base & (K - 1);
#pragma unroll
    for (int x = 0; x < 4; ++x) {
        const float v = src[(size_t)(k + x) * N + n];
        const _Float16 h = (_Float16)v;
        const _Float16 l = (_Float16)(v - (float)h);
        dst[(size_t)n * 2 * K + k + x]     = h;
        dst[(size_t)n * 2 * K + K + k + x] = l;
    }
}

// ---------------------------------------------------------------------------
// One-time cast of G [N][64] fp32 -> fp16
// ---------------------------------------------------------------------------
__global__ __launch_bounds__(256)
void presplit_g(const float* __restrict__ G, _Float16* __restrict__ Gf)
{
    const int i = (blockIdx.x * 256 + threadIdx.x) * 4;
    if (i >= NN * 64) return;
    const float4 v = *reinterpret_cast<const float4*>(G + i);
    Gf[i]     = (_Float16)v.x;
    Gf[i + 1] = (_Float16)v.y;
    Gf[i + 2] = (_Float16)v.z;
    Gf[i + 3] = (_Float16)v.w;
}

// ---------------------------------------------------------------------------
// Shared GEMM core (unchanged from R7): 2-term fp16 MFMA, pure-copy staging.
// ---------------------------------------------------------------------------
__device__ __forceinline__ void gemm_core(
    const _Float16* __restrict__ Aps, const int K,
    const _Float16* __restrict__ Bps,
    const int M, const int m0, f32x4 (&acc)[4][4])
{
    __shared__ __attribute__((aligned(16))) _Float16 As[128 * LDK];
    __shared__ __attribute__((aligned(16))) _Float16 Bh[128 * LDK];
    __shared__ __attribute__((aligned(16))) _Float16 Bl[128 * LDK];

    const int t    = threadIdx.x;
    const int lane = t & 63;
    const int wr   = (t >> 6) >> 1, wc = (t >> 6) & 1;
    const int fr   = lane & 15, fg = lane >> 4;
    const int r    = t >> 1;
    const int kh   = (t & 1) << 4;
    const int K2   = K * 2;

    for (int k0 = 0; k0 < K; k0 += 32) {
        {
            const int gm = m0 + r;
            half8 v0 = {0,0,0,0,0,0,0,0}, v1 = v0;
            if (gm < M) {
                const _Float16* p = Aps + (size_t)gm * K + k0 + kh;
                v0 = *reinterpret_cast<const half8*>(p);
                v1 = *reinterpret_cast<const half8*>(p + 8);
            }
            *reinterpret_cast<half8*>(&As[r * LDK + kh])     = v0;
            *reinterpret_cast<half8*>(&As[r * LDK + kh + 8]) = v1;
        }
        {
            const _Float16* p = Bps + (size_t)r * K2 + k0 + kh;
            const half8 h0 = *reinterpret_cast<const half8*>(p);
            const half8 h1 = *reinterpret_cast<const half8*>(p + 8);
            const half8 l0 = *reinterpret_cast<const half8*>(p + K);
            const half8 l1 = *reinterpret_cast<const half8*>(p + K + 8);
            *reinterpret_cast<half8*>(&Bh[r * LDK + kh])     = h0;
            *reinterpret_cast<half8*>(&Bh[r * LDK + kh + 8]) = h1;
            *reinterpret_cast<half8*>(&Bl[r * LDK + kh])     = l0;
            *reinterpret_cast<half8*>(&Bl[r * LDK + kh + 8]) = l1;
        }
        __syncthreads();

        half8 a[4], bh[4], bl[4];
#pragma unroll
        for (int i = 0; i < 4; ++i) {
            const int m = wr * 64 + i * 16 + fr;
            a[i] = *reinterpret_cast<const half8*>(&As[m * LDK + fg * 8]);
        }
#pragma unroll
        for (int j = 0; j < 4; ++j) {
            const int n = wc * 64 + j * 16 + fr;
            bh[j] = *reinterpret_cast<const half8*>(&Bh[n * LDK + fg * 8]);
            bl[j] = *reinterpret_cast<const half8*>(&Bl[n * LDK + fg * 8]);
        }
#pragma unroll
        for (int i = 0; i < 4; ++i)
#pragma unroll
            for (int j = 0; j < 4; ++j) {
                f32x4 x = acc[i][j];
                x = __builtin_amdgcn_mfma_f32_16x16x32_f16(a[i], bh[j], x, 0, 0, 0);
                x = __builtin_amdgcn_mfma_f32_16x16x32_f16(a[i], bl[j], x, 0, 0, 0);
                acc[i][j] = x;
            }
        __syncthreads();
    }
}

// ---------------------------------------------------------------------------
// GEMM -> fp16 activation output [m][Kout]; optional fused colsum.
// ---------------------------------------------------------------------------
template<bool RELU, bool COLSUM>
__global__ __launch_bounds__(256)
void gemm_ps(const _Float16* __restrict__ Aps, int K,
             const _Float16* __restrict__ Bps,
             const float* __restrict__ bias,
             _Float16* __restrict__ outf, int Kout,
             float* __restrict__ gsum, int M)
{
    f32x4 acc[4][4] = {};
    const int m0 = blockIdx.y << 7;
    const int n0 = blockIdx.x << 7;
    gemm_core(Aps, K, Bps + (size_t)n0 * 2 * K, M, m0, acc);

    const int t = threadIdx.x, lane = t & 63;
    const int wr = (t >> 6) >> 1, wc = (t >> 6) & 1;
    const int fr = lane & 15, fg = lane >> 4;
#pragma unroll
    for (int j = 0; j < 4; ++j) {
        const int gn = n0 + wc * 64 + j * 16 + fr;
        const float bv = bias[gn];
        float csum = 0.f;
#pragma unroll
        for (int i = 0; i < 4; ++i) {
            const int mbase = m0 + wr * 64 + i * 16 + fg * 4;
#pragma unroll
            for (int rr = 0; rr < 4; ++rr) {
                const int gm = mbase + rr;
                if (gm < M) {
                    float v = acc[i][j][rr] + bv;
                    if (RELU) v = fmaxf(v, 0.f);
                    if (COLSUM) csum += v;
                    outf[(size_t)gm * Kout + gn] = (_Float16)v;
                }
            }
        }
        if (COLSUM) {
            csum += __shfl_xor(csum, 16);
            csum += __shfl_xor(csum, 32);
            if (fg == 0) atomicAdd(&gsum[gn], csum);
        }
    }
}

// ---------------------------------------------------------------------------
// Fused k|s|q|v GEMM. Interleaved channel-pair outputs (fp16):
//   ksb[n][pair p] = {k2p, k2p+1, s2p, s2p+1}   (nb 0 -> +0/1, nb 1 -> +2/3)
//   qvb[n][pair p] = {q2p, q2p+1, v2p, v2p+1}   (nb 2 -> +0/1, nb 3 -> +2/3)
// ---------------------------------------------------------------------------
__global__ __launch_bounds__(256)
void gemm_kqvs(const _Float16* __restrict__ Aps,
               const _Float16* __restrict__ B0, const _Float16* __restrict__ B1,
               const _Float16* __restrict__ B2, const _Float16* __restrict__ B3,
               const float* __restrict__ b0, const float* __restrict__ b1,
               const float* __restrict__ b2, const float* __restrict__ b3,
               _Float16* __restrict__ ksb, _Float16* __restrict__ qvb, int M)
{
    const int nb = blockIdx.x;
    const _Float16* Bt = (nb == 0) ? B0 : (nb == 1) ? B1 : (nb == 2) ? B2 : B3;
    const float*    bt = (nb == 0) ? b0 : (nb == 1) ? b1 : (nb == 2) ? b2 : b3;
    _Float16* dst   = (nb < 2) ? ksb : qvb;
    const int  sub  = (nb & 1) * 2;            // k/q -> 0, s/v -> 2

    f32x4 acc[4][4] = {};
    const int m0 = blockIdx.y << 7;
    gemm_core(Aps, 128, Bt, M, m0, acc);

    const int t = threadIdx.x, lane = t & 63;
    const int wr = (t >> 6) >> 1, wc = (t >> 6) & 1;
    const int fr = lane & 15, fg = lane >> 4;
#pragma unroll
    for (int j = 0; j < 4; ++j) {
        const int gnl = wc * 64 + j * 16 + fr;                 // channel 0..127
        const int pos = ((gnl >> 1) << 2) + sub + (gnl & 1);   // interleaved idx
        const float bv = bt[gnl];
#pragma unroll
        for (int i = 0; i < 4; ++i) {
            const int mbase = m0 + wr * 64 + i * 16 + fg * 4;
#pragma unroll
            for (int rr = 0; rr < 4; ++rr) {
                const int gm = mbase + rr;
                if (gm < M)
                    dst[(size_t)gm * 256 + pos] = (_Float16)(acc[i][j][rr] + bv);
            }
        }
    }
}

// ---------------------------------------------------------------------------
// Head: u2 = relu(u1 @ Wl2 + bl2); out = u2 . wl3 + bl3
// ---------------------------------------------------------------------------
__global__ __launch_bounds__(256)
void gemm_head(const _Float16* __restrict__ Aps,
               const _Float16* __restrict__ Bt,
               const float* __restrict__ bl2,
               const float* __restrict__ wl3,
               const float* __restrict__ bl3,
               float* __restrict__ out, int M)
{
    __shared__ float psum[2][128];
    f32x4 acc[4][4] = {};
    const int m0 = blockIdx.y << 7;
    gemm_core(Aps, 256, Bt, M, m0, acc);

    const int t = threadIdx.x, lane = t & 63;
    const int wr = (t >> 6) >> 1, wc = (t >> 6) & 1;
    const int fr = lane & 15, fg = lane >> 4;

    float p[4][4] = {};
#pragma unroll
    for (int j = 0; j < 4; ++j) {
        const int gnl = wc * 64 + j * 16 + fr;
        const float bv = bl2[gnl];
        const float wv = wl3[gnl];
#pragma unroll
        for (int i = 0; i < 4; ++i)
#pragma unroll
            for (int rr = 0; rr < 4; ++rr)
                p[i][rr] += fmaxf(acc[i][j][rr] + bv, 0.f) * wv;
    }
#pragma unroll
    for (int i = 0; i < 4; ++i)
#pragma unroll
        for (int rr = 0; rr < 4; ++rr) {
            float s = p[i][rr];
            s += __shfl_xor(s, 1);
            s += __shfl_xor(s, 2);
            s += __shfl_xor(s, 4);
            s += __shfl_xor(s, 8);
            p[i][rr] = s;
        }
    if (fr == 0) {
#pragma unroll
        for (int i = 0; i < 4; ++i)
#pragma unroll
            for (int rr = 0; rr < 4; ++rr)
                psum[wc][wr * 64 + i * 16 + fg * 4 + rr] = p[i][rr];
    }
    __syncthreads();
    if (t < 128) {
        const int gm = m0 + t;
        if (gm < M) out[gm] = psum[0][t] + psum[1][t] + bl3[0];
    }
}

// ---------------------------------------------------------------------------
// CSR build
// ---------------------------------------------------------------------------
__global__ __launch_bounds__(256)
void hist_kernel(const int* __restrict__ ei, int* __restrict__ deg)
{
    const int e = blockIdx.x * 256 + threadIdx.x;
    if (e < NE) atomicAdd(&deg[ei[NE + e]], 1);
}

__global__ __launch_bounds__(SCAN_BS)
void scan1_kernel(const int* __restrict__ deg, int* __restrict__ incl,
                  int* __restrict__ bsum)
{
    __shared__ int sm[SCAN_BS];
    const int t = threadIdx.x;
    const int i = blockIdx.x * SCAN_BS + t;
    sm[t] = (i < NN) ? deg[i] : 0;
    __syncthreads();
    for (int d = 1; d < SCAN_BS; d <<= 1) {
        const int add = (t >= d) ? sm[t - d] : 0;
        __syncthreads();
        sm[t] += add;
        __syncthreads();
    }
    if (i < NN) incl[i] = sm[t];
    if (t == SCAN_BS - 1) bsum[blockIdx.x] = sm[t];
}

__global__ __launch_bounds__(128)
void scan2_kernel(int* __restrict__ bsum)
{
    __shared__ int sm[128];
    const int t = threadIdx.x;
    const int v = (t < SCAN_NB) ? bsum[t] : 0;
    sm[t] = v;
    __syncthreads();
    for (int d = 1; d < 128; d <<= 1) {
        const int add = (t >= d) ? sm[t - d] : 0;
        __syncthreads();
        sm[t] += add;
        __syncthreads();
    }
    if (t < SCAN_NB) bsum[t] = sm[t] - v;
}

__global__ __launch_bounds__(SCAN_BS)
void scan3_kernel(const int* __restrict__ incl, const int* __restrict__ deg,
                  const int* __restrict__ bsum, int* __restrict__ offs)
{
    const int t = threadIdx.x;
    const int i = blockIdx.x * SCAN_BS + t;
    if (i < NN) offs[i] = incl[i] - deg[i] + bsum[blockIdx.x];
    if (i == 0) offs[NN] = NE;
}

__global__ __launch_bounds__(256)
void scatter_kernel(const int* __restrict__ ei, const int* __restrict__ offs,
                    int* __restrict__ cur,
                    int* __restrict__ csr_src, int* __restrict__ csr_eid)
{
    const int e = blockIdx.x * 256 + threadIdx.x;
    if (e >= NE) return;
    const int d = ei[NE + e];
    const int p = offs[d] + atomicAdd(&cur[d], 1);
    csr_src[p] = ei[e];
    csr_eid[p] = e;
}

// ---------------------------------------------------------------------------
// Build CSR-ordered duplicated edge-attrs: ea2[j][q] = half2{ea[eid][q], same}
// ---------------------------------------------------------------------------
__global__ __launch_bounds__(256)
void build_ea2(const int* __restrict__ csr_eid, const float* __restrict__ ea,
               unsigned* __restrict__ ea2)
{
    const int j = blockIdx.x * 256 + threadIdx.x;
    if (j >= NE) return;
    const int eid = csr_eid[j];
    const float* src = ea + (size_t)eid * 21;
    unsigned* dst = ea2 + (size_t)j * 21;
#pragma unroll
    for (int q = 0; q < 21; ++q) {
        const __half2 h = __floats2half2_rn(src[q], src[q]);
        dst[q] = __builtin_bit_cast(unsigned, h);
    }
}

// ---------------------------------------------------------------------------
// Conv aggregation + skip + ReLU. One wave per dst node; lane = ch pair
// {2l, 2l+1}. We resident as 21 half2 VGPRs (fits under 64-reg cliff).
// ea2 = CSR-ordered dup'd attrs (uniform s_load stream, no eidx dependency).
// qvb gather = single dwordx2/edge. 4-edge batching for MLP.
// ---------------------------------------------------------------------------
__global__ __launch_bounds__(256, 8)
void conv_agg_kernel(const int* __restrict__ offs,
                     const int* __restrict__ csr_src,
                     const unsigned* __restrict__ ea2,
                     const float* __restrict__ We,
                     const _Float16* __restrict__ ksb,
                     const _Float16* __restrict__ qvb,
                     _Float16* __restrict__ outh)
{
    const int t    = threadIdx.x;
    const int lane = t & 63;
    const int n    = blockIdx.x * 4 + (t >> 6);
    if (n >= NN) return;

    // We column pair -> 21 half2 VGPRs
    __half2 w2[21];
#pragma unroll
    for (int q = 0; q < 21; ++q) {
        const float2 wq = *reinterpret_cast<const float2*>(&We[q * HH + 2 * lane]);
        w2[q] = __floats2half2_rn(wq.x, wq.y);
    }

    // k|s pairs: one dwordx2 per node
    const uint2 ks = *reinterpret_cast<const uint2*>(ksb + (size_t)n * 256 + lane * 4);
    const __half2 k2 = __builtin_bit_cast(__half2, ks.x);
    const __half2 s2 = __builtin_bit_cast(__half2, ks.y);
    const float kdx = __low2float(k2), kdy = __high2float(k2);

    const int j0 = __builtin_amdgcn_readfirstlane(offs[n]);
    const int j1 = __builtin_amdgcn_readfirstlane(offs[n + 1]);
    float acc0 = 0.f, acc1 = 0.f;

#define GATHER(S) (*reinterpret_cast<const uint2*>(qvb + (size_t)(S) * 256 + lane * 4))

#define EDGE(QV, J) { \
    const __half2* aa_ = reinterpret_cast<const __half2*>(ea2 + (size_t)(J) * 21); \
    __half2 e01_ = __float2half2_rn(0.f); \
    _Pragma("unroll") \
    for (int q_ = 0; q_ < 21; ++q_) e01_ = __hfma2(aa_[q_], w2[q_], e01_); \
    const float e0_ = __low2float(e01_), e1_ = __high2float(e01_); \
    const __half2 q2_ = __builtin_bit_cast(__half2, (QV).x); \
    const __half2 v2_ = __builtin_bit_cast(__half2, (QV).y); \
    float g0_ = kdx + __low2float(q2_) + 2.f * e0_; \
    float g1_ = kdy + __high2float(q2_) + 2.f * e1_; \
    g0_ = 1.f / (1.f + __expf(-g0_)); \
    g1_ = 1.f / (1.f + __expf(-g1_)); \
    acc0 += g0_ * (__low2float(v2_) + e0_); \
    acc1 += g1_ * (__high2float(v2_) + e1_); }

    int j = j0;
    for (; j + 4 <= j1; j += 4) {
        const int sa = csr_src[j],     sb = csr_src[j + 1];
        const int sc = csr_src[j + 2], sd = csr_src[j + 3];
        const uint2 qva = GATHER(sa);
        const uint2 qvb_ = GATHER(sb);
        const uint2 qvc = GATHER(sc);
        const uint2 qvd = GATHER(sd);
        EDGE(qva, j)
        EDGE(qvb_, j + 1)
        EDGE(qvc, j + 2)
        EDGE(qvd, j + 3)
    }
    for (; j < j1; ++j) {
        const int s_ = csr_src[j];
        const uint2 qv = GATHER(s_);
        EDGE(qv, j)
    }
#undef GATHER
#undef EDGE

    const float r0 = fmaxf(acc0 + __low2float(s2), 0.f);
    const float r1 = fmaxf(acc1 + __high2float(s2), 0.f);
    const __half2 res = __floats2half2_rn(r0, r1);
    *reinterpret_cast<__half2*>(outh + (size_t)n * HH + 2 * lane) = res;
}

// ---------------------------------------------------------------------------
__global__ __launch_bounds__(256)
void gvec_kernel(const float* __restrict__ gsum,
                 const float* __restrict__ Wl1,
                 const float* __restrict__ bl1,
                 float* __restrict__ gvec, float invM)
{
    const int j = threadIdx.x;
    float acc = bl1[j];
    for (int k = 0; k < 128; ++k)
        acc += (gsum[k] * invM) * Wl1[(size_t)(128 + k) * 256 + j];
    gvec[j] = acc;
}

// ---------------------------------------------------------------------------
extern "C" void kernel_launch(void* const* d_in, const int* in_sizes, int n_in,
                              void* d_out, int out_size, void* d_ws, size_t ws_size,
                              hipStream_t stream)
{
    const float* G   = (const float*)d_in[0];
    const int*   ei  = (const int*)  d_in[1];
    const float* ea  = (const float*)d_in[2];
    const float* We1 = (const float*)d_in[3];  const float* be1 = (const float*)d_in[4];
    const float* We2 = (const float*)d_in[5];  const float* be2 = (const float*)d_in[6];
    const float* We3 = (const float*)d_in[7];  const float* be3 = (const float*)d_in[8];
    const float* c1_Wk = (const float*)d_in[9];  const float* c1_bk = (const float*)d_in[10];
    const float* c1_Wq = (const float*)d_in[11]; const float* c1_bq = (const float*)d_in[12];
    const float* c1_Wv = (const float*)d_in[13]; const float* c1_bv = (const float*)d_in[14];
    const float* c1_We = (const float*)d_in[15];
    const float* c1_Ws = (const float*)d_in[16]; const float* c1_bs = (const float*)d_in[17];
    const float* c2_Wk = (const float*)d_in[18]; const float* c2_bk = (const float*)d_in[19];
    const float* c2_Wq = (const float*)d_in[20]; const float* c2_bq = (const float*)d_in[21];
    const float* c2_Wv = (const float*)d_in[22]; const float* c2_bv = (const float*)d_in[23];
    const float* c2_We = (const float*)d_in[24];
    const float* c2_Ws = (const float*)d_in[25]; const float* c2_bs = (const float*)d_in[26];
    const float* Wg1 = (const float*)d_in[27]; const float* bg1 = (const float*)d_in[28];
    const float* Wg2 = (const float*)d_in[29]; const float* bg2 = (const float*)d_in[30];
    const float* Wl1 = (const float*)d_in[31]; const float* bl1 = (const float*)d_in[32];
    const float* Wl2 = (const float*)d_in[33]; const float* bl2 = (const float*)d_in[34];
    const float* Wl3 = (const float*)d_in[35]; const float* bl3 = (const float*)d_in[36];

    float* out = (float*)d_out;

    // ---- workspace layout (~158 MB, under the 161 MB proven in R2)
    char* ws = (char*)d_ws;
    size_t off = 0;
    _Float16* Gf   = (_Float16*)(ws + off); off += (size_t)NN * 64 * 2;    // 6.4 MB
    _Float16* wps  = (_Float16*)(ws + off); off += 540672 * 2;             // 1.1 MB
    _Float16* hA   = (_Float16*)(ws + off); off += (size_t)NN * 128 * 2;   // 12.8 MB
    _Float16* hB   = (_Float16*)(ws + off); off += (size_t)NN * 128 * 2;   // 12.8 MB
    _Float16* ksb  = (_Float16*)(ws + off); off += (size_t)NN * 256 * 2;   // 25.6 MB
    _Float16* qvb  = (_Float16*)(ws + off); off += (size_t)NN * 256 * 2;   // 25.6 MB (alias u1)
    unsigned* ea2  = (unsigned*)(ws + off); off += (size_t)NE * 21 * 4;    // 67.2 MB
    float*    gsum = (float*)   (ws + off); off += 256 * 4;
    float*    gvec = (float*)   (ws + off); off += 256 * 4;
    int*      deg  = (int*)     (ws + off); off += (size_t)NN * 4;
    int*      incl = (int*)     (ws + off); off += (size_t)NN * 4;
    int*      bsum = (int*)     (ws + off); off += 128 * 4;
    int*      offs = (int*)     (ws + off); off += (size_t)(NN + 2) * 4;
    int*      cur  = (int*)     (ws + off); off += (size_t)NN * 4;
    int*      csr_src = (int*)  (ws + off); off += (size_t)NE * 4;         // 3.2 MB
    int*      csr_eid = (int*)  (ws + off); off += (size_t)NE * 4;         // 3.2 MB
    _Float16* u1f  = qvb;   // reuse (dead after conv2)

    const int O_We1 = 0,      O_We2 = 16384,  O_We3 = 49152;
    const int O_c1k = 81920,  O_c1s = 114688, O_c1q = 147456, O_c1v = 180224;
    const int O_c2k = 212992, O_c2s = 245760, O_c2q = 278528, O_c2v = 311296;
    const int O_Wg1 = 344064, O_Wg2 = 376832, O_Wl1 = 409600, O_Wl2 = 475136;

    const dim3 blk(256);
    const int  MT = (NN + 127) / 128;     // 391
    const dim3 g1(1, MT), g2(2, MT), g4(4, MT);
    const int  EB = (NE + 255) / 256;
    const int  AGGB = (NN + 3) / 4;

    // ---- one-time pre-splits
    presplit_w<<<dim3(32, 15), blk, 0, stream>>>(
        We1, We2, We3, c1_Wk, c1_Ws, c1_Wq, c1_Wv,
        c2_Wk, c2_Ws, c2_Wq, c2_Wv, Wg1, Wg2, Wl1, Wl2, wps);
    presplit_g<<<dim3((NN * 64 + 1023) / 1024), blk, 0, stream>>>(G, Gf);

    // ---- CSR build
    hipMemsetAsync(deg, 0, (size_t)NN * 4, stream);
    hipMemsetAsync(cur, 0, (size_t)NN * 4, stream);
    hipMemsetAsync(gsum, 0, 128 * 4, stream);
    hist_kernel<<<dim3(EB), blk, 0, stream>>>(ei, deg);
    scan1_kernel<<<dim3(SCAN_NB), dim3(SCAN_BS), 0, stream>>>(deg, incl, bsum);
    scan2_kernel<<<dim3(1), dim3(128), 0, stream>>>(bsum);
    scan3_kernel<<<dim3(SCAN_NB), dim3(SCAN_BS), 0, stream>>>(incl, deg, bsum, offs);
    scatter_kernel<<<dim3(EB), blk, 0, stream>>>(ei, offs, cur, csr_src, csr_eid);
    build_ea2<<<dim3(EB), blk, 0, stream>>>(csr_eid, ea, ea2);

    // ---- node-feature MLP
    gemm_ps<true, false><<<g1, blk, 0, stream>>>(Gf, 64,  wps + O_We1, be1, hA, 128, nullptr, NN);
    gemm_ps<true, false><<<g1, blk, 0, stream>>>(hA, 128, wps + O_We2, be2, hB, 128, nullptr, NN);
    gemm_ps<true, false><<<g1, blk, 0, stream>>>(hB, 128, wps + O_We3, be3, hA, 128, nullptr, NN);

    // ---- conv1
    gemm_kqvs<<<g4, blk, 0, stream>>>(hA,
        wps + O_c1k, wps + O_c1s, wps + O_c1q, wps + O_c1v,
        c1_bk, c1_bs, c1_bq, c1_bv, ksb, qvb, NN);
    conv_agg_kernel<<<dim3(AGGB), blk, 0, stream>>>(offs, csr_src, ea2, c1_We,
        ksb, qvb, hB);

    // ---- conv2
    gemm_kqvs<<<g4, blk, 0, stream>>>(hB,
        wps + O_c2k, wps + O_c2s, wps + O_c2q, wps + O_c2v,
        c2_bk, c2_bs, c2_bq, c2_bv, ksb, qvb, NN);
    conv_agg_kernel<<<dim3(AGGB), blk, 0, stream>>>(offs, csr_src, ea2, c2_We,
        ksb, qvb, hA);

    // ---- graph-level MLP (+ fused colsum)
    gemm_ps<true,  false><<<g1, blk, 0, stream>>>(hA, 128, wps + O_Wg1, bg1, hB, 128, nullptr, NN);
    gemm_ps<false, true ><<<g1, blk, 0, stream>>>(hB, 128, wps + O_Wg2, bg2, hA, 128, gsum, NN);

    // ---- graph mean -> gvec
    gvec_kernel<<<dim3(1), dim3(256), 0, stream>>>(gsum, Wl1, bl1, gvec, 1.f / NN);

    // ---- head
    gemm_ps<true, false><<<g2, blk, 0, stream>>>(hA, 128, wps + O_Wl1, gvec, u1f, 256, nullptr, NN);
    gemm_head<<<g1, blk, 0, stream>>>(u1f, wps + O_Wl2, bl2, Wl3, bl3, out, NN);
}

// Round 9
// 570.198 us; speedup vs baseline: 1.5874x; 1.1574x over previous
//
#include <hip/hip_runtime.h>
#include <hip/hip_fp16.h>

#define NN 50000
#define NE 800000
#define HH 128
#define SCAN_BS 512
#define SCAN_NB 98
#define LDK 40

typedef _Float16 half8 __attribute__((ext_vector_type(8)));
typedef float f32x4  __attribute__((ext_vector_type(4)));

// ---------------------------------------------------------------------------
// One-time transpose+cast of weights to fp16: Wt[n][K]
// ---------------------------------------------------------------------------
__global__ __launch_bounds__(256)
void presplit_w(const float* __restrict__ s0,  const float* __restrict__ s1,
                const float* __restrict__ s2,  const float* __restrict__ s3,
                const float* __restrict__ s4,  const float* __restrict__ s5,
                const float* __restrict__ s6,  const float* __restrict__ s7,
                const float* __restrict__ s8,  const float* __restrict__ s9,
                const float* __restrict__ s10, const float* __restrict__ s11,
                const float* __restrict__ s12, const float* __restrict__ s13,
                const float* __restrict__ s14, _Float16* __restrict__ wps)
{
    const float* srcs[15] = {s0,s1,s2,s3,s4,s5,s6,s7,s8,s9,s10,s11,s12,s13,s14};
    const int Ks[15]   = {64,128,128,128,128,128,128,128,128,128,128,128,128,128,256};
    const int logKs[15]= { 6,  7,  7,  7,  7,  7,  7,  7,  7,  7,  7,  7,  7,  7,  8};
    const int off[15]  = {0,8192,24576,40960,57344,73728,90112,106496,122880,
                          139264,155648,172032,188416,204800,237568};

    const int mi = blockIdx.y;
    const float* src = srcs[mi];
    const int K = Ks[mi], logK = logKs[mi];
    const int N = (mi == 13) ? 256 : 128;
    _Float16* dst = wps + off[mi];
    const int tot = K * N;
    const int base = (blockIdx.x * 256 + threadIdx.x) * 4;
    if (base >= tot) return;
    const int n = base >> logK;
    const int k = base & (K - 1);
#pragma unroll
    for (int x = 0; x < 4; ++x)
        dst[(size_t)n * K + k + x] = (_Float16)src[(size_t)(k + x) * N + n];
}

// ---------------------------------------------------------------------------
__global__ __launch_bounds__(256)
void presplit_g(const float* __restrict__ G, _Float16* __restrict__ Gf)
{
    const int i = (blockIdx.x * 256 + threadIdx.x) * 4;
    if (i >= NN * 64) return;
    const float4 v = *reinterpret_cast<const float4*>(G + i);
    Gf[i]     = (_Float16)v.x;
    Gf[i + 1] = (_Float16)v.y;
    Gf[i + 2] = (_Float16)v.z;
    Gf[i + 3] = (_Float16)v.w;
}

// ---------------------------------------------------------------------------
// GEMM core: 64-row x 128-col tile, BK=32, 4 waves (2x2 of 32x64).
// Single-term fp16 MFMA. A [m][K] fp16, Bt [n][K] fp16.
// ---------------------------------------------------------------------------
__device__ __forceinline__ void gemm_core(
    const _Float16* __restrict__ A, const int K,
    const _Float16* __restrict__ Bt,
    const int M, const int m0, f32x4 (&acc)[2][4])
{
    __shared__ __attribute__((aligned(16))) _Float16 As[64 * LDK];
    __shared__ __attribute__((aligned(16))) _Float16 Bs[128 * LDK];

    const int t    = threadIdx.x;
    const int lane = t & 63;
    const int wid  = t >> 6;
    const int wr   = wid >> 1, wc = wid & 1;
    const int fr   = lane & 15, fg = lane >> 4;
    const int ra   = t >> 2, ka = (t & 3) * 8;
    const int rb   = t >> 1, kb = (t & 1) * 16;

    for (int k0 = 0; k0 < K; k0 += 32) {
        {
            const int gm = m0 + ra;
            half8 v = {0,0,0,0,0,0,0,0};
            if (gm < M) v = *reinterpret_cast<const half8*>(A + (size_t)gm * K + k0 + ka);
            *reinterpret_cast<half8*>(&As[ra * LDK + ka]) = v;
        }
        {
            const _Float16* p = Bt + (size_t)rb * K + k0 + kb;
            const half8 v0 = *reinterpret_cast<const half8*>(p);
            const half8 v1 = *reinterpret_cast<const half8*>(p + 8);
            *reinterpret_cast<half8*>(&Bs[rb * LDK + kb])     = v0;
            *reinterpret_cast<half8*>(&Bs[rb * LDK + kb + 8]) = v1;
        }
        __syncthreads();

        half8 a[2], b[4];
#pragma unroll
        for (int i = 0; i < 2; ++i)
            a[i] = *reinterpret_cast<const half8*>(&As[(wr * 32 + i * 16 + fr) * LDK + fg * 8]);
#pragma unroll
        for (int j = 0; j < 4; ++j)
            b[j] = *reinterpret_cast<const half8*>(&Bs[(wc * 64 + j * 16 + fr) * LDK + fg * 8]);
#pragma unroll
        for (int i = 0; i < 2; ++i)
#pragma unroll
            for (int j = 0; j < 4; ++j)
                acc[i][j] = __builtin_amdgcn_mfma_f32_16x16x32_f16(a[i], b[j], acc[i][j], 0, 0, 0);
        __syncthreads();
    }
}

// ---------------------------------------------------------------------------
template<bool RELU, bool COLSUM>
__global__ __launch_bounds__(256)
void gemm_ps(const _Float16* __restrict__ Aps, int K,
             const _Float16* __restrict__ Bps,
             const float* __restrict__ bias,
             _Float16* __restrict__ outf, int Kout,
             float* __restrict__ gsum, int M)
{
    f32x4 acc[2][4] = {};
    const int m0 = blockIdx.y << 6;
    const int n0 = blockIdx.x << 7;
    gemm_core(Aps, K, Bps + (size_t)n0 * K, M, m0, acc);

    const int t = threadIdx.x, lane = t & 63;
    const int wr = (t >> 6) >> 1, wc = (t >> 6) & 1;
    const int fr = lane & 15, fg = lane >> 4;
#pragma unroll
    for (int j = 0; j < 4; ++j) {
        const int gn = n0 + wc * 64 + j * 16 + fr;
        const float bv = bias[gn];
        float csum = 0.f;
#pragma unroll
        for (int i = 0; i < 2; ++i) {
            const int mbase = m0 + wr * 32 + i * 16 + fg * 4;
#pragma unroll
            for (int rr = 0; rr < 4; ++rr) {
                const int gm = mbase + rr;
                if (gm < M) {
                    float v = acc[i][j][rr] + bv;
                    if (RELU) v = fmaxf(v, 0.f);
                    if (COLSUM) csum += v;
                    outf[(size_t)gm * Kout + gn] = (_Float16)v;
                }
            }
        }
        if (COLSUM) {
            csum += __shfl_xor(csum, 16);
            csum += __shfl_xor(csum, 32);
            if (fg == 0) atomicAdd(&gsum[gn], csum);
        }
    }
}

// ---------------------------------------------------------------------------
// Fused k|s|q|v GEMM, interleaved channel-pair outputs.
// ---------------------------------------------------------------------------
__global__ __launch_bounds__(256)
void gemm_kqvs(const _Float16* __restrict__ Aps,
               const _Float16* __restrict__ B0, const _Float16* __restrict__ B1,
               const _Float16* __restrict__ B2, const _Float16* __restrict__ B3,
               const float* __restrict__ b0, const float* __restrict__ b1,
               const float* __restrict__ b2, const float* __restrict__ b3,
               _Float16* __restrict__ ksb, _Float16* __restrict__ qvb, int M)
{
    const int nb = blockIdx.x;
    const _Float16* Bt = (nb == 0) ? B0 : (nb == 1) ? B1 : (nb == 2) ? B2 : B3;
    const float*    bt = (nb == 0) ? b0 : (nb == 1) ? b1 : (nb == 2) ? b2 : b3;
    _Float16* dst   = (nb < 2) ? ksb : qvb;
    const int  sub  = (nb & 1) * 2;

    f32x4 acc[2][4] = {};
    const int m0 = blockIdx.y << 6;
    gemm_core(Aps, 128, Bt, M, m0, acc);

    const int t = threadIdx.x, lane = t & 63;
    const int wr = (t >> 6) >> 1, wc = (t >> 6) & 1;
    const int fr = lane & 15, fg = lane >> 4;
#pragma unroll
    for (int j = 0; j < 4; ++j) {
        const int gnl = wc * 64 + j * 16 + fr;
        const int pos = ((gnl >> 1) << 2) + sub + (gnl & 1);
        const float bv = bt[gnl];
#pragma unroll
        for (int i = 0; i < 2; ++i) {
            const int mbase = m0 + wr * 32 + i * 16 + fg * 4;
#pragma unroll
            for (int rr = 0; rr < 4; ++rr) {
                const int gm = mbase + rr;
                if (gm < M)
                    dst[(size_t)gm * 256 + pos] = (_Float16)(acc[i][j][rr] + bv);
            }
        }
    }
}

// ---------------------------------------------------------------------------
__global__ __launch_bounds__(256)
void gemm_head(const _Float16* __restrict__ Aps,
               const _Float16* __restrict__ Bt,
               const float* __restrict__ bl2,
               const float* __restrict__ wl3,
               const float* __restrict__ bl3,
               float* __restrict__ out, int M)
{
    __shared__ float psum[2][64];
    f32x4 acc[2][4] = {};
    const int m0 = blockIdx.y << 6;
    gemm_core(Aps, 256, Bt, M, m0, acc);

    const int t = threadIdx.x, lane = t & 63;
    const int wr = (t >> 6) >> 1, wc = (t >> 6) & 1;
    const int fr = lane & 15, fg = lane >> 4;

    float p[2][4] = {};
#pragma unroll
    for (int j = 0; j < 4; ++j) {
        const int gnl = wc * 64 + j * 16 + fr;
        const float bv = bl2[gnl];
        const float wv = wl3[gnl];
#pragma unroll
        for (int i = 0; i < 2; ++i)
#pragma unroll
            for (int rr = 0; rr < 4; ++rr)
                p[i][rr] += fmaxf(acc[i][j][rr] + bv, 0.f) * wv;
    }
#pragma unroll
    for (int i = 0; i < 2; ++i)
#pragma unroll
        for (int rr = 0; rr < 4; ++rr) {
            float s = p[i][rr];
            s += __shfl_xor(s, 1);
            s += __shfl_xor(s, 2);
            s += __shfl_xor(s, 4);
            s += __shfl_xor(s, 8);
            p[i][rr] = s;
        }
    if (fr == 0) {
#pragma unroll
        for (int i = 0; i < 2; ++i)
#pragma unroll
            for (int rr = 0; rr < 4; ++rr)
                psum[wc][wr * 32 + i * 16 + fg * 4 + rr] = p[i][rr];
    }
    __syncthreads();
    if (t < 64) {
        const int gm = m0 + t;
        if (gm < M) out[gm] = psum[0][t] + psum[1][t] + bl3[0];
    }
}

// ---------------------------------------------------------------------------
// CSR build
// ---------------------------------------------------------------------------
__global__ __launch_bounds__(256)
void hist_kernel(const int* __restrict__ ei, int* __restrict__ deg)
{
    const int e = blockIdx.x * 256 + threadIdx.x;
    if (e < NE) atomicAdd(&deg[ei[NE + e]], 1);
}

__global__ __launch_bounds__(SCAN_BS)
void scan1_kernel(const int* __restrict__ deg, int* __restrict__ incl,
                  int* __restrict__ bsum)
{
    __shared__ int sm[SCAN_BS];
    const int t = threadIdx.x;
    const int i = blockIdx.x * SCAN_BS + t;
    sm[t] = (i < NN) ? deg[i] : 0;
    __syncthreads();
    for (int d = 1; d < SCAN_BS; d <<= 1) {
        const int add = (t >= d) ? sm[t - d] : 0;
        __syncthreads();
        sm[t] += add;
        __syncthreads();
    }
    if (i < NN) incl[i] = sm[t];
    if (t == SCAN_BS - 1) bsum[blockIdx.x] = sm[t];
}

__global__ __launch_bounds__(128)
void scan2_kernel(int* __restrict__ bsum)
{
    __shared__ int sm[128];
    const int t = threadIdx.x;
    const int v = (t < SCAN_NB) ? bsum[t] : 0;
    sm[t] = v;
    __syncthreads();
    for (int d = 1; d < 128; d <<= 1) {
        const int add = (t >= d) ? sm[t - d] : 0;
        __syncthreads();
        sm[t] += add;
        __syncthreads();
    }
    if (t < SCAN_NB) bsum[t] = sm[t] - v;
}

__global__ __launch_bounds__(SCAN_BS)
void scan3_kernel(const int* __restrict__ incl, const int* __restrict__ deg,
                  const int* __restrict__ bsum, int* __restrict__ offs)
{
    const int t = threadIdx.x;
    const int i = blockIdx.x * SCAN_BS + t;
    if (i < NN) offs[i] = incl[i] - deg[i] + bsum[blockIdx.x];
    if (i == 0) offs[NN] = NE;
}

__global__ __launch_bounds__(256)
void scatter_kernel(const int* __restrict__ ei, const int* __restrict__ offs,
                    int* __restrict__ cur,
                    int* __restrict__ csr_src, int* __restrict__ csr_eid)
{
    const int e = blockIdx.x * 256 + threadIdx.x;
    if (e >= NE) return;
    const int d = ei[NE + e];
    const int p = offs[d] + atomicAdd(&cur[d], 1);
    csr_src[p] = ei[e];
    csr_eid[p] = e;
}

__global__ __launch_bounds__(256)
void build_ea2(const int* __restrict__ csr_eid, const float* __restrict__ ea,
               unsigned* __restrict__ ea2)
{
    const int j = blockIdx.x * 256 + threadIdx.x;
    if (j >= NE) return;
    const int eid = csr_eid[j];
    const float* src = ea + (size_t)eid * 21;
    unsigned* dst = ea2 + (size_t)j * 21;
#pragma unroll
    for (int q = 0; q < 21; ++q) {
        const __half2 h = __floats2half2_rn(src[q], src[q]);
        dst[q] = __builtin_bit_cast(unsigned, h);
    }
}

// ---------------------------------------------------------------------------
// Conv aggregation + skip + ReLU. Wave/node; lane = ch pair {2l,2l+1}.
// Packed fp16 gate path (h2exp/h2rcp saturation gives exact 0/1 gates).
// ---------------------------------------------------------------------------
__global__ __launch_bounds__(256, 8)
void conv_agg_kernel(const int* __restrict__ offs,
                     const int* __restrict__ csr_src,
                     const unsigned* __restrict__ ea2,
                     const float* __restrict__ We,
                     const _Float16* __restrict__ ksb,
                     const _Float16* __restrict__ qvb,
                     _Float16* __restrict__ outh)
{
    const int t    = threadIdx.x;
    const int lane = t & 63;
    const int n    = blockIdx.x * 4 + (t >> 6);
    if (n >= NN) return;

    __half2 w2[21];
#pragma unroll
    for (int q = 0; q < 21; ++q) {
        const float2 wq = *reinterpret_cast<const float2*>(&We[q * HH + 2 * lane]);
        w2[q] = __floats2half2_rn(wq.x, wq.y);
    }

    const uint2 ks = *reinterpret_cast<const uint2*>(ksb + (size_t)n * 256 + lane * 4);
    const __half2 k2 = __builtin_bit_cast(__half2, ks.x);
    const __half2 s2 = __builtin_bit_cast(__half2, ks.y);
    const __half2 one2 = __float2half2_rn(1.f);
    const __half2 two2 = __float2half2_rn(2.f);

    const int j0 = __builtin_amdgcn_readfirstlane(offs[n]);
    const int j1 = __builtin_amdgcn_readfirstlane(offs[n + 1]);
    float acc0 = 0.f, acc1 = 0.f;

#define GATHER(S) (*reinterpret_cast<const uint2*>(qvb + (size_t)(S) * 256 + lane * 4))

#define EDGE(QV, J) { \
    const __half2* aa_ = reinterpret_cast<const __half2*>(ea2 + (size_t)(J) * 21); \
    __half2 e01_ = __float2half2_rn(0.f); \
    _Pragma("unroll") \
    for (int q_ = 0; q_ < 21; ++q_) e01_ = __hfma2(aa_[q_], w2[q_], e01_); \
    const __half2 q2_ = __builtin_bit_cast(__half2, (QV).x); \
    const __half2 v2_ = __builtin_bit_cast(__half2, (QV).y); \
    const __half2 g_  = __hadd2(k2, __hfma2(two2, e01_, q2_)); \
    const __half2 ex_ = h2exp(__hneg2(g_)); \
    const __half2 gate_ = h2rcp(__hadd2(one2, ex_)); \
    const __half2 m_ = __hmul2(gate_, __hadd2(v2_, e01_)); \
    acc0 += __low2float(m_); \
    acc1 += __high2float(m_); }

    int j = j0;
    for (; j + 4 <= j1; j += 4) {
        const int sa = csr_src[j],     sb = csr_src[j + 1];
        const int sc = csr_src[j + 2], sd = csr_src[j + 3];
        const uint2 qva = GATHER(sa);
        const uint2 qvb_ = GATHER(sb);
        const uint2 qvc = GATHER(sc);
        const uint2 qvd = GATHER(sd);
        EDGE(qva, j)
        EDGE(qvb_, j + 1)
        EDGE(qvc, j + 2)
        EDGE(qvd, j + 3)
    }
    for (; j < j1; ++j) {
        const int s_ = csr_src[j];
        const uint2 qv = GATHER(s_);
        EDGE(qv, j)
    }
#undef GATHER
#undef EDGE

    const float r0 = fmaxf(acc0 + __low2float(s2), 0.f);
    const float r1 = fmaxf(acc1 + __high2float(s2), 0.f);
    const __half2 res = __floats2half2_rn(r0, r1);
    *reinterpret_cast<__half2*>(outh + (size_t)n * HH + 2 * lane) = res;
}

// ---------------------------------------------------------------------------
__global__ __launch_bounds__(256)
void gvec_kernel(const float* __restrict__ gsum,
                 const float* __restrict__ Wl1,
                 const float* __restrict__ bl1,
                 float* __restrict__ gvec, float invM)
{
    const int j = threadIdx.x;
    float acc = bl1[j];
    for (int k = 0; k < 128; ++k)
        acc += (gsum[k] * invM) * Wl1[(size_t)(128 + k) * 256 + j];
    gvec[j] = acc;
}

// ---------------------------------------------------------------------------
extern "C" void kernel_launch(void* const* d_in, const int* in_sizes, int n_in,
                              void* d_out, int out_size, void* d_ws, size_t ws_size,
                              hipStream_t stream)
{
    const float* G   = (const float*)d_in[0];
    const int*   ei  = (const int*)  d_in[1];
    const float* ea  = (const float*)d_in[2];
    const float* We1 = (const float*)d_in[3];  const float* be1 = (const float*)d_in[4];
    const float* We2 = (const float*)d_in[5];  const float* be2 = (const float*)d_in[6];
    const float* We3 = (const float*)d_in[7];  const float* be3 = (const float*)d_in[8];
    const float* c1_Wk = (const float*)d_in[9];  const float* c1_bk = (const float*)d_in[10];
    const float* c1_Wq = (const float*)d_in[11]; const float* c1_bq = (const float*)d_in[12];
    const float* c1_Wv = (const float*)d_in[13]; const float* c1_bv = (const float*)d_in[14];
    const float* c1_We = (const float*)d_in[15];
    const float* c1_Ws = (const float*)d_in[16]; const float* c1_bs = (const float*)d_in[17];
    const float* c2_Wk = (const float*)d_in[18]; const float* c2_bk = (const float*)d_in[19];
    const float* c2_Wq = (const float*)d_in[20]; const float* c2_bq = (const float*)d_in[21];
    const float* c2_Wv = (const float*)d_in[22]; const float* c2_bv = (const float*)d_in[23];
    const float* c2_We = (const float*)d_in[24];
    const float* c2_Ws = (const float*)d_in[25]; const float* c2_bs = (const float*)d_in[26];
    const float* Wg1 = (const float*)d_in[27]; const float* bg1 = (const float*)d_in[28];
    const float* Wg2 = (const float*)d_in[29]; const float* bg2 = (const float*)d_in[30];
    const float* Wl1 = (const float*)d_in[31]; const float* bl1 = (const float*)d_in[32];
    const float* Wl2 = (const float*)d_in[33]; const float* bl2 = (const float*)d_in[34];
    const float* Wl3 = (const float*)d_in[35]; const float* bl3 = (const float*)d_in[36];

    float* out = (float*)d_out;

    // ---- workspace layout
    char* ws = (char*)d_ws;
    size_t off = 0;
    _Float16* Gf   = (_Float16*)(ws + off); off += (size_t)NN * 64 * 2;    // 6.4 MB
    _Float16* wps  = (_Float16*)(ws + off); off += 270336 * 2;             // 0.54 MB
    _Float16* hA   = (_Float16*)(ws + off); off += (size_t)NN * 128 * 2;   // 12.8 MB
    _Float16* hB   = (_Float16*)(ws + off); off += (size_t)NN * 128 * 2;   // 12.8 MB
    _Float16* ksb  = (_Float16*)(ws + off); off += (size_t)NN * 256 * 2;   // 25.6 MB
    _Float16* qvb  = (_Float16*)(ws + off); off += (size_t)NN * 256 * 2;   // 25.6 MB (alias u1)
    unsigned* ea2  = (unsigned*)(ws + off); off += (size_t)NE * 21 * 4;    // 67.2 MB
    // deg | cur | gsum contiguous -> one memset
    int*      deg  = (int*)     (ws + off); off += (size_t)NN * 4;
    int*      cur  = (int*)     (ws + off); off += (size_t)NN * 4;
    float*    gsum = (float*)   (ws + off); off += 256 * 4;
    float*    gvec = (float*)   (ws + off); off += 256 * 4;
    int*      incl = (int*)     (ws + off); off += (size_t)NN * 4;
    int*      bsum = (int*)     (ws + off); off += 128 * 4;
    int*      offs = (int*)     (ws + off); off += (size_t)(NN + 2) * 4;
    int*      csr_src = (int*)  (ws + off); off += (size_t)NE * 4;         // 3.2 MB
    int*      csr_eid = (int*)  (ws + off); off += (size_t)NE * 4;         // 3.2 MB
    _Float16* u1f  = qvb;

    const int O_We1 = 0,      O_We2 = 8192,   O_We3 = 24576;
    const int O_c1k = 40960,  O_c1s = 57344,  O_c1q = 73728,  O_c1v = 90112;
    const int O_c2k = 106496, O_c2s = 122880, O_c2q = 139264, O_c2v = 155648;
    const int O_Wg1 = 172032, O_Wg2 = 188416, O_Wl1 = 204800, O_Wl2 = 237568;

    const dim3 blk(256);
    const int  MT = (NN + 63) / 64;       // 782 m-tiles
    const dim3 g1(1, MT), g2(2, MT), g4(4, MT);
    const int  EB = (NE + 255) / 256;
    const int  AGGB = (NN + 3) / 4;

    // ---- one-time prep
    presplit_w<<<dim3(32, 15), blk, 0, stream>>>(
        We1, We2, We3, c1_Wk, c1_Ws, c1_Wq, c1_Wv,
        c2_Wk, c2_Ws, c2_Wq, c2_Wv, Wg1, Wg2, Wl1, Wl2, wps);
    presplit_g<<<dim3((NN * 64 + 1023) / 1024), blk, 0, stream>>>(G, Gf);

    // ---- CSR build (single memset covers deg|cur|gsum)
    hipMemsetAsync(deg, 0, (size_t)(2 * NN + 256) * 4, stream);
    hist_kernel<<<dim3(EB), blk, 0, stream>>>(ei, deg);
    scan1_kernel<<<dim3(SCAN_NB), dim3(SCAN_BS), 0, stream>>>(deg, incl, bsum);
    scan2_kernel<<<dim3(1), dim3(128), 0, stream>>>(bsum);
    scan3_kernel<<<dim3(SCAN_NB), dim3(SCAN_BS), 0, stream>>>(incl, deg, bsum, offs);
    scatter_kernel<<<dim3(EB), blk, 0, stream>>>(ei, offs, cur, csr_src, csr_eid);
    build_ea2<<<dim3(EB), blk, 0, stream>>>(csr_eid, ea, ea2);

    // ---- node-feature MLP
    gemm_ps<true, false><<<g1, blk, 0, stream>>>(Gf, 64,  wps + O_We1, be1, hA, 128, nullptr, NN);
    gemm_ps<true, false><<<g1, blk, 0, stream>>>(hA, 128, wps + O_We2, be2, hB, 128, nullptr, NN);
    gemm_ps<true, false><<<g1, blk, 0, stream>>>(hB, 128, wps + O_We3, be3, hA, 128, nullptr, NN);

    // ---- conv1
    gemm_kqvs<<<g4, blk, 0, stream>>>(hA,
        wps + O_c1k, wps + O_c1s, wps + O_c1q, wps + O_c1v,
        c1_bk, c1_bs, c1_bq, c1_bv, ksb, qvb, NN);
    conv_agg_kernel<<<dim3(AGGB), blk, 0, stream>>>(offs, csr_src, ea2, c1_We,
        ksb, qvb, hB);

    // ---- conv2
    gemm_kqvs<<<g4, blk, 0, stream>>>(hB,
        wps + O_c2k, wps + O_c2s, wps + O_c2q, wps + O_c2v,
        c2_bk, c2_bs, c2_bq, c2_bv, ksb, qvb, NN);
    conv_agg_kernel<<<dim3(AGGB), blk, 0, stream>>>(offs, csr_src, ea2, c2_We,
        ksb, qvb, hA);

    // ---- graph-level MLP (+ fused colsum)
    gemm_ps<true,  false><<<g1, blk, 0, stream>>>(hA, 128, wps + O_Wg1, bg1, hB, 128, nullptr, NN);
    gemm_ps<false, true ><<<g1, blk, 0, stream>>>(hB, 128, wps + O_Wg2, bg2, hA, 128, gsum, NN);

    // ---- graph mean -> gvec
    gvec_kernel<<<dim3(1), dim3(256), 0, stream>>>(gsum, Wl1, bl1, gvec, 1.f / NN);

    // ---- head
    gemm_ps<true, false><<<g2, blk, 0, stream>>>(hA, 128, wps + O_Wl1, gvec, u1f, 256, nullptr, NN);
    gemm_head<<<g1, blk, 0, stream>>>(u1f, wps + O_Wl2, bl2, Wl3, bl3, out, NN);
}

// Round 10
// 516.075 us; speedup vs baseline: 1.7538x; 1.1049x over previous
//
#include <hip/hip_runtime.h>
#include <hip/hip_fp16.h>

#define NN 50000
#define NE 800000
#define HH 128
#define SCAN_BS 512
#define SCAN_NB 98
#define LDK 40
#define LDA 136   // 64-row activation tile stride (halfs): 272B row ≡ 4 dwords mod 32 -> 2-way (free)
#define LDU 264   // 256-wide u1 tile stride

typedef _Float16 half8 __attribute__((ext_vector_type(8)));
typedef float f32x4  __attribute__((ext_vector_type(4)));

// ---------------------------------------------------------------------------
// One-time transpose+cast of weights to fp16: Wt[n][K]
// ---------------------------------------------------------------------------
__global__ __launch_bounds__(256)
void presplit_w(const float* __restrict__ s0,  const float* __restrict__ s1,
                const float* __restrict__ s2,  const float* __restrict__ s3,
                const float* __restrict__ s4,  const float* __restrict__ s5,
                const float* __restrict__ s6,  const float* __restrict__ s7,
                const float* __restrict__ s8,  const float* __restrict__ s9,
                const float* __restrict__ s10, const float* __restrict__ s11,
                const float* __restrict__ s12, const float* __restrict__ s13,
                const float* __restrict__ s14, _Float16* __restrict__ wps)
{
    const float* srcs[15] = {s0,s1,s2,s3,s4,s5,s6,s7,s8,s9,s10,s11,s12,s13,s14};
    const int Ks[15]   = {64,128,128,128,128,128,128,128,128,128,128,128,128,128,256};
    const int logKs[15]= { 6,  7,  7,  7,  7,  7,  7,  7,  7,  7,  7,  7,  7,  7,  8};
    const int off[15]  = {0,8192,24576,40960,57344,73728,90112,106496,122880,
                          139264,155648,172032,188416,204800,237568};

    const int mi = blockIdx.y;
    const float* src = srcs[mi];
    const int K = Ks[mi], logK = logKs[mi];
    const int N = (mi == 13) ? 256 : 128;
    _Float16* dst = wps + off[mi];
    const int tot = K * N;
    const int base = (blockIdx.x * 256 + threadIdx.x) * 4;
    if (base >= tot) return;
    const int n = base >> logK;
    const int k = base & (K - 1);
#pragma unroll
    for (int x = 0; x < 4; ++x)
        dst[(size_t)n * K + k + x] = (_Float16)src[(size_t)(k + x) * N + n];
}

// ---------------------------------------------------------------------------
// LDS->LDS layer: actO[64][ldo](+oc0) = act(relu)(actA[64][lda] @ Bt^T + bias)
// Bt global [128 cols][K] fp16. 4 waves, 32x64/wave, acc[2][4].
// ---------------------------------------------------------------------------
template<bool RELU>
__device__ __forceinline__ void layer_l2l(
    const _Float16* __restrict__ actA, int lda, int K,
    const _Float16* __restrict__ Bt,
    const float* __restrict__ bias,
    _Float16* __restrict__ actO, int ldo, int oc0,
    _Float16* __restrict__ Bs)
{
    const int t = threadIdx.x, lane = t & 63;
    const int wr = (t >> 6) >> 1, wc = (t >> 6) & 1;
    const int fr = lane & 15, fg = lane >> 4;
    const int rb = t >> 1, kb = (t & 1) * 16;

    f32x4 acc[2][4] = {};
    for (int k0 = 0; k0 < K; k0 += 32) {
        const _Float16* p = Bt + (size_t)rb * K + k0 + kb;
        const half8 v0 = *reinterpret_cast<const half8*>(p);
        const half8 v1 = *reinterpret_cast<const half8*>(p + 8);
        *reinterpret_cast<half8*>(&Bs[rb * LDK + kb])     = v0;
        *reinterpret_cast<half8*>(&Bs[rb * LDK + kb + 8]) = v1;
        __syncthreads();

        half8 a[2], b[4];
#pragma unroll
        for (int i = 0; i < 2; ++i)
            a[i] = *reinterpret_cast<const half8*>(&actA[(wr * 32 + i * 16 + fr) * lda + k0 + fg * 8]);
#pragma unroll
        for (int j = 0; j < 4; ++j)
            b[j] = *reinterpret_cast<const half8*>(&Bs[(wc * 64 + j * 16 + fr) * LDK + fg * 8]);
#pragma unroll
        for (int i = 0; i < 2; ++i)
#pragma unroll
            for (int j = 0; j < 4; ++j)
                acc[i][j] = __builtin_amdgcn_mfma_f32_16x16x32_f16(a[i], b[j], acc[i][j], 0, 0, 0);
        __syncthreads();
    }
#pragma unroll
    for (int j = 0; j < 4; ++j) {
        const int gnl = wc * 64 + j * 16 + fr;
        const float bv = bias[gnl];
#pragma unroll
        for (int i = 0; i < 2; ++i)
#pragma unroll
            for (int rr = 0; rr < 4; ++rr) {
                float v = acc[i][j][rr] + bv;
                if (RELU) v = fmaxf(v, 0.f);
                actO[(wr * 32 + i * 16 + fg * 4 + rr) * ldo + oc0 + gnl] = (_Float16)v;
            }
    }
    __syncthreads();
}

// ---------------------------------------------------------------------------
// Fused node MLP: hA = relu(relu(relu(G@We1+b1)@We2+b2)@We3+b3), one dispatch.
// ---------------------------------------------------------------------------
__global__ __launch_bounds__(256)
void mlp3_kernel(const float* __restrict__ G,
                 const _Float16* __restrict__ W1, const float* __restrict__ b1,
                 const _Float16* __restrict__ W2, const float* __restrict__ b2,
                 const _Float16* __restrict__ W3, const float* __restrict__ b3,
                 _Float16* __restrict__ outf, int M)
{
    __shared__ __attribute__((aligned(16))) _Float16 AA[64 * LDA];
    __shared__ __attribute__((aligned(16))) _Float16 AB[64 * LDA];
    __shared__ __attribute__((aligned(16))) _Float16 Bs[128 * LDK];

    const int t  = threadIdx.x;
    const int m0 = blockIdx.x << 6;

    // stage G fp32 -> AA fp16 (64 rows x 64 cols)
    {
        const int r  = t >> 2;
        const int c0 = (t & 3) * 16;
        const int gm = m0 + r;
#pragma unroll
        for (int h = 0; h < 2; ++h) {
            float4 v0 = make_float4(0.f, 0.f, 0.f, 0.f), v1 = v0;
            if (gm < M) {
                v0 = *reinterpret_cast<const float4*>(G + (size_t)gm * 64 + c0 + h * 8);
                v1 = *reinterpret_cast<const float4*>(G + (size_t)gm * 64 + c0 + h * 8 + 4);
            }
            half8 hv;
            hv[0] = (_Float16)v0.x; hv[1] = (_Float16)v0.y;
            hv[2] = (_Float16)v0.z; hv[3] = (_Float16)v0.w;
            hv[4] = (_Float16)v1.x; hv[5] = (_Float16)v1.y;
            hv[6] = (_Float16)v1.z; hv[7] = (_Float16)v1.w;
            *reinterpret_cast<half8*>(&AA[r * LDA + c0 + h * 8]) = hv;
        }
    }
    __syncthreads();

    layer_l2l<true>(AA, LDA, 64,  W1, b1, AB, LDA, 0, Bs);
    layer_l2l<true>(AB, LDA, 128, W2, b2, AA, LDA, 0, Bs);
    layer_l2l<true>(AA, LDA, 128, W3, b3, AB, LDA, 0, Bs);

    // write AB -> outf [M][128]
    {
        const int r  = t >> 2;
        const int c0 = (t & 3) * 32;
        const int gm = m0 + r;
        if (gm < M) {
#pragma unroll
            for (int x = 0; x < 32; x += 8)
                *reinterpret_cast<half8*>(outf + (size_t)gm * 128 + c0 + x) =
                    *reinterpret_cast<const half8*>(&AB[r * LDA + c0 + x]);
        }
    }
}

// ---------------------------------------------------------------------------
// Fused k|s|q|v: stage act once, loop 4 weight sets, interleaved outputs.
// ---------------------------------------------------------------------------
__global__ __launch_bounds__(256)
void kqvs_kernel(const _Float16* __restrict__ act,
                 const _Float16* __restrict__ B0, const _Float16* __restrict__ B1,
                 const _Float16* __restrict__ B2, const _Float16* __restrict__ B3,
                 const float* __restrict__ b0, const float* __restrict__ b1,
                 const float* __restrict__ b2, const float* __restrict__ b3,
                 _Float16* __restrict__ ksb, _Float16* __restrict__ qvb, int M)
{
    __shared__ __attribute__((aligned(16))) _Float16 AA[64 * LDA];
    __shared__ __attribute__((aligned(16))) _Float16 Bs[128 * LDK];

    const int t  = threadIdx.x, lane = t & 63;
    const int m0 = blockIdx.x << 6;
    const int wr = (t >> 6) >> 1, wc = (t >> 6) & 1;
    const int fr = lane & 15, fg = lane >> 4;
    const int rb = t >> 1, kb = (t & 1) * 16;

    // stage act fp16 -> AA
    {
        const int r  = t >> 2;
        const int c0 = (t & 3) * 32;
        const int gm = m0 + r;
#pragma unroll
        for (int x = 0; x < 32; x += 8) {
            half8 v = {0,0,0,0,0,0,0,0};
            if (gm < M) v = *reinterpret_cast<const half8*>(act + (size_t)gm * 128 + c0 + x);
            *reinterpret_cast<half8*>(&AA[r * LDA + c0 + x]) = v;
        }
    }
    __syncthreads();

#pragma unroll
    for (int nb = 0; nb < 4; ++nb) {
        const _Float16* Bt = (nb == 0) ? B0 : (nb == 1) ? B1 : (nb == 2) ? B2 : B3;
        const float*    bt = (nb == 0) ? b0 : (nb == 1) ? b1 : (nb == 2) ? b2 : b3;
        _Float16* dst = (nb < 2) ? ksb : qvb;
        const int sub = (nb & 1) * 2;

        f32x4 acc[2][4] = {};
        for (int k0 = 0; k0 < 128; k0 += 32) {
            const _Float16* p = Bt + (size_t)rb * 128 + k0 + kb;
            const half8 v0 = *reinterpret_cast<const half8*>(p);
            const half8 v1 = *reinterpret_cast<const half8*>(p + 8);
            *reinterpret_cast<half8*>(&Bs[rb * LDK + kb])     = v0;
            *reinterpret_cast<half8*>(&Bs[rb * LDK + kb + 8]) = v1;
            __syncthreads();

            half8 a[2], b[4];
#pragma unroll
            for (int i = 0; i < 2; ++i)
                a[i] = *reinterpret_cast<const half8*>(&AA[(wr * 32 + i * 16 + fr) * LDA + k0 + fg * 8]);
#pragma unroll
            for (int j = 0; j < 4; ++j)
                b[j] = *reinterpret_cast<const half8*>(&Bs[(wc * 64 + j * 16 + fr) * LDK + fg * 8]);
#pragma unroll
            for (int i = 0; i < 2; ++i)
#pragma unroll
                for (int j = 0; j < 4; ++j)
                    acc[i][j] = __builtin_amdgcn_mfma_f32_16x16x32_f16(a[i], b[j], acc[i][j], 0, 0, 0);
            __syncthreads();
        }
#pragma unroll
        for (int j = 0; j < 4; ++j) {
            const int gnl = wc * 64 + j * 16 + fr;
            const int pos = ((gnl >> 1) << 2) + sub + (gnl & 1);
            const float bv = bt[gnl];
#pragma unroll
            for (int i = 0; i < 2; ++i) {
                const int mbase = m0 + wr * 32 + i * 16 + fg * 4;
#pragma unroll
                for (int rr = 0; rr < 4; ++rr) {
                    const int gm = mbase + rr;
                    if (gm < M)
                        dst[(size_t)gm * 256 + pos] = (_Float16)(acc[i][j][rr] + bv);
                }
            }
        }
    }
}

// ---------------------------------------------------------------------------
// Fused graph MLP: g2 = (relu(act@Wg1+bg1))@Wg2+bg2 -> g2f fp16 + colsum atomics.
// ---------------------------------------------------------------------------
__global__ __launch_bounds__(256)
void graph2_kernel(const _Float16* __restrict__ act,
                   const _Float16* __restrict__ Wg1t, const float* __restrict__ bg1,
                   const _Float16* __restrict__ Wg2t, const float* __restrict__ bg2,
                   _Float16* __restrict__ g2f, float* __restrict__ gsum, int M)
{
    __shared__ __attribute__((aligned(16))) _Float16 AA[64 * LDA];
    __shared__ __attribute__((aligned(16))) _Float16 AB[64 * LDA];
    __shared__ __attribute__((aligned(16))) _Float16 Bs[128 * LDK];

    const int t  = threadIdx.x, lane = t & 63;
    const int m0 = blockIdx.x << 6;
    const int wr = (t >> 6) >> 1, wc = (t >> 6) & 1;
    const int fr = lane & 15, fg = lane >> 4;
    const int rb = t >> 1, kb = (t & 1) * 16;

    {
        const int r  = t >> 2;
        const int c0 = (t & 3) * 32;
        const int gm = m0 + r;
#pragma unroll
        for (int x = 0; x < 32; x += 8) {
            half8 v = {0,0,0,0,0,0,0,0};
            if (gm < M) v = *reinterpret_cast<const half8*>(act + (size_t)gm * 128 + c0 + x);
            *reinterpret_cast<half8*>(&AA[r * LDA + c0 + x]) = v;
        }
    }
    __syncthreads();

    layer_l2l<true>(AA, LDA, 128, Wg1t, bg1, AB, LDA, 0, Bs);

    // layer 2 with global write + colsum
    f32x4 acc[2][4] = {};
    for (int k0 = 0; k0 < 128; k0 += 32) {
        const _Float16* p = Wg2t + (size_t)rb * 128 + k0 + kb;
        const half8 v0 = *reinterpret_cast<const half8*>(p);
        const half8 v1 = *reinterpret_cast<const half8*>(p + 8);
        *reinterpret_cast<half8*>(&Bs[rb * LDK + kb])     = v0;
        *reinterpret_cast<half8*>(&Bs[rb * LDK + kb + 8]) = v1;
        __syncthreads();
        half8 a[2], b[4];
#pragma unroll
        for (int i = 0; i < 2; ++i)
            a[i] = *reinterpret_cast<const half8*>(&AB[(wr * 32 + i * 16 + fr) * LDA + k0 + fg * 8]);
#pragma unroll
        for (int j = 0; j < 4; ++j)
            b[j] = *reinterpret_cast<const half8*>(&Bs[(wc * 64 + j * 16 + fr) * LDK + fg * 8]);
#pragma unroll
        for (int i = 0; i < 2; ++i)
#pragma unroll
            for (int j = 0; j < 4; ++j)
                acc[i][j] = __builtin_amdgcn_mfma_f32_16x16x32_f16(a[i], b[j], acc[i][j], 0, 0, 0);
        __syncthreads();
    }
#pragma unroll
    for (int j = 0; j < 4; ++j) {
        const int gn = wc * 64 + j * 16 + fr;
        const float bv = bg2[gn];
        float csum = 0.f;
#pragma unroll
        for (int i = 0; i < 2; ++i) {
            const int mbase = m0 + wr * 32 + i * 16 + fg * 4;
#pragma unroll
            for (int rr = 0; rr < 4; ++rr) {
                const int gm = mbase + rr;
                if (gm < M) {
                    const float v = acc[i][j][rr] + bv;
                    csum += v;
                    g2f[(size_t)gm * 128 + gn] = (_Float16)v;
                }
            }
        }
        csum += __shfl_xor(csum, 16);
        csum += __shfl_xor(csum, 32);
        if (fg == 0) atomicAdd(&gsum[gn], csum);
    }
}

// ---------------------------------------------------------------------------
// Fused head: u1 = relu(g2@Wl1 + gvec) (256-wide, in LDS);
//             u2 = relu(u1@Wl2 + bl2); out = u2 . wl3 + bl3.
// ---------------------------------------------------------------------------
__global__ __launch_bounds__(256)
void head3_kernel(const _Float16* __restrict__ g2f,
                  const _Float16* __restrict__ Wl1t,   // [256][128]
                  const float* __restrict__ gvec,      // [256] bias
                  const _Float16* __restrict__ Wl2t,   // [128][256]
                  const float* __restrict__ bl2,
                  const float* __restrict__ wl3,
                  const float* __restrict__ bl3,
                  float* __restrict__ out, int M)
{
    __shared__ __attribute__((aligned(16))) _Float16 AA[64 * LDA];
    __shared__ __attribute__((aligned(16))) _Float16 UB[64 * LDU];
    __shared__ __attribute__((aligned(16))) _Float16 Bs[128 * LDK];
    __shared__ float psum[2][64];

    const int t  = threadIdx.x, lane = t & 63;
    const int m0 = blockIdx.x << 6;
    const int wr = (t >> 6) >> 1, wc = (t >> 6) & 1;
    const int fr = lane & 15, fg = lane >> 4;
    const int rb = t >> 1, kb = (t & 1) * 16;

    {
        const int r  = t >> 2;
        const int c0 = (t & 3) * 32;
        const int gm = m0 + r;
#pragma unroll
        for (int x = 0; x < 32; x += 8) {
            half8 v = {0,0,0,0,0,0,0,0};
            if (gm < M) v = *reinterpret_cast<const half8*>(g2f + (size_t)gm * 128 + c0 + x);
            *reinterpret_cast<half8*>(&AA[r * LDA + c0 + x]) = v;
        }
    }
    __syncthreads();

    layer_l2l<true>(AA, LDA, 128, Wl1t,             gvec,       UB, LDU, 0,   Bs);
    layer_l2l<true>(AA, LDA, 128, Wl1t + 128 * 128, gvec + 128, UB, LDU, 128, Bs);

    // layer 2: K=256 from UB, N=128, then fused dot with wl3
    f32x4 acc[2][4] = {};
    for (int k0 = 0; k0 < 256; k0 += 32) {
        const _Float16* p = Wl2t + (size_t)rb * 256 + k0 + kb;
        const half8 v0 = *reinterpret_cast<const half8*>(p);
        const half8 v1 = *reinterpret_cast<const half8*>(p + 8);
        *reinterpret_cast<half8*>(&Bs[rb * LDK + kb])     = v0;
        *reinterpret_cast<half8*>(&Bs[rb * LDK + kb + 8]) = v1;
        __syncthreads();
        half8 a[2], b[4];
#pragma unroll
        for (int i = 0; i < 2; ++i)
            a[i] = *reinterpret_cast<const half8*>(&UB[(wr * 32 + i * 16 + fr) * LDU + k0 + fg * 8]);
#pragma unroll
        for (int j = 0; j < 4; ++j)
            b[j] = *reinterpret_cast<const half8*>(&Bs[(wc * 64 + j * 16 + fr) * LDK + fg * 8]);
#pragma unroll
        for (int i = 0; i < 2; ++i)
#pragma unroll
            for (int j = 0; j < 4; ++j)
                acc[i][j] = __builtin_amdgcn_mfma_f32_16x16x32_f16(a[i], b[j], acc[i][j], 0, 0, 0);
        __syncthreads();
    }

    float p[2][4] = {};
#pragma unroll
    for (int j = 0; j < 4; ++j) {
        const int gnl = wc * 64 + j * 16 + fr;
        const float bv = bl2[gnl];
        const float wv = wl3[gnl];
#pragma unroll
        for (int i = 0; i < 2; ++i)
#pragma unroll
            for (int rr = 0; rr < 4; ++rr)
                p[i][rr] += fmaxf(acc[i][j][rr] + bv, 0.f) * wv;
    }
#pragma unroll
    for (int i = 0; i < 2; ++i)
#pragma unroll
        for (int rr = 0; rr < 4; ++rr) {
            float s = p[i][rr];
            s += __shfl_xor(s, 1);
            s += __shfl_xor(s, 2);
            s += __shfl_xor(s, 4);
            s += __shfl_xor(s, 8);
            p[i][rr] = s;
        }
    if (fr == 0) {
#pragma unroll
        for (int i = 0; i < 2; ++i)
#pragma unroll
            for (int rr = 0; rr < 4; ++rr)
                psum[wc][wr * 32 + i * 16 + fg * 4 + rr] = p[i][rr];
    }
    __syncthreads();
    if (t < 64) {
        const int gm = m0 + t;
        if (gm < M) out[gm] = psum[0][t] + psum[1][t] + bl3[0];
    }
}

// ---------------------------------------------------------------------------
// CSR build
// ---------------------------------------------------------------------------
__global__ __launch_bounds__(256)
void hist_kernel(const int* __restrict__ ei, int* __restrict__ deg)
{
    const int e = blockIdx.x * 256 + threadIdx.x;
    if (e < NE) atomicAdd(&deg[ei[NE + e]], 1);
}

__global__ __launch_bounds__(SCAN_BS)
void scan1_kernel(const int* __restrict__ deg, int* __restrict__ incl,
                  int* __restrict__ bsum)
{
    __shared__ int sm[SCAN_BS];
    const int t = threadIdx.x;
    const int i = blockIdx.x * SCAN_BS + t;
    sm[t] = (i < NN) ? deg[i] : 0;
    __syncthreads();
    for (int d = 1; d < SCAN_BS; d <<= 1) {
        const int add = (t >= d) ? sm[t - d] : 0;
        __syncthreads();
        sm[t] += add;
        __syncthreads();
    }
    if (i < NN) incl[i] = sm[t];
    if (t == SCAN_BS - 1) bsum[blockIdx.x] = sm[t];
}

__global__ __launch_bounds__(128)
void scan2_kernel(int* __restrict__ bsum)
{
    __shared__ int sm[128];
    const int t = threadIdx.x;
    const int v = (t < SCAN_NB) ? bsum[t] : 0;
    sm[t] = v;
    __syncthreads();
    for (int d = 1; d < 128; d <<= 1) {
        const int add = (t >= d) ? sm[t - d] : 0;
        __syncthreads();
        sm[t] += add;
        __syncthreads();
    }
    if (t < SCAN_NB) bsum[t] = sm[t] - v;
}

__global__ __launch_bounds__(SCAN_BS)
void scan3_kernel(const int* __restrict__ incl, const int* __restrict__ deg,
                  const int* __restrict__ bsum, int* __restrict__ offs)
{
    const int t = threadIdx.x;
    const int i = blockIdx.x * SCAN_BS + t;
    if (i < NN) offs[i] = incl[i] - deg[i] + bsum[blockIdx.x];
    if (i == 0) offs[NN] = NE;
}

__global__ __launch_bounds__(256)
void scatter_kernel(const int* __restrict__ ei, const int* __restrict__ offs,
                    int* __restrict__ cur,
                    int* __restrict__ csr_src, int* __restrict__ csr_eid)
{
    const int e = blockIdx.x * 256 + threadIdx.x;
    if (e >= NE) return;
    const int d = ei[NE + e];
    const int p = offs[d] + atomicAdd(&cur[d], 1);
    csr_src[p] = ei[e];
    csr_eid[p] = e;
}

__global__ __launch_bounds__(256)
void build_ea2(const int* __restrict__ csr_eid, const float* __restrict__ ea,
               unsigned* __restrict__ ea2)
{
    const int j = blockIdx.x * 256 + threadIdx.x;
    if (j >= NE) return;
    const int eid = csr_eid[j];
    const float* src = ea + (size_t)eid * 21;
    unsigned* dst = ea2 + (size_t)j * 21;
#pragma unroll
    for (int q = 0; q < 21; ++q) {
        const __half2 h = __floats2half2_rn(src[q], src[q]);
        dst[q] = __builtin_bit_cast(unsigned, h);
    }
}

// ---------------------------------------------------------------------------
// Conv aggregation + skip + ReLU (unchanged from R9).
// ---------------------------------------------------------------------------
__global__ __launch_bounds__(256, 8)
void conv_agg_kernel(const int* __restrict__ offs,
                     const int* __restrict__ csr_src,
                     const unsigned* __restrict__ ea2,
                     const float* __restrict__ We,
                     const _Float16* __restrict__ ksb,
                     const _Float16* __restrict__ qvb,
                     _Float16* __restrict__ outh)
{
    const int t    = threadIdx.x;
    const int lane = t & 63;
    const int n    = blockIdx.x * 4 + (t >> 6);
    if (n >= NN) return;

    __half2 w2[21];
#pragma unroll
    for (int q = 0; q < 21; ++q) {
        const float2 wq = *reinterpret_cast<const float2*>(&We[q * HH + 2 * lane]);
        w2[q] = __floats2half2_rn(wq.x, wq.y);
    }

    const uint2 ks = *reinterpret_cast<const uint2*>(ksb + (size_t)n * 256 + lane * 4);
    const __half2 k2 = __builtin_bit_cast(__half2, ks.x);
    const __half2 s2 = __builtin_bit_cast(__half2, ks.y);
    const __half2 one2 = __float2half2_rn(1.f);
    const __half2 two2 = __float2half2_rn(2.f);

    const int j0 = __builtin_amdgcn_readfirstlane(offs[n]);
    const int j1 = __builtin_amdgcn_readfirstlane(offs[n + 1]);
    float acc0 = 0.f, acc1 = 0.f;

#define GATHER(S) (*reinterpret_cast<const uint2*>(qvb + (size_t)(S) * 256 + lane * 4))

#define EDGE(QV, J) { \
    const __half2* aa_ = reinterpret_cast<const __half2*>(ea2 + (size_t)(J) * 21); \
    __half2 e01_ = __float2half2_rn(0.f); \
    _Pragma("unroll") \
    for (int q_ = 0; q_ < 21; ++q_) e01_ = __hfma2(aa_[q_], w2[q_], e01_); \
    const __half2 q2_ = __builtin_bit_cast(__half2, (QV).x); \
    const __half2 v2_ = __builtin_bit_cast(__half2, (QV).y); \
    const __half2 g_  = __hadd2(k2, __hfma2(two2, e01_, q2_)); \
    const __half2 ex_ = h2exp(__hneg2(g_)); \
    const __half2 gate_ = h2rcp(__hadd2(one2, ex_)); \
    const __half2 m_ = __hmul2(gate_, __hadd2(v2_, e01_)); \
    acc0 += __low2float(m_); \
    acc1 += __high2float(m_); }

    int j = j0;
    for (; j + 4 <= j1; j += 4) {
        const int sa = csr_src[j],     sb = csr_src[j + 1];
        const int sc = csr_src[j + 2], sd = csr_src[j + 3];
        const uint2 qva = GATHER(sa);
        const uint2 qvb_ = GATHER(sb);
        const uint2 qvc = GATHER(sc);
        const uint2 qvd = GATHER(sd);
        EDGE(qva, j)
        EDGE(qvb_, j + 1)
        EDGE(qvc, j + 2)
        EDGE(qvd, j + 3)
    }
    for (; j < j1; ++j) {
        const int s_ = csr_src[j];
        const uint2 qv = GATHER(s_);
        EDGE(qv, j)
    }
#undef GATHER
#undef EDGE

    const float r0 = fmaxf(acc0 + __low2float(s2), 0.f);
    const float r1 = fmaxf(acc1 + __high2float(s2), 0.f);
    const __half2 res = __floats2half2_rn(r0, r1);
    *reinterpret_cast<__half2*>(outh + (size_t)n * HH + 2 * lane) = res;
}

// ---------------------------------------------------------------------------
__global__ __launch_bounds__(256)
void gvec_kernel(const float* __restrict__ gsum,
                 const float* __restrict__ Wl1,
                 const float* __restrict__ bl1,
                 float* __restrict__ gvec, float invM)
{
    const int j = threadIdx.x;
    float acc = bl1[j];
    for (int k = 0; k < 128; ++k)
        acc += (gsum[k] * invM) * Wl1[(size_t)(128 + k) * 256 + j];
    gvec[j] = acc;
}

// ---------------------------------------------------------------------------
extern "C" void kernel_launch(void* const* d_in, const int* in_sizes, int n_in,
                              void* d_out, int out_size, void* d_ws, size_t ws_size,
                              hipStream_t stream)
{
    const float* G   = (const float*)d_in[0];
    const int*   ei  = (const int*)  d_in[1];
    const float* ea  = (const float*)d_in[2];
    const float* We1 = (const float*)d_in[3];  const float* be1 = (const float*)d_in[4];
    const float* We2 = (const float*)d_in[5];  const float* be2 = (const float*)d_in[6];
    const float* We3 = (const float*)d_in[7];  const float* be3 = (const float*)d_in[8];
    const float* c1_Wk = (const float*)d_in[9];  const float* c1_bk = (const float*)d_in[10];
    const float* c1_Wq = (const float*)d_in[11]; const float* c1_bq = (const float*)d_in[12];
    const float* c1_Wv = (const float*)d_in[13]; const float* c1_bv = (const float*)d_in[14];
    const float* c1_We = (const float*)d_in[15];
    const float* c1_Ws = (const float*)d_in[16]; const float* c1_bs = (const float*)d_in[17];
    const float* c2_Wk = (const float*)d_in[18]; const float* c2_bk = (const float*)d_in[19];
    const float* c2_Wq = (const float*)d_in[20]; const float* c2_bq = (const float*)d_in[21];
    const float* c2_Wv = (const float*)d_in[22]; const float* c2_bv = (const float*)d_in[23];
    const float* c2_We = (const float*)d_in[24];
    const float* c2_Ws = (const float*)d_in[25]; const float* c2_bs = (const float*)d_in[26];
    const float* Wg1 = (const float*)d_in[27]; const float* bg1 = (const float*)d_in[28];
    const float* Wg2 = (const float*)d_in[29]; const float* bg2 = (const float*)d_in[30];
    const float* Wl1 = (const float*)d_in[31]; const float* bl1 = (const float*)d_in[32];
    const float* Wl2 = (const float*)d_in[33]; const float* bl2 = (const float*)d_in[34];
    const float* Wl3 = (const float*)d_in[35]; const float* bl3 = (const float*)d_in[36];

    float* out = (float*)d_out;

    // ---- workspace layout
    char* ws = (char*)d_ws;
    size_t off = 0;
    _Float16* wps  = (_Float16*)(ws + off); off += 270336 * 2;             // 0.54 MB
    _Float16* hA   = (_Float16*)(ws + off); off += (size_t)NN * 128 * 2;   // 12.8 MB
    _Float16* hB   = (_Float16*)(ws + off); off += (size_t)NN * 128 * 2;   // 12.8 MB
    _Float16* ksb  = (_Float16*)(ws + off); off += (size_t)NN * 256 * 2;   // 25.6 MB
    _Float16* qvb  = (_Float16*)(ws + off); off += (size_t)NN * 256 * 2;   // 25.6 MB
    unsigned* ea2  = (unsigned*)(ws + off); off += (size_t)NE * 21 * 4;    // 67.2 MB
    int*      deg  = (int*)     (ws + off); off += (size_t)NN * 4;
    int*      cur  = (int*)     (ws + off); off += (size_t)NN * 4;
    float*    gsum = (float*)   (ws + off); off += 256 * 4;
    float*    gvec = (float*)   (ws + off); off += 256 * 4;
    int*      incl = (int*)     (ws + off); off += (size_t)NN * 4;
    int*      bsum = (int*)     (ws + off); off += 128 * 4;
    int*      offs = (int*)     (ws + off); off += (size_t)(NN + 2) * 4;
    int*      csr_src = (int*)  (ws + off); off += (size_t)NE * 4;         // 3.2 MB
    int*      csr_eid = (int*)  (ws + off); off += (size_t)NE * 4;         // 3.2 MB

    const int O_We1 = 0,      O_We2 = 8192,   O_We3 = 24576;
    const int O_c1k = 40960,  O_c1s = 57344,  O_c1q = 73728,  O_c1v = 90112;
    const int O_c2k = 106496, O_c2s = 122880, O_c2q = 139264, O_c2v = 155648;
    const int O_Wg1 = 172032, O_Wg2 = 188416, O_Wl1 = 204800, O_Wl2 = 237568;

    const dim3 blk(256);
    const int  MT = (NN + 63) / 64;       // 782 row blocks
    const int  EB = (NE + 255) / 256;
    const int  AGGB = (NN + 3) / 4;

    // ---- one-time prep
    presplit_w<<<dim3(32, 15), blk, 0, stream>>>(
        We1, We2, We3, c1_Wk, c1_Ws, c1_Wq, c1_Wv,
        c2_Wk, c2_Ws, c2_Wq, c2_Wv, Wg1, Wg2, Wl1, Wl2, wps);

    // ---- CSR build (single memset covers deg|cur|gsum)
    hipMemsetAsync(deg, 0, (size_t)(2 * NN + 256) * 4, stream);
    hist_kernel<<<dim3(EB), blk, 0, stream>>>(ei, deg);
    scan1_kernel<<<dim3(SCAN_NB), dim3(SCAN_BS), 0, stream>>>(deg, incl, bsum);
    scan2_kernel<<<dim3(1), dim3(128), 0, stream>>>(bsum);
    scan3_kernel<<<dim3(SCAN_NB), dim3(SCAN_BS), 0, stream>>>(incl, deg, bsum, offs);
    scatter_kernel<<<dim3(EB), blk, 0, stream>>>(ei, offs, cur, csr_src, csr_eid);
    build_ea2<<<dim3(EB), blk, 0, stream>>>(csr_eid, ea, ea2);

    // ---- fused node MLP (G fp32 -> hA fp16)
    mlp3_kernel<<<dim3(MT), blk, 0, stream>>>(G,
        wps + O_We1, be1, wps + O_We2, be2, wps + O_We3, be3, hA, NN);

    // ---- conv1
    kqvs_kernel<<<dim3(MT), blk, 0, stream>>>(hA,
        wps + O_c1k, wps + O_c1s, wps + O_c1q, wps + O_c1v,
        c1_bk, c1_bs, c1_bq, c1_bv, ksb, qvb, NN);
    conv_agg_kernel<<<dim3(AGGB), blk, 0, stream>>>(offs, csr_src, ea2, c1_We,
        ksb, qvb, hB);

    // ---- conv2
    kqvs_kernel<<<dim3(MT), blk, 0, stream>>>(hB,
        wps + O_c2k, wps + O_c2s, wps + O_c2q, wps + O_c2v,
        c2_bk, c2_bs, c2_bq, c2_bv, ksb, qvb, NN);
    conv_agg_kernel<<<dim3(AGGB), blk, 0, stream>>>(offs, csr_src, ea2, c2_We,
        ksb, qvb, hA);

    // ---- fused graph MLP (+ colsum) -> hB (g2 fp16)
    graph2_kernel<<<dim3(MT), blk, 0, stream>>>(hA,
        wps + O_Wg1, bg1, wps + O_Wg2, bg2, hB, gsum, NN);

    // ---- graph mean -> gvec
    gvec_kernel<<<dim3(1), dim3(256), 0, stream>>>(gsum, Wl1, bl1, gvec, 1.f / NN);

    // ---- fused head -> out
    head3_kernel<<<dim3(MT), blk, 0, stream>>>(hB,
        wps + O_Wl1, gvec, wps + O_Wl2, bl2, Wl3, bl3, out, NN);
}

// Round 11
// 454.893 us; speedup vs baseline: 1.9897x; 1.1345x over previous
//
#include <hip/hip_runtime.h>
#include <hip/hip_fp16.h>

#define NN 50000
#define NE 800000
#define HH 128
#define SCAN_BS 512
#define SCAN_NB 98
#define LDK 40
#define LDA 136
#define LDU 264
#define EBLK ((NE + 255) / 256)   // 3125

typedef _Float16 half8 __attribute__((ext_vector_type(8)));
typedef float f32x4  __attribute__((ext_vector_type(4)));

// ---------------------------------------------------------------------------
// prep: blocks [0,480) transpose+cast weights; blocks [480, 480+EBLK) histogram.
// ---------------------------------------------------------------------------
__global__ __launch_bounds__(256)
void prep_kernel(const float* __restrict__ s0,  const float* __restrict__ s1,
                 const float* __restrict__ s2,  const float* __restrict__ s3,
                 const float* __restrict__ s4,  const float* __restrict__ s5,
                 const float* __restrict__ s6,  const float* __restrict__ s7,
                 const float* __restrict__ s8,  const float* __restrict__ s9,
                 const float* __restrict__ s10, const float* __restrict__ s11,
                 const float* __restrict__ s12, const float* __restrict__ s13,
                 const float* __restrict__ s14, _Float16* __restrict__ wps,
                 const int* __restrict__ ei, int* __restrict__ deg)
{
    const int b = blockIdx.x;
    if (b >= 480) {
        const int e = (b - 480) * 256 + threadIdx.x;
        if (e < NE) atomicAdd(&deg[ei[NE + e]], 1);
        return;
    }
    const float* srcs[15] = {s0,s1,s2,s3,s4,s5,s6,s7,s8,s9,s10,s11,s12,s13,s14};
    const int Ks[15]   = {64,128,128,128,128,128,128,128,128,128,128,128,128,128,256};
    const int logKs[15]= { 6,  7,  7,  7,  7,  7,  7,  7,  7,  7,  7,  7,  7,  7,  8};
    const int off[15]  = {0,8192,24576,40960,57344,73728,90112,106496,122880,
                          139264,155648,172032,188416,204800,237568};

    const int mi = b >> 5;
    const int bx = b & 31;
    const float* src = srcs[mi];
    const int K = Ks[mi], logK = logKs[mi];
    const int N = (mi == 13) ? 256 : 128;
    _Float16* dst = wps + off[mi];
    const int tot = K * N;
    const int base = (bx * 256 + threadIdx.x) * 4;
    if (base >= tot) return;
    const int n = base >> logK;
    const int k = base & (K - 1);
#pragma unroll
    for (int x = 0; x < 4; ++x)
        dst[(size_t)n * K + k + x] = (_Float16)src[(size_t)(k + x) * N + n];
}

// ---------------------------------------------------------------------------
// LDS->LDS layer (unchanged)
// ---------------------------------------------------------------------------
template<bool RELU>
__device__ __forceinline__ void layer_l2l(
    const _Float16* __restrict__ actA, int lda, int K,
    const _Float16* __restrict__ Bt,
    const float* __restrict__ bias,
    _Float16* __restrict__ actO, int ldo, int oc0,
    _Float16* __restrict__ Bs)
{
    const int t = threadIdx.x, lane = t & 63;
    const int wr = (t >> 6) >> 1, wc = (t >> 6) & 1;
    const int fr = lane & 15, fg = lane >> 4;
    const int rb = t >> 1, kb = (t & 1) * 16;

    f32x4 acc[2][4] = {};
    for (int k0 = 0; k0 < K; k0 += 32) {
        const _Float16* p = Bt + (size_t)rb * K + k0 + kb;
        const half8 v0 = *reinterpret_cast<const half8*>(p);
        const half8 v1 = *reinterpret_cast<const half8*>(p + 8);
        *reinterpret_cast<half8*>(&Bs[rb * LDK + kb])     = v0;
        *reinterpret_cast<half8*>(&Bs[rb * LDK + kb + 8]) = v1;
        __syncthreads();

        half8 a[2], bfr[4];
#pragma unroll
        for (int i = 0; i < 2; ++i)
            a[i] = *reinterpret_cast<const half8*>(&actA[(wr * 32 + i * 16 + fr) * lda + k0 + fg * 8]);
#pragma unroll
        for (int j = 0; j < 4; ++j)
            bfr[j] = *reinterpret_cast<const half8*>(&Bs[(wc * 64 + j * 16 + fr) * LDK + fg * 8]);
#pragma unroll
        for (int i = 0; i < 2; ++i)
#pragma unroll
            for (int j = 0; j < 4; ++j)
                acc[i][j] = __builtin_amdgcn_mfma_f32_16x16x32_f16(a[i], bfr[j], acc[i][j], 0, 0, 0);
        __syncthreads();
    }
#pragma unroll
    for (int j = 0; j < 4; ++j) {
        const int gnl = wc * 64 + j * 16 + fr;
        const float bv = bias[gnl];
#pragma unroll
        for (int i = 0; i < 2; ++i)
#pragma unroll
            for (int rr = 0; rr < 4; ++rr) {
                float v = acc[i][j][rr] + bv;
                if (RELU) v = fmaxf(v, 0.f);
                actO[(wr * 32 + i * 16 + fg * 4 + rr) * ldo + oc0 + gnl] = (_Float16)v;
            }
    }
    __syncthreads();
}

// ---------------------------------------------------------------------------
// phase5: blocks [0,EBLK) scatter edges + write CSR-ordered ea2 directly;
//         blocks [EBLK, EBLK+MT) run the fused 3-layer node MLP (overlapped).
// ---------------------------------------------------------------------------
__global__ __launch_bounds__(256)
void phase5_kernel(const int* __restrict__ ei, const int* __restrict__ offs,
                   int* __restrict__ cur, const float* __restrict__ ea,
                   int* __restrict__ csr_src, unsigned* __restrict__ ea2,
                   const float* __restrict__ G,
                   const _Float16* __restrict__ W1, const float* __restrict__ b1,
                   const _Float16* __restrict__ W2, const float* __restrict__ b2,
                   const _Float16* __restrict__ W3, const float* __restrict__ b3,
                   _Float16* __restrict__ outf, int M)
{
    __shared__ __attribute__((aligned(16))) _Float16 AA[64 * LDA];
    __shared__ __attribute__((aligned(16))) _Float16 AB[64 * LDA];
    __shared__ __attribute__((aligned(16))) _Float16 Bs[128 * LDK];

    const int t = threadIdx.x;
    if (blockIdx.x < EBLK) {
        const int e = blockIdx.x * 256 + t;
        if (e >= NE) return;
        const int d = ei[NE + e];
        const int p = offs[d] + atomicAdd(&cur[d], 1);
        csr_src[p] = ei[e];
        const float* src = ea + (size_t)e * 21;
        unsigned* dst = ea2 + (size_t)p * 21;
#pragma unroll
        for (int q = 0; q < 21; ++q) {
            const __half2 h = __floats2half2_rn(src[q], src[q]);
            dst[q] = __builtin_bit_cast(unsigned, h);
        }
        return;
    }

    const int m0 = (blockIdx.x - EBLK) << 6;
    // stage G fp32 -> AA fp16
    {
        const int r  = t >> 2;
        const int c0 = (t & 3) * 16;
        const int gm = m0 + r;
#pragma unroll
        for (int h = 0; h < 2; ++h) {
            float4 v0 = make_float4(0.f, 0.f, 0.f, 0.f), v1 = v0;
            if (gm < M) {
                v0 = *reinterpret_cast<const float4*>(G + (size_t)gm * 64 + c0 + h * 8);
                v1 = *reinterpret_cast<const float4*>(G + (size_t)gm * 64 + c0 + h * 8 + 4);
            }
            half8 hv;
            hv[0] = (_Float16)v0.x; hv[1] = (_Float16)v0.y;
            hv[2] = (_Float16)v0.z; hv[3] = (_Float16)v0.w;
            hv[4] = (_Float16)v1.x; hv[5] = (_Float16)v1.y;
            hv[6] = (_Float16)v1.z; hv[7] = (_Float16)v1.w;
            *reinterpret_cast<half8*>(&AA[r * LDA + c0 + h * 8]) = hv;
        }
    }
    __syncthreads();

    layer_l2l<true>(AA, LDA, 64,  W1, b1, AB, LDA, 0, Bs);
    layer_l2l<true>(AB, LDA, 128, W2, b2, AA, LDA, 0, Bs);
    layer_l2l<true>(AA, LDA, 128, W3, b3, AB, LDA, 0, Bs);

    {
        const int r  = t >> 2;
        const int c0 = (t & 3) * 32;
        const int gm = m0 + r;
        if (gm < M) {
#pragma unroll
            for (int x = 0; x < 32; x += 8)
                *reinterpret_cast<half8*>(outf + (size_t)gm * 128 + c0 + x) =
                    *reinterpret_cast<const half8*>(&AB[r * LDA + c0 + x]);
        }
    }
}

// ---------------------------------------------------------------------------
// Fused k|s|q|v (k and q pre-scaled by -log2(e) for the exp2 gate path).
// ---------------------------------------------------------------------------
__global__ __launch_bounds__(256)
void kqvs_kernel(const _Float16* __restrict__ act,
                 const _Float16* __restrict__ B0, const _Float16* __restrict__ B1,
                 const _Float16* __restrict__ B2, const _Float16* __restrict__ B3,
                 const float* __restrict__ b0, const float* __restrict__ b1,
                 const float* __restrict__ b2, const float* __restrict__ b3,
                 _Float16* __restrict__ ksb, _Float16* __restrict__ qvb, int M)
{
    __shared__ __attribute__((aligned(16))) _Float16 AA[64 * LDA];
    __shared__ __attribute__((aligned(16))) _Float16 Bs[128 * LDK];

    const int t  = threadIdx.x, lane = t & 63;
    const int m0 = blockIdx.x << 6;
    const int wr = (t >> 6) >> 1, wc = (t >> 6) & 1;
    const int fr = lane & 15, fg = lane >> 4;
    const int rb = t >> 1, kb = (t & 1) * 16;

    {
        const int r  = t >> 2;
        const int c0 = (t & 3) * 32;
        const int gm = m0 + r;
#pragma unroll
        for (int x = 0; x < 32; x += 8) {
            half8 v = {0,0,0,0,0,0,0,0};
            if (gm < M) v = *reinterpret_cast<const half8*>(act + (size_t)gm * 128 + c0 + x);
            *reinterpret_cast<half8*>(&AA[r * LDA + c0 + x]) = v;
        }
    }
    __syncthreads();

#pragma unroll
    for (int nb = 0; nb < 4; ++nb) {
        const _Float16* Bt = (nb == 0) ? B0 : (nb == 1) ? B1 : (nb == 2) ? B2 : B3;
        const float*    bt = (nb == 0) ? b0 : (nb == 1) ? b1 : (nb == 2) ? b2 : b3;
        _Float16* dst = (nb < 2) ? ksb : qvb;
        const int sub = (nb & 1) * 2;
        const float scl = (nb == 0 || nb == 2) ? -1.44269504f : 1.0f;   // k', q'

        f32x4 acc[2][4] = {};
        for (int k0 = 0; k0 < 128; k0 += 32) {
            const _Float16* p = Bt + (size_t)rb * 128 + k0 + kb;
            const half8 v0 = *reinterpret_cast<const half8*>(p);
            const half8 v1 = *reinterpret_cast<const half8*>(p + 8);
            *reinterpret_cast<half8*>(&Bs[rb * LDK + kb])     = v0;
            *reinterpret_cast<half8*>(&Bs[rb * LDK + kb + 8]) = v1;
            __syncthreads();

            half8 a[2], b[4];
#pragma unroll
            for (int i = 0; i < 2; ++i)
                a[i] = *reinterpret_cast<const half8*>(&AA[(wr * 32 + i * 16 + fr) * LDA + k0 + fg * 8]);
#pragma unroll
            for (int j = 0; j < 4; ++j)
                b[j] = *reinterpret_cast<const half8*>(&Bs[(wc * 64 + j * 16 + fr) * LDK + fg * 8]);
#pragma unroll
            for (int i = 0; i < 2; ++i)
#pragma unroll
                for (int j = 0; j < 4; ++j)
                    acc[i][j] = __builtin_amdgcn_mfma_f32_16x16x32_f16(a[i], b[j], acc[i][j], 0, 0, 0);
            __syncthreads();
        }
#pragma unroll
        for (int j = 0; j < 4; ++j) {
            const int gnl = wc * 64 + j * 16 + fr;
            const int pos = ((gnl >> 1) << 2) + sub + (gnl & 1);
            const float bv = bt[gnl];
#pragma unroll
            for (int i = 0; i < 2; ++i) {
                const int mbase = m0 + wr * 32 + i * 16 + fg * 4;
#pragma unroll
                for (int rr = 0; rr < 4; ++rr) {
                    const int gm = mbase + rr;
                    if (gm < M)
                        dst[(size_t)gm * 256 + pos] = (_Float16)((acc[i][j][rr] + bv) * scl);
                }
            }
        }
    }
}

// ---------------------------------------------------------------------------
// Fused graph MLP (+colsum)
// ---------------------------------------------------------------------------
__global__ __launch_bounds__(256)
void graph2_kernel(const _Float16* __restrict__ act,
                   const _Float16* __restrict__ Wg1t, const float* __restrict__ bg1,
                   const _Float16* __restrict__ Wg2t, const float* __restrict__ bg2,
                   _Float16* __restrict__ g2f, float* __restrict__ gsum, int M)
{
    __shared__ __attribute__((aligned(16))) _Float16 AA[64 * LDA];
    __shared__ __attribute__((aligned(16))) _Float16 AB[64 * LDA];
    __shared__ __attribute__((aligned(16))) _Float16 Bs[128 * LDK];

    const int t  = threadIdx.x, lane = t & 63;
    const int m0 = blockIdx.x << 6;
    const int wr = (t >> 6) >> 1, wc = (t >> 6) & 1;
    const int fr = lane & 15, fg = lane >> 4;
    const int rb = t >> 1, kb = (t & 1) * 16;

    {
        const int r  = t >> 2;
        const int c0 = (t & 3) * 32;
        const int gm = m0 + r;
#pragma unroll
        for (int x = 0; x < 32; x += 8) {
            half8 v = {0,0,0,0,0,0,0,0};
            if (gm < M) v = *reinterpret_cast<const half8*>(act + (size_t)gm * 128 + c0 + x);
            *reinterpret_cast<half8*>(&AA[r * LDA + c0 + x]) = v;
        }
    }
    __syncthreads();

    layer_l2l<true>(AA, LDA, 128, Wg1t, bg1, AB, LDA, 0, Bs);

    f32x4 acc[2][4] = {};
    for (int k0 = 0; k0 < 128; k0 += 32) {
        const _Float16* p = Wg2t + (size_t)rb * 128 + k0 + kb;
        const half8 v0 = *reinterpret_cast<const half8*>(p);
        const half8 v1 = *reinterpret_cast<const half8*>(p + 8);
        *reinterpret_cast<half8*>(&Bs[rb * LDK + kb])     = v0;
        *reinterpret_cast<half8*>(&Bs[rb * LDK + kb + 8]) = v1;
        __syncthreads();
        half8 a[2], b[4];
#pragma unroll
        for (int i = 0; i < 2; ++i)
            a[i] = *reinterpret_cast<const half8*>(&AB[(wr * 32 + i * 16 + fr) * LDA + k0 + fg * 8]);
#pragma unroll
        for (int j = 0; j < 4; ++j)
            b[j] = *reinterpret_cast<const half8*>(&Bs[(wc * 64 + j * 16 + fr) * LDK + fg * 8]);
#pragma unroll
        for (int i = 0; i < 2; ++i)
#pragma unroll
            for (int j = 0; j < 4; ++j)
                acc[i][j] = __builtin_amdgcn_mfma_f32_16x16x32_f16(a[i], b[j], acc[i][j], 0, 0, 0);
        __syncthreads();
    }
#pragma unroll
    for (int j = 0; j < 4; ++j) {
        const int gn = wc * 64 + j * 16 + fr;
        const float bv = bg2[gn];
        float csum = 0.f;
#pragma unroll
        for (int i = 0; i < 2; ++i) {
            const int mbase = m0 + wr * 32 + i * 16 + fg * 4;
#pragma unroll
            for (int rr = 0; rr < 4; ++rr) {
                const int gm = mbase + rr;
                if (gm < M) {
                    const float v = acc[i][j][rr] + bv;
                    csum += v;
                    g2f[(size_t)gm * 128 + gn] = (_Float16)v;
                }
            }
        }
        csum += __shfl_xor(csum, 16);
        csum += __shfl_xor(csum, 32);
        if (fg == 0) atomicAdd(&gsum[gn], csum);
    }
}

// ---------------------------------------------------------------------------
// Fused head (unchanged)
// ---------------------------------------------------------------------------
__global__ __launch_bounds__(256)
void head3_kernel(const _Float16* __restrict__ g2f,
                  const _Float16* __restrict__ Wl1t,
                  const float* __restrict__ gvec,
                  const _Float16* __restrict__ Wl2t,
                  const float* __restrict__ bl2,
                  const float* __restrict__ wl3,
                  const float* __restrict__ bl3,
                  float* __restrict__ out, int M)
{
    __shared__ __attribute__((aligned(16))) _Float16 AA[64 * LDA];
    __shared__ __attribute__((aligned(16))) _Float16 UB[64 * LDU];
    __shared__ __attribute__((aligned(16))) _Float16 Bs[128 * LDK];
    __shared__ float psum[2][64];

    const int t  = threadIdx.x, lane = t & 63;
    const int m0 = blockIdx.x << 6;
    const int wr = (t >> 6) >> 1, wc = (t >> 6) & 1;
    const int fr = lane & 15, fg = lane >> 4;
    const int rb = t >> 1, kb = (t & 1) * 16;

    {
        const int r  = t >> 2;
        const int c0 = (t & 3) * 32;
        const int gm = m0 + r;
#pragma unroll
        for (int x = 0; x < 32; x += 8) {
            half8 v = {0,0,0,0,0,0,0,0};
            if (gm < M) v = *reinterpret_cast<const half8*>(g2f + (size_t)gm * 128 + c0 + x);
            *reinterpret_cast<half8*>(&AA[r * LDA + c0 + x]) = v;
        }
    }
    __syncthreads();

    layer_l2l<true>(AA, LDA, 128, Wl1t,             gvec,       UB, LDU, 0,   Bs);
    layer_l2l<true>(AA, LDA, 128, Wl1t + 128 * 128, gvec + 128, UB, LDU, 128, Bs);

    f32x4 acc[2][4] = {};
    for (int k0 = 0; k0 < 256; k0 += 32) {
        const _Float16* p = Wl2t + (size_t)rb * 256 + k0 + kb;
        const half8 v0 = *reinterpret_cast<const half8*>(p);
        const half8 v1 = *reinterpret_cast<const half8*>(p + 8);
        *reinterpret_cast<half8*>(&Bs[rb * LDK + kb])     = v0;
        *reinterpret_cast<half8*>(&Bs[rb * LDK + kb + 8]) = v1;
        __syncthreads();
        half8 a[2], b[4];
#pragma unroll
        for (int i = 0; i < 2; ++i)
            a[i] = *reinterpret_cast<const half8*>(&UB[(wr * 32 + i * 16 + fr) * LDU + k0 + fg * 8]);
#pragma unroll
        for (int j = 0; j < 4; ++j)
            b[j] = *reinterpret_cast<const half8*>(&Bs[(wc * 64 + j * 16 + fr) * LDK + fg * 8]);
#pragma unroll
        for (int i = 0; i < 2; ++i)
#pragma unroll
            for (int j = 0; j < 4; ++j)
                acc[i][j] = __builtin_amdgcn_mfma_f32_16x16x32_f16(a[i], b[j], acc[i][j], 0, 0, 0);
        __syncthreads();
    }

    float p[2][4] = {};
#pragma unroll
    for (int j = 0; j < 4; ++j) {
        const int gnl = wc * 64 + j * 16 + fr;
        const float bv = bl2[gnl];
        const float wv = wl3[gnl];
#pragma unroll
        for (int i = 0; i < 2; ++i)
#pragma unroll
            for (int rr = 0; rr < 4; ++rr)
                p[i][rr] += fmaxf(acc[i][j][rr] + bv, 0.f) * wv;
    }
#pragma unroll
    for (int i = 0; i < 2; ++i)
#pragma unroll
        for (int rr = 0; rr < 4; ++rr) {
            float s = p[i][rr];
            s += __shfl_xor(s, 1);
            s += __shfl_xor(s, 2);
            s += __shfl_xor(s, 4);
            s += __shfl_xor(s, 8);
            p[i][rr] = s;
        }
    if (fr == 0) {
#pragma unroll
        for (int i = 0; i < 2; ++i)
#pragma unroll
            for (int rr = 0; rr < 4; ++rr)
                psum[wc][wr * 32 + i * 16 + fg * 4 + rr] = p[i][rr];
    }
    __syncthreads();
    if (t < 64) {
        const int gm = m0 + t;
        if (gm < M) out[gm] = psum[0][t] + psum[1][t] + bl3[0];
    }
}

// ---------------------------------------------------------------------------
// scans
// ---------------------------------------------------------------------------
__global__ __launch_bounds__(SCAN_BS)
void scan1_kernel(const int* __restrict__ deg, int* __restrict__ incl,
                  int* __restrict__ bsum)
{
    __shared__ int sm[SCAN_BS];
    const int t = threadIdx.x;
    const int i = blockIdx.x * SCAN_BS + t;
    sm[t] = (i < NN) ? deg[i] : 0;
    __syncthreads();
    for (int d = 1; d < SCAN_BS; d <<= 1) {
        const int add = (t >= d) ? sm[t - d] : 0;
        __syncthreads();
        sm[t] += add;
        __syncthreads();
    }
    if (i < NN) incl[i] = sm[t];
    if (t == SCAN_BS - 1) bsum[blockIdx.x] = sm[t];
}

__global__ __launch_bounds__(128)
void scan2_kernel(int* __restrict__ bsum)
{
    __shared__ int sm[128];
    const int t = threadIdx.x;
    const int v = (t < SCAN_NB) ? bsum[t] : 0;
    sm[t] = v;
    __syncthreads();
    for (int d = 1; d < 128; d <<= 1) {
        const int add = (t >= d) ? sm[t - d] : 0;
        __syncthreads();
        sm[t] += add;
        __syncthreads();
    }
    if (t < SCAN_NB) bsum[t] = sm[t] - v;
}

__global__ __launch_bounds__(SCAN_BS)
void scan3_kernel(const int* __restrict__ incl, const int* __restrict__ deg,
                  const int* __restrict__ bsum, int* __restrict__ offs)
{
    const int t = threadIdx.x;
    const int i = blockIdx.x * SCAN_BS + t;
    if (i < NN) offs[i] = incl[i] - deg[i] + bsum[blockIdx.x];
    if (i == 0) offs[NN] = NE;
}

// ---------------------------------------------------------------------------
// Conv aggregation (exp2 gate path; k', q' pre-scaled by -log2 e).
// ---------------------------------------------------------------------------
__global__ __launch_bounds__(256, 8)
void conv_agg_kernel(const int* __restrict__ offs,
                     const int* __restrict__ csr_src,
                     const unsigned* __restrict__ ea2,
                     const float* __restrict__ We,
                     const _Float16* __restrict__ ksb,
                     const _Float16* __restrict__ qvb,
                     _Float16* __restrict__ outh)
{
    const int t    = threadIdx.x;
    const int lane = t & 63;
    const int n    = blockIdx.x * 4 + (t >> 6);
    if (n >= NN) return;

    __half2 w2[21];
#pragma unroll
    for (int q = 0; q < 21; ++q) {
        const float2 wq = *reinterpret_cast<const float2*>(&We[q * HH + 2 * lane]);
        w2[q] = __floats2half2_rn(wq.x, wq.y);
    }

    const uint2 ks = *reinterpret_cast<const uint2*>(ksb + (size_t)n * 256 + lane * 4);
    const __half2 k2 = __builtin_bit_cast(__half2, ks.x);   // k' = -log2e * k
    const __half2 s2 = __builtin_bit_cast(__half2, ks.y);
    const __half2 one2 = __float2half2_rn(1.f);
    const __half2 cm2  = __float2half2_rn(-2.88539008f);    // -2*log2e

    const int j0 = __builtin_amdgcn_readfirstlane(offs[n]);
    const int j1 = __builtin_amdgcn_readfirstlane(offs[n + 1]);
    float acc0 = 0.f, acc1 = 0.f;

#define GATHER(S) (*reinterpret_cast<const uint2*>(qvb + (size_t)(S) * 256 + lane * 4))

#define EDGE(QV, J) { \
    const __half2* aa_ = reinterpret_cast<const __half2*>(ea2 + (size_t)(J) * 21); \
    __half2 e01_ = __float2half2_rn(0.f); \
    _Pragma("unroll") \
    for (int q_ = 0; q_ < 21; ++q_) e01_ = __hfma2(aa_[q_], w2[q_], e01_); \
    const __half2 q2_ = __builtin_bit_cast(__half2, (QV).x); \
    const __half2 v2_ = __builtin_bit_cast(__half2, (QV).y); \
    const __half2 arg_ = __hadd2(k2, __hfma2(cm2, e01_, q2_)); \
    const __half2 gate_ = h2rcp(__hadd2(one2, h2exp2(arg_))); \
    const __half2 m_ = __hmul2(gate_, __hadd2(v2_, e01_)); \
    acc0 += __low2float(m_); \
    acc1 += __high2float(m_); }

    int j = j0;
    for (; j + 4 <= j1; j += 4) {
        const int sa = csr_src[j],     sb = csr_src[j + 1];
        const int sc = csr_src[j + 2], sd = csr_src[j + 3];
        const uint2 qva = GATHER(sa);
        const uint2 qvb_ = GATHER(sb);
        const uint2 qvc = GATHER(sc);
        const uint2 qvd = GATHER(sd);
        EDGE(qva, j)
        EDGE(qvb_, j + 1)
        EDGE(qvc, j + 2)
        EDGE(qvd, j + 3)
    }
    for (; j < j1; ++j) {
        const int s_ = csr_src[j];
        const uint2 qv = GATHER(s_);
        EDGE(qv, j)
    }
#undef GATHER
#undef EDGE

    const float r0 = fmaxf(acc0 + __low2float(s2), 0.f);
    const float r1 = fmaxf(acc1 + __high2float(s2), 0.f);
    const __half2 res = __floats2half2_rn(r0, r1);
    *reinterpret_cast<__half2*>(outh + (size_t)n * HH + 2 * lane) = res;
}

// ---------------------------------------------------------------------------
__global__ __launch_bounds__(256)
void gvec_kernel(const float* __restrict__ gsum,
                 const float* __restrict__ Wl1,
                 const float* __restrict__ bl1,
                 float* __restrict__ gvec, float invM)
{
    const int j = threadIdx.x;
    float acc = bl1[j];
    for (int k = 0; k < 128; ++k)
        acc += (gsum[k] * invM) * Wl1[(size_t)(128 + k) * 256 + j];
    gvec[j] = acc;
}

// ---------------------------------------------------------------------------
extern "C" void kernel_launch(void* const* d_in, const int* in_sizes, int n_in,
                              void* d_out, int out_size, void* d_ws, size_t ws_size,
                              hipStream_t stream)
{
    const float* G   = (const float*)d_in[0];
    const int*   ei  = (const int*)  d_in[1];
    const float* ea  = (const float*)d_in[2];
    const float* We1 = (const float*)d_in[3];  const float* be1 = (const float*)d_in[4];
    const float* We2 = (const float*)d_in[5];  const float* be2 = (const float*)d_in[6];
    const float* We3 = (const float*)d_in[7];  const float* be3 = (const float*)d_in[8];
    const float* c1_Wk = (const float*)d_in[9];  const float* c1_bk = (const float*)d_in[10];
    const float* c1_Wq = (const float*)d_in[11]; const float* c1_bq = (const float*)d_in[12];
    const float* c1_Wv = (const float*)d_in[13]; const float* c1_bv = (const float*)d_in[14];
    const float* c1_We = (const float*)d_in[15];
    const float* c1_Ws = (const float*)d_in[16]; const float* c1_bs = (const float*)d_in[17];
    const float* c2_Wk = (const float*)d_in[18]; const float* c2_bk = (const float*)d_in[19];
    const float* c2_Wq = (const float*)d_in[20]; const float* c2_bq = (const float*)d_in[21];
    const float* c2_Wv = (const float*)d_in[22]; const float* c2_bv = (const float*)d_in[23];
    const float* c2_We = (const float*)d_in[24];
    const float* c2_Ws = (const float*)d_in[25]; const float* c2_bs = (const float*)d_in[26];
    const float* Wg1 = (const float*)d_in[27]; const float* bg1 = (const float*)d_in[28];
    const float* Wg2 = (const float*)d_in[29]; const float* bg2 = (const float*)d_in[30];
    const float* Wl1 = (const float*)d_in[31]; const float* bl1 = (const float*)d_in[32];
    const float* Wl2 = (const float*)d_in[33]; const float* bl2 = (const float*)d_in[34];
    const float* Wl3 = (const float*)d_in[35]; const float* bl3 = (const float*)d_in[36];

    float* out = (float*)d_out;

    // ---- workspace layout
    char* ws = (char*)d_ws;
    size_t off = 0;
    _Float16* wps  = (_Float16*)(ws + off); off += 270336 * 2;
    _Float16* hA   = (_Float16*)(ws + off); off += (size_t)NN * 128 * 2;
    _Float16* hB   = (_Float16*)(ws + off); off += (size_t)NN * 128 * 2;
    _Float16* ksb  = (_Float16*)(ws + off); off += (size_t)NN * 256 * 2;
    _Float16* qvb  = (_Float16*)(ws + off); off += (size_t)NN * 256 * 2;
    unsigned* ea2  = (unsigned*)(ws + off); off += (size_t)NE * 21 * 4;
    int*      deg  = (int*)     (ws + off); off += (size_t)NN * 4;
    int*      cur  = (int*)     (ws + off); off += (size_t)NN * 4;
    float*    gsum = (float*)   (ws + off); off += 256 * 4;
    float*    gvec = (float*)   (ws + off); off += 256 * 4;
    int*      incl = (int*)     (ws + off); off += (size_t)NN * 4;
    int*      bsum = (int*)     (ws + off); off += 128 * 4;
    int*      offs = (int*)     (ws + off); off += (size_t)(NN + 2) * 4;
    int*      csr_src = (int*)  (ws + off); off += (size_t)NE * 4;

    const int O_We1 = 0,      O_We2 = 8192,   O_We3 = 24576;
    const int O_c1k = 40960,  O_c1s = 57344,  O_c1q = 73728,  O_c1v = 90112;
    const int O_c2k = 106496, O_c2s = 122880, O_c2q = 139264, O_c2v = 155648;
    const int O_Wg1 = 172032, O_Wg2 = 188416, O_Wl1 = 204800, O_Wl2 = 237568;

    const dim3 blk(256);
    const int  MT = (NN + 63) / 64;       // 782
    const int  AGGB = (NN + 3) / 4;

    // ---- prep (weights transpose + degree histogram) after zeroing counters
    hipMemsetAsync(deg, 0, (size_t)(2 * NN + 256) * 4, stream);
    prep_kernel<<<dim3(480 + EBLK), blk, 0, stream>>>(
        We1, We2, We3, c1_Wk, c1_Ws, c1_Wq, c1_Wv,
        c2_Wk, c2_Ws, c2_Wq, c2_Wv, Wg1, Wg2, Wl1, Wl2, wps, ei, deg);

    scan1_kernel<<<dim3(SCAN_NB), dim3(SCAN_BS), 0, stream>>>(deg, incl, bsum);
    scan2_kernel<<<dim3(1), dim3(128), 0, stream>>>(bsum);
    scan3_kernel<<<dim3(SCAN_NB), dim3(SCAN_BS), 0, stream>>>(incl, deg, bsum, offs);

    // ---- scatter + ea2 + fused node MLP (overlapped in one dispatch)
    phase5_kernel<<<dim3(EBLK + MT), blk, 0, stream>>>(
        ei, offs, cur, ea, csr_src, ea2, G,
        wps + O_We1, be1, wps + O_We2, be2, wps + O_We3, be3, hA, NN);

    // ---- conv1
    kqvs_kernel<<<dim3(MT), blk, 0, stream>>>(hA,
        wps + O_c1k, wps + O_c1s, wps + O_c1q, wps + O_c1v,
        c1_bk, c1_bs, c1_bq, c1_bv, ksb, qvb, NN);
    conv_agg_kernel<<<dim3(AGGB), blk, 0, stream>>>(offs, csr_src, ea2, c1_We,
        ksb, qvb, hB);

    // ---- conv2
    kqvs_kernel<<<dim3(MT), blk, 0, stream>>>(hB,
        wps + O_c2k, wps + O_c2s, wps + O_c2q, wps + O_c2v,
        c2_bk, c2_bs, c2_bq, c2_bv, ksb, qvb, NN);
    conv_agg_kernel<<<dim3(AGGB), blk, 0, stream>>>(offs, csr_src, ea2, c2_We,
        ksb, qvb, hA);

    // ---- graph MLP (+colsum) -> hB
    graph2_kernel<<<dim3(MT), blk, 0, stream>>>(hA,
        wps + O_Wg1, bg1, wps + O_Wg2, bg2, hB, gsum, NN);

    // ---- graph mean -> gvec
    gvec_kernel<<<dim3(1), dim3(256), 0, stream>>>(gsum, Wl1, bl1, gvec, 1.f / NN);

    // ---- head -> out
    head3_kernel<<<dim3(MT), blk, 0, stream>>>(hB,
        wps + O_Wl1, gvec, wps + O_Wl2, bl2, Wl3, bl3, out, NN);
}